// Round 9
// baseline (226.391 us; speedup 1.0000x reference)
//
#include <hip/hip_runtime.h>

// loraLinearAttention on MI355X — fp32, LoRA folded into effective weights,
// linear attention collapsed to per-(b,h) 32x32 context and per-batch 128x128
// merged output matrix M_b = w_out @ blockdiag(ctx_h^T) * SCALE.
//
// R8->R9: ctx_partial matvec made ALL-LDS. R8 counters (VALUBusy 41%, dur
// 103us vs 42us of VALU issue) point at the smem+ds mix in the inner loop:
// W via s_load and x via ds_read share lgkmcnt, SMEM completes out-of-order
// -> compiler must lgkmcnt(0) every iteration -> ~200cyc/c serial stall.
// Now W is staged in LDS (8KB quarters next to 8KB x quarters; per c: 1
// ds_read_b32 + 4 broadcast ds_read_b128 + 16 FMA, all in-order DS ->
// counted lgkmcnt pipelining). Bias hoisted to regs. kv/exp/ctx phases and
// all other kernels unchanged from R8.

#define SCALING 0.25f
#define SCALE   0.17677669529663687f   /* 32^-0.5 */
#define NCHUNK  16

__global__ __launch_bounds__(256) void fold_kernel(
    const float* __restrict__ w_qkv,
    const float* __restrict__ wA_q, const float* __restrict__ bA_q,
    const float* __restrict__ wB_q, const float* __restrict__ bB_q,
    const float* __restrict__ wA_k, const float* __restrict__ bA_k,
    const float* __restrict__ wB_k, const float* __restrict__ bB_k,
    const float* __restrict__ wA_v, const float* __restrict__ bA_v,
    const float* __restrict__ wB_v, const float* __restrict__ bB_v,
    float* __restrict__ Wt, float* __restrict__ beff)
{
    int idx = blockIdx.x * 256 + threadIdx.x;   // 49152 total
    int m = idx >> 14;
    int c = (idx >> 7) & 127;
    int o = idx & 127;
    const float* wA = (m == 0) ? wA_q : (m == 1) ? wA_k : wA_v;
    const float* wB = (m == 0) ? wB_q : (m == 1) ? wB_k : wB_v;
    float s = w_qkv[(m * 128 + o) * 128 + c];
    #pragma unroll
    for (int r = 0; r < 4; ++r)
        s += SCALING * wB[o * 4 + r] * wA[r * 128 + c];
    Wt[m * 16384 + c * 128 + o] = s;           // transposed [c][o]

    if (blockIdx.x == 0 && threadIdx.x < 384) {
        int mm = threadIdx.x >> 7, oo = threadIdx.x & 127;
        const float* wBm = (mm == 0) ? wB_q : (mm == 1) ? wB_k : wB_v;
        const float* bAm = (mm == 0) ? bA_q : (mm == 1) ? bA_k : bA_v;
        const float* bBm = (mm == 0) ? bB_q : (mm == 1) ? bB_k : bB_v;
        float bb = bBm[oo];
        #pragma unroll
        for (int r = 0; r < 4; ++r) bb += wBm[oo * 4 + r] * bAm[r];
        beff[mm * 128 + oo] = SCALING * bb;
    }
}

// grid (chunk=16, h=4, b=16) = 1024 blocks, 256 threads, ~34KB LDS.
// Each block: 256 pixels in 4 tiles of 64; x AND W streamed in 32-channel
// quarters through LDS (all-LDS matvec: in-order lgkmcnt pipelining).
__global__ __launch_bounds__(256) void ctx_partial_kernel(
    const float* __restrict__ x, const float* __restrict__ Wt,
    const float* __restrict__ beff, float* __restrict__ part)
{
    __shared__ float x_q[32 * 64];       // 8 KB: x quarter [32c][64n]
    __shared__ float w_q[32 * 64];       // 8 KB: W quarter [32c][64j]
    __shared__ float kv_t[2][32 * 65];   // pitch 65: column reads conflict-free
    __shared__ float lsum[8][32];
    const int t = threadIdx.x;
    const int chunk = blockIdx.x, h = blockIdx.y, b = blockIdx.z;
    const int n = t & 63;
    const int og = __builtin_amdgcn_readfirstlane(t >> 6);  // wave id 0..3
    const int is_v = og >> 1;            // waves 0,1 -> k; 2,3 -> v
    const int r0 = (og & 1) * 16;
    const float* bm = beff + (1 + is_v) * 128 + h * 32 + r0;
    const float* xb = x + (size_t)b * (128 * 4096);
    const int d = t & 31;                // row for exp/ctx phases
    const int g = t >> 5;                // 0..7

    // per-thread W-stage source mapping (thread loads 2 float4 per quarter):
    // idx4 = i*256+t -> c_loc = idx4>>4, j4 = idx4&15
    // j = j4*4..j4*4+3 -> matrix m = 1+(j4>>3) (k or v), rows h*32+(j4&7)*4
    float bias[16];
    #pragma unroll
    for (int i = 0; i < 16; ++i) bias[i] = bm[i];   // hoisted: no per-tile s_load

    float cacc[4] = {0.f, 0.f, 0.f, 0.f};
    float lpart = 0.f;

    #pragma unroll 1
    for (int tt = 0; tt < 4; ++tt) {
        const int n0 = chunk * 256 + tt * 64;
        float acc[16];
        #pragma unroll
        for (int i = 0; i < 16; ++i) acc[i] = bias[i];
        #pragma unroll 1
        for (int qq = 0; qq < 4; ++qq) {
            __syncthreads();             // prev reads of x_q/w_q (or kv) done
            #pragma unroll
            for (int i = 0; i < 2; ++i) {   // x quarter [32][64]
                int idx4 = i * 256 + t;
                int c = idx4 >> 4, q4 = idx4 & 15;
                *(float4*)(&x_q[c * 64 + q4 * 4]) =
                    *(const float4*)(xb + (size_t)(qq * 32 + c) * 4096
                                     + n0 + q4 * 4);
            }
            #pragma unroll
            for (int i = 0; i < 2; ++i) {   // W quarter [32][64]
                int idx4 = i * 256 + t;
                int c = idx4 >> 4, j4 = idx4 & 15;
                *(float4*)(&w_q[c * 64 + j4 * 4]) =
                    *(const float4*)(Wt + (1 + (j4 >> 3)) * 16384
                                     + (size_t)(qq * 32 + c) * 128
                                     + h * 32 + (j4 & 7) * 4);
            }
            __syncthreads();
            const float* wbase = &w_q[og * 16];
            for (int c = 0; c < 32; ++c) {
                float xv = x_q[c * 64 + n];
                float4 w0 = *(const float4*)(wbase + c * 64);
                float4 w1 = *(const float4*)(wbase + c * 64 + 4);
                float4 w2 = *(const float4*)(wbase + c * 64 + 8);
                float4 w3 = *(const float4*)(wbase + c * 64 + 12);
                acc[ 0] = fmaf(w0.x, xv, acc[ 0]);
                acc[ 1] = fmaf(w0.y, xv, acc[ 1]);
                acc[ 2] = fmaf(w0.z, xv, acc[ 2]);
                acc[ 3] = fmaf(w0.w, xv, acc[ 3]);
                acc[ 4] = fmaf(w1.x, xv, acc[ 4]);
                acc[ 5] = fmaf(w1.y, xv, acc[ 5]);
                acc[ 6] = fmaf(w1.z, xv, acc[ 6]);
                acc[ 7] = fmaf(w1.w, xv, acc[ 7]);
                acc[ 8] = fmaf(w2.x, xv, acc[ 8]);
                acc[ 9] = fmaf(w2.y, xv, acc[ 9]);
                acc[10] = fmaf(w2.z, xv, acc[10]);
                acc[11] = fmaf(w2.w, xv, acc[11]);
                acc[12] = fmaf(w3.x, xv, acc[12]);
                acc[13] = fmaf(w3.y, xv, acc[13]);
                acc[14] = fmaf(w3.z, xv, acc[14]);
                acc[15] = fmaf(w3.w, xv, acc[15]);
            }
        }
        __syncthreads();                 // all matvec reads done
        #pragma unroll
        for (int i = 0; i < 16; ++i) kv_t[is_v][(r0 + i) * 65 + n] = acc[i];
        __syncthreads();
        // exp(k) in place (max-free softmax: |k| bounded ~4), row partial sums
        float lp = 0.f;
        #pragma unroll
        for (int j = 0; j < 8; ++j) {
            int nn = g * 8 + j;
            float p = __expf(kv_t[0][d * 65 + nn]);
            kv_t[0][d * 65 + nn] = p;
            lp += p;
        }
        lpart += lp;
        __syncthreads();
        // context accumulate: thread owns (d, e = g*4+j), j<4
        for (int nn = 0; nn < 64; ++nn) {
            float p = kv_t[0][d * 65 + nn];
            #pragma unroll
            for (int j = 0; j < 4; ++j)
                cacc[j] = fmaf(p, kv_t[1][(g * 4 + j) * 65 + nn], cacc[j]);
        }
    }
    lsum[g][d] = lpart;
    __syncthreads();
    float* pout = part + (size_t)((b * 4 + h) * NCHUNK + chunk) * 1056;
    if (t < 32) {
        float l = 0.f;
        #pragma unroll
        for (int gg = 0; gg < 8; ++gg) l += lsum[gg][t];
        pout[1024 + t] = l;
    }
    #pragma unroll
    for (int j = 0; j < 4; ++j) pout[d * 32 + g * 4 + j] = cacc[j];
}

// grid (16 = batch), 256 threads
__global__ __launch_bounds__(256) void combine_m_kernel(
    const float* __restrict__ part, const float* __restrict__ w_out,
    float* __restrict__ Mt)
{
    __shared__ float ctx[4096];        // [h][d][e]
    __shared__ float linv[128];
    __shared__ float wt[128 * 129];    // w_out^T, padded
    const int t = threadIdx.x;
    const int b = blockIdx.x;
    const float* pb = part + (size_t)b * 4 * NCHUNK * 1056;

    if (t < 128) {
        int h = t >> 5, d = t & 31;
        float l = 0.f;
        for (int ch = 0; ch < NCHUNK; ++ch)
            l += pb[(h * NCHUNK + ch) * 1056 + 1024 + d];
        linv[t] = 1.0f / (l * 4096.0f);   // folds the v/n division
    }
    for (int i = 0; i < 64; ++i) {        // stage w_out transposed
        int idx = i * 256 + t;
        int o = idx >> 7, c = idx & 127;
        wt[c * 129 + o] = w_out[idx];
    }
    __syncthreads();
    for (int i = 0; i < 16; ++i) {        // context = sum(partials) * linv
        int idx = i * 256 + t;
        int h = idx >> 10, d = (idx >> 5) & 31, e = idx & 31;
        float s = 0.f;
        for (int ch = 0; ch < NCHUNK; ++ch)
            s += pb[(h * NCHUNK + ch) * 1056 + d * 32 + e];
        ctx[idx] = s * linv[h * 32 + d];
    }
    __syncthreads();
    for (int i = 0; i < 64; ++i) {        // M_b^T[j][o] = SCALE * sum_e wt[he][o]*ctx[h][d][e]
        int idx = i * 256 + t;
        int j = idx >> 7, o = idx & 127;
        int h = j >> 5, d = j & 31;
        float s = 0.f;
        #pragma unroll
        for (int e = 0; e < 32; ++e)
            s = fmaf(wt[(h * 32 + e) * 129 + o], ctx[(h * 32 + d) * 32 + e], s);
        Mt[(size_t)b * 16384 + j * 128 + o] = s * SCALE;
    }
}

// grid (tile=64, b=16), 256 threads, 32KB LDS; 64 pixels per block.
// buf = x tile during q matvec, then qs (softmaxed q) for the M matvec.
__global__ __launch_bounds__(256) void pass_b_kernel(
    const float* __restrict__ x, const float* __restrict__ Wt,
    const float* __restrict__ beff, const float* __restrict__ Mt,
    const float* __restrict__ b_out, float* __restrict__ out)
{
    __shared__ float buf[8192];          // exactly 32 KB
    const int t = threadIdx.x;
    const int tile = blockIdx.x, b = blockIdx.y;
    const int n = t & 63;
    const int h = __builtin_amdgcn_readfirstlane(t >> 6);  // wave id = head
    const int n0 = tile * 64;
    const float* xb = x + (size_t)b * (128 * 4096);

    #pragma unroll
    for (int i = 0; i < 8; ++i) {
        int idx4 = i * 256 + t;
        int c = idx4 >> 4, q4 = idx4 & 15;
        *(float4*)(&buf[c * 64 + q4 * 4]) =
            *(const float4*)(xb + (size_t)c * 4096 + n0 + q4 * 4);
    }
    __syncthreads();
    // q logits: 32 rows o = h*32+i
    float acc[32];
    const float* Wq = Wt + h * 32;
    const float* bq = beff + h * 32;
    #pragma unroll
    for (int i = 0; i < 32; ++i) acc[i] = bq[i];
    for (int c = 0; c < 128; ++c) {
        float xv = buf[c * 64 + n];
        const float* wr = Wq + c * 128;
        #pragma unroll
        for (int i = 0; i < 32; ++i) acc[i] = fmaf(wr[i], xv, acc[i]);
    }
    // softmax over the 32 head channels (in registers)
    float m = acc[0];
    #pragma unroll
    for (int i = 1; i < 32; ++i) m = fmaxf(m, acc[i]);
    float s = 0.f;
    #pragma unroll
    for (int i = 0; i < 32; ++i) { acc[i] = __expf(acc[i] - m); s += acc[i]; }
    float inv = 1.0f / s;
    __syncthreads();                     // all q-matvec reads of x done
    #pragma unroll
    for (int i = 0; i < 32; ++i) buf[(h * 32 + i) * 64 + n] = acc[i] * inv;
    __syncthreads();
    // out = M_b @ qs (+ b_out)
    float oacc[32];
    const float* Mb = Mt + (size_t)b * 16384 + h * 32;
    const float* bo = b_out + h * 32;
    #pragma unroll
    for (int i = 0; i < 32; ++i) oacc[i] = bo[i];
    for (int j = 0; j < 128; ++j) {
        float qv = buf[j * 64 + n];
        const float* mr = Mb + j * 128;
        #pragma unroll
        for (int i = 0; i < 32; ++i) oacc[i] = fmaf(mr[i], qv, oacc[i]);
    }
    float* ob = out + (size_t)b * (128 * 4096) + n0;
    #pragma unroll
    for (int i = 0; i < 32; ++i) ob[(h * 32 + i) * 4096 + n] = oacc[i];
}

extern "C" void kernel_launch(void* const* d_in, const int* in_sizes, int n_in,
                              void* d_out, int out_size, void* d_ws, size_t ws_size,
                              hipStream_t stream) {
    const float* x     = (const float*)d_in[0];
    const float* w_qkv = (const float*)d_in[1];
    const float* wA_q  = (const float*)d_in[2];
    const float* bA_q  = (const float*)d_in[3];
    const float* wB_q  = (const float*)d_in[4];
    const float* bB_q  = (const float*)d_in[5];
    const float* wA_k  = (const float*)d_in[6];
    const float* bA_k  = (const float*)d_in[7];
    const float* wB_k  = (const float*)d_in[8];
    const float* bB_k  = (const float*)d_in[9];
    const float* wA_v  = (const float*)d_in[10];
    const float* bA_v  = (const float*)d_in[11];
    const float* wB_v  = (const float*)d_in[12];
    const float* bB_v  = (const float*)d_in[13];
    const float* w_out = (const float*)d_in[14];
    const float* b_out = (const float*)d_in[15];
    float* out = (float*)d_out;

    float* ws = (float*)d_ws;
    float* Wt   = ws;                          // 3 * 16384
    float* beff = ws + 49152;                  // 3 * 128
    float* part = ws + 49536;                  // 16*4*16 * 1056 = 1081344
    float* Mt   = ws + 49536 + 1081344;        // 16 * 16384

    fold_kernel<<<192, 256, 0, stream>>>(w_qkv,
        wA_q, bA_q, wB_q, bB_q, wA_k, bA_k, wB_k, bB_k, wA_v, bA_v, wB_v, bB_v,
        Wt, beff);
    ctx_partial_kernel<<<dim3(NCHUNK, 4, 16), 256, 0, stream>>>(x, Wt, beff, part);
    combine_m_kernel<<<16, 256, 0, stream>>>(part, w_out, Mt);
    pass_b_kernel<<<dim3(64, 16), 256, 0, stream>>>(x, Wt, beff, Mt, b_out, out);
}

// Round 10
// 161.986 us; speedup vs baseline: 1.3976x; 1.3976x over previous
//
#include <hip/hip_runtime.h>

// loraLinearAttention on MI355X.
// R9->R10: ctx_partial reverted to R8 body (103us known-good). pass_b
// rewritten as bf16 hi/lo-split MFMA (16x16x32): GEMM1 Wq.x -> in-register
// softmax (shfl_xor over lane-groups) -> GEMM2 M.qs. Wq and M pre-packed in
// MFMA A-fragment order (wfrag kernel / combine epilogue). Error budget:
// hi/lo split => ~1e-5 relative. R9's all-LDS fp32 matvec was LDS-issue
// bound (VALUBusy 28%, 156us) - fp32 vector path abandoned for pass_b.

typedef float f32x4 __attribute__((ext_vector_type(4)));
typedef short bf16x8 __attribute__((ext_vector_type(8)));

#define SCALING 0.25f
#define SCALE   0.17677669529663687f   /* 32^-0.5 */
#define NCHUNK  16

__device__ __forceinline__ unsigned short f2bf_rn(float x) {
    union { float f; unsigned u; } v; v.f = x;
    unsigned r = v.u + 0x7FFFu + ((v.u >> 16) & 1u);
    return (unsigned short)(r >> 16);
}
__device__ __forceinline__ float bf2f(unsigned short h) {
    union { unsigned u; float f; } v; v.u = ((unsigned)h) << 16;
    return v.f;
}
__device__ __forceinline__ void hilo2(float a, float b, unsigned& hi, unsigned& lo) {
    unsigned short ah = f2bf_rn(a), bh = f2bf_rn(b);
    unsigned short al = f2bf_rn(a - bf2f(ah)), bl = f2bf_rn(b - bf2f(bh));
    hi = (unsigned)ah | ((unsigned)bh << 16);
    lo = (unsigned)al | ((unsigned)bl << 16);
}

__global__ __launch_bounds__(256) void fold_kernel(
    const float* __restrict__ w_qkv,
    const float* __restrict__ wA_q, const float* __restrict__ bA_q,
    const float* __restrict__ wB_q, const float* __restrict__ bB_q,
    const float* __restrict__ wA_k, const float* __restrict__ bA_k,
    const float* __restrict__ wB_k, const float* __restrict__ bB_k,
    const float* __restrict__ wA_v, const float* __restrict__ bA_v,
    const float* __restrict__ wB_v, const float* __restrict__ bB_v,
    float* __restrict__ Wt, float* __restrict__ beff)
{
    int idx = blockIdx.x * 256 + threadIdx.x;   // 49152 total
    int m = idx >> 14;
    int c = (idx >> 7) & 127;
    int o = idx & 127;
    const float* wA = (m == 0) ? wA_q : (m == 1) ? wA_k : wA_v;
    const float* wB = (m == 0) ? wB_q : (m == 1) ? wB_k : wB_v;
    float s = w_qkv[(m * 128 + o) * 128 + c];
    #pragma unroll
    for (int r = 0; r < 4; ++r)
        s += SCALING * wB[o * 4 + r] * wA[r * 128 + c];
    Wt[m * 16384 + c * 128 + o] = s;           // transposed [c][o]

    if (blockIdx.x == 0 && threadIdx.x < 384) {
        int mm = threadIdx.x >> 7, oo = threadIdx.x & 127;
        const float* wBm = (mm == 0) ? wB_q : (mm == 1) ? wB_k : wB_v;
        const float* bAm = (mm == 0) ? bA_q : (mm == 1) ? bA_k : bA_v;
        const float* bBm = (mm == 0) ? bB_q : (mm == 1) ? bB_k : bB_v;
        float bb = bBm[oo];
        #pragma unroll
        for (int r = 0; r < 4; ++r) bb += wBm[oo * 4 + r] * bAm[r];
        beff[mm * 128 + oo] = SCALING * bb;
    }
}

// Pack Wq (Wt[0], stored [c][o]) into MFMA A-fragment order, bf16 hi/lo.
// Fragment: element (o,c): rt=o>>4, ks=c>>5, lane=(o&15)+16*((c>>3)&3),
// i=c&7; u32-pair index fp = (((rt*4+ks)*64+lane)*8+i)/2. grid 32x256.
__global__ __launch_bounds__(256) void wfrag_kernel(
    const float* __restrict__ Wt, unsigned* __restrict__ whi,
    unsigned* __restrict__ wlo)
{
    int fp = blockIdx.x * 256 + threadIdx.x;   // 8192 pairs
    int f = fp * 2;
    int i = f & 7;
    int l = (f >> 3) & 63;
    int rtks = f >> 9;
    int rt = rtks >> 2, ks = rtks & 3;
    int o = rt * 16 + (l & 15);
    int c = ks * 32 + (l >> 4) * 8 + i;
    float a = Wt[c * 128 + o];
    float b = Wt[(c + 1) * 128 + o];
    unsigned hi, lo;
    hilo2(a, b, hi, lo);
    whi[fp] = hi; wlo[fp] = lo;
}

// grid (chunk=16, h=4, b=16), 256 threads — R8 body verbatim (103us).
__global__ __launch_bounds__(256) void ctx_partial_kernel(
    const float* __restrict__ x, const float* __restrict__ Wt,
    const float* __restrict__ beff, float* __restrict__ part)
{
    __shared__ float x_t[64 * 64];       // one c-half of the x tile (16 KB)
    __shared__ float kv_t[2][32 * 65];   // pitch 65: column reads conflict-free
    __shared__ float lsum[8][32];
    const int t = threadIdx.x;
    const int chunk = blockIdx.x, h = blockIdx.y, b = blockIdx.z;
    const int n = t & 63;
    const int og = __builtin_amdgcn_readfirstlane(t >> 6);  // wave id 0..3
    const int is_v = og >> 1;            // waves 0,1 -> k; 2,3 -> v
    const int r0 = (og & 1) * 16;
    const float* Wm = Wt + (1 + is_v) * 16384 + h * 32 + r0;
    const float* bm = beff + (1 + is_v) * 128 + h * 32 + r0;
    const float* xb = x + (size_t)b * (128 * 4096);
    const int d = t & 31;                // row for exp/ctx phases
    const int g = t >> 5;                // 0..7

    float cacc[4] = {0.f, 0.f, 0.f, 0.f};
    float lpart = 0.f;

    #pragma unroll 1
    for (int tt = 0; tt < 4; ++tt) {
        const int n0 = chunk * 256 + tt * 64;
        float acc[16];
        #pragma unroll
        for (int i = 0; i < 16; ++i) acc[i] = bm[i];
        #pragma unroll 1
        for (int ch = 0; ch < 2; ++ch) {
            __syncthreads();
            #pragma unroll
            for (int i = 0; i < 4; ++i) {   // x half-tile [64][64] as float4
                int idx4 = i * 256 + t;
                int c = idx4 >> 4, q4 = idx4 & 15;
                float4 v = *(const float4*)(xb + (size_t)(ch * 64 + c) * 4096
                                            + n0 + q4 * 4);
                *(float4*)(&x_t[c * 64 + q4 * 4]) = v;
            }
            __syncthreads();
            const float* Wc = Wm + (ch * 64) * 128;
            for (int c = 0; c < 64; ++c) {
                float xv = x_t[c * 64 + n];
                const float* wr = Wc + c * 128;
                #pragma unroll
                for (int i = 0; i < 16; ++i) acc[i] = fmaf(wr[i], xv, acc[i]);
            }
        }
        __syncthreads();
        #pragma unroll
        for (int i = 0; i < 16; ++i) kv_t[is_v][(r0 + i) * 65 + n] = acc[i];
        __syncthreads();
        float lp = 0.f;
        #pragma unroll
        for (int j = 0; j < 8; ++j) {
            int nn = g * 8 + j;
            float p = __expf(kv_t[0][d * 65 + nn]);
            kv_t[0][d * 65 + nn] = p;
            lp += p;
        }
        lpart += lp;
        __syncthreads();
        for (int nn = 0; nn < 64; ++nn) {
            float p = kv_t[0][d * 65 + nn];
            #pragma unroll
            for (int j = 0; j < 4; ++j)
                cacc[j] = fmaf(p, kv_t[1][(g * 4 + j) * 65 + nn], cacc[j]);
        }
    }
    lsum[g][d] = lpart;
    __syncthreads();
    float* pout = part + (size_t)((b * 4 + h) * NCHUNK + chunk) * 1056;
    if (t < 32) {
        float l = 0.f;
        #pragma unroll
        for (int gg = 0; gg < 8; ++gg) l += lsum[gg][t];
        pout[1024 + t] = l;
    }
    #pragma unroll
    for (int j = 0; j < 4; ++j) pout[d * 32 + g * 4 + j] = cacc[j];
}

// grid (16 = batch), 256 threads. Emits M_b in A-fragment order, bf16 hi/lo.
__global__ __launch_bounds__(256) void combine_m_kernel(
    const float* __restrict__ part, const float* __restrict__ w_out,
    unsigned* __restrict__ mhi, unsigned* __restrict__ mlo)
{
    __shared__ float ctx[4096];        // [h][d][e]
    __shared__ float linv[128];
    __shared__ float wt[128 * 129];    // w_out^T, padded
    const int t = threadIdx.x;
    const int b = blockIdx.x;
    const float* pb = part + (size_t)b * 4 * NCHUNK * 1056;

    if (t < 128) {
        int h = t >> 5, d = t & 31;
        float l = 0.f;
        for (int ch = 0; ch < NCHUNK; ++ch)
            l += pb[(h * NCHUNK + ch) * 1056 + 1024 + d];
        linv[t] = 1.0f / (l * 4096.0f);   // folds the v/n division
    }
    for (int i = 0; i < 64; ++i) {        // stage w_out transposed
        int idx = i * 256 + t;
        int o = idx >> 7, c = idx & 127;
        wt[c * 129 + o] = w_out[idx];
    }
    __syncthreads();
    for (int i = 0; i < 16; ++i) {        // context = sum(partials) * linv
        int idx = i * 256 + t;
        int h = idx >> 10, d = (idx >> 5) & 31, e = idx & 31;
        float s = 0.f;
        for (int ch = 0; ch < NCHUNK; ++ch)
            s += pb[(h * NCHUNK + ch) * 1056 + d * 32 + e];
        ctx[idx] = s * linv[h * 32 + d];
    }
    __syncthreads();
    // M[o][j] = SCALE * sum_e wt[(hj*32+e)][o] * ctx[hj][dj][e], j=hj*32+dj.
    // Written in A-fragment order (coalesced u32 pair stores).
    for (int it = 0; it < 32; ++it) {
        int fp = it * 256 + t;            // 8192 pairs per batch
        int f = fp * 2;
        int i = f & 7;
        int l = (f >> 3) & 63;
        int rtks = f >> 9;
        int rt = rtks >> 2, ks = rtks & 3;
        int o = rt * 16 + (l & 15);
        int j0 = ks * 32 + (l >> 4) * 8 + i;
        float v01[2];
        #pragma unroll
        for (int jj = 0; jj < 2; ++jj) {
            int j = j0 + jj;
            int h = j >> 5, d = j & 31;
            float s = 0.f;
            #pragma unroll
            for (int e = 0; e < 32; ++e)
                s = fmaf(wt[(h * 32 + e) * 129 + o], ctx[h * 1024 + d * 32 + e], s);
            v01[jj] = s * SCALE;
        }
        unsigned hi, lo;
        hilo2(v01[0], v01[1], hi, lo);
        mhi[(size_t)b * 8192 + fp] = hi;
        mlo[(size_t)b * 8192 + fp] = lo;
    }
}

// grid (tile=64, b=16), 256 threads, ~33KB LDS; 64 pixels per block.
// MFMA pipeline: stage x->bf16 hi/lo B-frags; GEMM1 Wq.x; softmax in regs;
// qs->B-frags (alias xs); GEMM2 M.qs; store + b_out.
__global__ __launch_bounds__(256) void pass_b_kernel(
    const float* __restrict__ x,
    const uint4* __restrict__ wqhi, const uint4* __restrict__ wqlo,
    const float* __restrict__ beff,
    const unsigned* __restrict__ mhi, const unsigned* __restrict__ mlo,
    const float* __restrict__ b_out, float* __restrict__ out)
{
    __shared__ uint4 xs_hi[1024];        // [(ks*4+kb)*64 + px] : 16 KB
    __shared__ uint4 xs_lo[1024];
    __shared__ float bias_q[128];
    __shared__ float bias_o[128];
    const int t = threadIdx.x;
    const int tile = blockIdx.x, b = blockIdx.y;
    const int lane = t & 63;
    const int w = __builtin_amdgcn_readfirstlane(t >> 6);  // wave id = head
    const int n0 = tile * 64;
    const float* xb = x + (size_t)b * (128 * 4096);

    if (t < 128) { bias_q[t] = beff[t]; bias_o[t] = b_out[t]; }

    // stage: wave w, pass p loads channels c=(p*4+w)*8..+7 for its 64 pixels,
    // converts to bf16 hi/lo, writes one b128 per buffer (frag layout).
    #pragma unroll
    for (int p = 0; p < 4; ++p) {
        float v[8];
        #pragma unroll
        for (int j = 0; j < 8; ++j)
            v[j] = xb[(size_t)((p * 4 + w) * 8 + j) * 4096 + n0 + lane];
        unsigned hw[4], lw[4];
        #pragma unroll
        for (int q = 0; q < 4; ++q) hilo2(v[2 * q], v[2 * q + 1], hw[q], lw[q]);
        xs_hi[(p * 4 + w) * 64 + lane] = make_uint4(hw[0], hw[1], hw[2], hw[3]);
        xs_lo[(p * 4 + w) * 64 + lane] = make_uint4(lw[0], lw[1], lw[2], lw[3]);
    }
    __syncthreads();

    const int lg = lane >> 4;            // k-block group 0..3
    const int l15 = lane & 15;

    // GEMM1: q[rows 32w..+32][64px], acc[rt][nt]
    f32x4 acc[2][4];
    #pragma unroll
    for (int rt = 0; rt < 2; ++rt)
        #pragma unroll
        for (int nt = 0; nt < 4; ++nt)
            acc[rt][nt] = (f32x4){0.f, 0.f, 0.f, 0.f};
    #pragma unroll
    for (int ks = 0; ks < 4; ++ks) {
        bf16x8 bh[4], bl[4];
        #pragma unroll
        for (int nt = 0; nt < 4; ++nt) {
            bh[nt] = __builtin_bit_cast(bf16x8, xs_hi[(ks * 4 + lg) * 64 + nt * 16 + l15]);
            bl[nt] = __builtin_bit_cast(bf16x8, xs_lo[(ks * 4 + lg) * 64 + nt * 16 + l15]);
        }
        #pragma unroll
        for (int rt = 0; rt < 2; ++rt) {
            int rg = 2 * w + rt;
            bf16x8 ah = __builtin_bit_cast(bf16x8, wqhi[(rg * 4 + ks) * 64 + lane]);
            bf16x8 al = __builtin_bit_cast(bf16x8, wqlo[(rg * 4 + ks) * 64 + lane]);
            #pragma unroll
            for (int nt = 0; nt < 4; ++nt) {
                acc[rt][nt] = __builtin_amdgcn_mfma_f32_16x16x32_bf16(ah, bh[nt], acc[rt][nt], 0, 0, 0);
                acc[rt][nt] = __builtin_amdgcn_mfma_f32_16x16x32_bf16(ah, bl[nt], acc[rt][nt], 0, 0, 0);
                acc[rt][nt] = __builtin_amdgcn_mfma_f32_16x16x32_bf16(al, bh[nt], acc[rt][nt], 0, 0, 0);
            }
        }
    }

    // bias + per-pixel softmax over the head's 32 channels.
    // lane holds channels ch = w*32 + rt*16 + lg*4 + r for pixel nt*16+l15.
    float bq[2][4];
    #pragma unroll
    for (int rt = 0; rt < 2; ++rt)
        #pragma unroll
        for (int r = 0; r < 4; ++r)
            bq[rt][r] = bias_q[w * 32 + rt * 16 + lg * 4 + r];
    #pragma unroll
    for (int nt = 0; nt < 4; ++nt) {
        float m = -1e30f;
        #pragma unroll
        for (int rt = 0; rt < 2; ++rt)
            #pragma unroll
            for (int r = 0; r < 4; ++r) {
                float q = acc[rt][nt][r] + bq[rt][r];
                acc[rt][nt][r] = q;
                m = fmaxf(m, q);
            }
        m = fmaxf(m, __shfl_xor(m, 16));
        m = fmaxf(m, __shfl_xor(m, 32));
        float s = 0.f;
        #pragma unroll
        for (int rt = 0; rt < 2; ++rt)
            #pragma unroll
            for (int r = 0; r < 4; ++r) {
                float e = __expf(acc[rt][nt][r] - m);
                acc[rt][nt][r] = e;
                s += e;
            }
        s += __shfl_xor(s, 16);
        s += __shfl_xor(s, 32);
        float inv = 1.0f / s;
        #pragma unroll
        for (int rt = 0; rt < 2; ++rt)
            #pragma unroll
            for (int r = 0; r < 4; ++r)
                acc[rt][nt][r] *= inv;
    }

    __syncthreads();                     // GEMM1 reads of xs done everywhere
    // write qs into xs (aliased) in B-fragment layout, bf16 hi/lo, b64 each.
    {
        uint2* qh = (uint2*)xs_hi;
        uint2* ql = (uint2*)xs_lo;
        int half = (lg & 1);             // i base = half*4
        #pragma unroll
        for (int rt = 0; rt < 2; ++rt) {
            int kb = rt * 2 + (lg >> 1);
            #pragma unroll
            for (int nt = 0; nt < 4; ++nt) {
                unsigned h0, l0, h1, l1;
                hilo2(acc[rt][nt][0], acc[rt][nt][1], h0, l0);
                hilo2(acc[rt][nt][2], acc[rt][nt][3], h1, l1);
                int idx = ((w * 4 + kb) * 64 + nt * 16 + l15) * 2 + half;
                qh[idx] = make_uint2(h0, h1);
                ql[idx] = make_uint2(l0, l1);
            }
        }
    }
    __syncthreads();

    // GEMM2: out[rows 32w..+32] = M.qs
    f32x4 acc2[2][4];
    #pragma unroll
    for (int rt = 0; rt < 2; ++rt)
        #pragma unroll
        for (int nt = 0; nt < 4; ++nt)
            acc2[rt][nt] = (f32x4){0.f, 0.f, 0.f, 0.f};
    const uint4* mh4 = (const uint4*)(mhi + (size_t)b * 8192);
    const uint4* ml4 = (const uint4*)(mlo + (size_t)b * 8192);
    #pragma unroll
    for (int ks = 0; ks < 4; ++ks) {
        bf16x8 bh[4], bl[4];
        #pragma unroll
        for (int nt = 0; nt < 4; ++nt) {
            bh[nt] = __builtin_bit_cast(bf16x8, xs_hi[(ks * 4 + lg) * 64 + nt * 16 + l15]);
            bl[nt] = __builtin_bit_cast(bf16x8, xs_lo[(ks * 4 + lg) * 64 + nt * 16 + l15]);
        }
        #pragma unroll
        for (int rt = 0; rt < 2; ++rt) {
            int rg = 2 * w + rt;
            bf16x8 ah = __builtin_bit_cast(bf16x8, mh4[(rg * 4 + ks) * 64 + lane]);
            bf16x8 al = __builtin_bit_cast(bf16x8, ml4[(rg * 4 + ks) * 64 + lane]);
            #pragma unroll
            for (int nt = 0; nt < 4; ++nt) {
                acc2[rt][nt] = __builtin_amdgcn_mfma_f32_16x16x32_bf16(ah, bh[nt], acc2[rt][nt], 0, 0, 0);
                acc2[rt][nt] = __builtin_amdgcn_mfma_f32_16x16x32_bf16(ah, bl[nt], acc2[rt][nt], 0, 0, 0);
                acc2[rt][nt] = __builtin_amdgcn_mfma_f32_16x16x32_bf16(al, bh[nt], acc2[rt][nt], 0, 0, 0);
            }
        }
    }
    // epilogue: + b_out, store. D: row=(lg)*4+r (+rt*16), col=nt*16+l15.
    float* ob = out + (size_t)b * (128 * 4096) + n0;
    #pragma unroll
    for (int rt = 0; rt < 2; ++rt)
        #pragma unroll
        for (int r = 0; r < 4; ++r) {
            int ch = w * 32 + rt * 16 + lg * 4 + r;
            float bo = bias_o[ch];
            #pragma unroll
            for (int nt = 0; nt < 4; ++nt)
                ob[(size_t)ch * 4096 + nt * 16 + l15] = acc2[rt][nt][r] + bo;
        }
}

extern "C" void kernel_launch(void* const* d_in, const int* in_sizes, int n_in,
                              void* d_out, int out_size, void* d_ws, size_t ws_size,
                              hipStream_t stream) {
    const float* x     = (const float*)d_in[0];
    const float* w_qkv = (const float*)d_in[1];
    const float* wA_q  = (const float*)d_in[2];
    const float* bA_q  = (const float*)d_in[3];
    const float* wB_q  = (const float*)d_in[4];
    const float* bB_q  = (const float*)d_in[5];
    const float* wA_k  = (const float*)d_in[6];
    const float* bA_k  = (const float*)d_in[7];
    const float* wB_k  = (const float*)d_in[8];
    const float* bB_k  = (const float*)d_in[9];
    const float* wA_v  = (const float*)d_in[10];
    const float* bA_v  = (const float*)d_in[11];
    const float* wB_v  = (const float*)d_in[12];
    const float* bB_v  = (const float*)d_in[13];
    const float* w_out = (const float*)d_in[14];
    const float* b_out = (const float*)d_in[15];
    float* out = (float*)d_out;

    float* ws = (float*)d_ws;
    float*    Wt   = ws;                            // 49152 f
    float*    beff = ws + 49152;                    // 384 f
    float*    part = ws + 49536;                    // 1081344 f
    unsigned* wqhi = (unsigned*)(ws + 1130880);     // 8192 u32
    unsigned* wqlo = (unsigned*)(ws + 1139072);     // 8192 u32
    unsigned* mhi  = (unsigned*)(ws + 1147264);     // 16*8192 u32
    unsigned* mlo  = (unsigned*)(ws + 1278336);     // 16*8192 u32

    fold_kernel<<<192, 256, 0, stream>>>(w_qkv,
        wA_q, bA_q, wB_q, bB_q, wA_k, bA_k, wB_k, bB_k, wA_v, bA_v, wB_v, bB_v,
        Wt, beff);
    wfrag_kernel<<<32, 256, 0, stream>>>(Wt, wqhi, wqlo);
    ctx_partial_kernel<<<dim3(NCHUNK, 4, 16), 256, 0, stream>>>(x, Wt, beff, part);
    combine_m_kernel<<<16, 256, 0, stream>>>(part, w_out, mhi, mlo);
    pass_b_kernel<<<dim3(64, 16), 256, 0, stream>>>(x,
        (const uint4*)wqhi, (const uint4*)wqlo, beff, mhi, mlo, b_out, out);
}

// Round 11
// 105.806 us; speedup vs baseline: 2.1397x; 1.5310x over previous
//
#include <hip/hip_runtime.h>

// loraLinearAttention on MI355X.
// R10->R11: ctx ported to MFMA (was 103us fp32 VALU-bound = 64% of total).
// ctx = P.V^T per (b,h) with P = exp(Wk.x+bk), V = Wv.x+bv: GEMM1 (A-frags
// of W from extended wfrag pack, B-frags of x hi/lo) -> bias+exp in regs ->
// P,V to LDS [row][px] pitch-72 bf16 hi/lo -> ctx GEMM P.V^T + l via
// ones-MFMA. All fragment machinery is the R10-validated pass_b pattern.
// pass_b/combine/fold unchanged (pass_b reads q region of the same wall pack).

typedef float f32x4 __attribute__((ext_vector_type(4)));
typedef short bf16x8 __attribute__((ext_vector_type(8)));

#define SCALING 0.25f
#define SCALE   0.17677669529663687f   /* 32^-0.5 */
#define NCHUNK  32                     /* 128-px chunks per (b,h) */

__device__ __forceinline__ unsigned short f2bf_rn(float x) {
    union { float f; unsigned u; } v; v.f = x;
    unsigned r = v.u + 0x7FFFu + ((v.u >> 16) & 1u);
    return (unsigned short)(r >> 16);
}
__device__ __forceinline__ float bf2f(unsigned short h) {
    union { unsigned u; float f; } v; v.u = ((unsigned)h) << 16;
    return v.f;
}
__device__ __forceinline__ void hilo2(float a, float b, unsigned& hi, unsigned& lo) {
    unsigned short ah = f2bf_rn(a), bh = f2bf_rn(b);
    unsigned short al = f2bf_rn(a - bf2f(ah)), bl = f2bf_rn(b - bf2f(bh));
    hi = (unsigned)ah | ((unsigned)bh << 16);
    lo = (unsigned)al | ((unsigned)bl << 16);
}

__global__ __launch_bounds__(256) void fold_kernel(
    const float* __restrict__ w_qkv,
    const float* __restrict__ wA_q, const float* __restrict__ bA_q,
    const float* __restrict__ wB_q, const float* __restrict__ bB_q,
    const float* __restrict__ wA_k, const float* __restrict__ bA_k,
    const float* __restrict__ wB_k, const float* __restrict__ bB_k,
    const float* __restrict__ wA_v, const float* __restrict__ bA_v,
    const float* __restrict__ wB_v, const float* __restrict__ bB_v,
    float* __restrict__ Wt, float* __restrict__ beff)
{
    int idx = blockIdx.x * 256 + threadIdx.x;   // 49152 total
    int m = idx >> 14;
    int c = (idx >> 7) & 127;
    int o = idx & 127;
    const float* wA = (m == 0) ? wA_q : (m == 1) ? wA_k : wA_v;
    const float* wB = (m == 0) ? wB_q : (m == 1) ? wB_k : wB_v;
    float s = w_qkv[(m * 128 + o) * 128 + c];
    #pragma unroll
    for (int r = 0; r < 4; ++r)
        s += SCALING * wB[o * 4 + r] * wA[r * 128 + c];
    Wt[m * 16384 + c * 128 + o] = s;           // transposed [c][o]

    if (blockIdx.x == 0 && threadIdx.x < 384) {
        int mm = threadIdx.x >> 7, oo = threadIdx.x & 127;
        const float* wBm = (mm == 0) ? wB_q : (mm == 1) ? wB_k : wB_v;
        const float* bAm = (mm == 0) ? bA_q : (mm == 1) ? bA_k : bA_v;
        const float* bBm = (mm == 0) ? bB_q : (mm == 1) ? bB_k : bB_v;
        float bb = bBm[oo];
        #pragma unroll
        for (int r = 0; r < 4; ++r) bb += wBm[oo * 4 + r] * bAm[r];
        beff[mm * 128 + oo] = SCALING * bb;
    }
}

// Pack ALL of [Wq;Wk;Wv] (384 rows x 128c, from Wt [m][c][o]) into MFMA
// A-fragment order, bf16 hi/lo. rt = global_row>>4 (0..23), element (o,c):
// lane=(o&15)+16*((c>>3)&3), i=c&7; pair index fp = (((rt*4+ks)*64+l)*8+i)/2.
__global__ __launch_bounds__(256) void wfrag_kernel(
    const float* __restrict__ Wt, unsigned* __restrict__ whi,
    unsigned* __restrict__ wlo)
{
    int fp = blockIdx.x * 256 + threadIdx.x;   // 24576 pairs
    int f = fp * 2;
    int i = f & 7;
    int l = (f >> 3) & 63;
    int rtks = f >> 9;
    int rt = rtks >> 2, ks = rtks & 3;
    int og = rt * 16 + (l & 15);               // global row 0..383
    int c = ks * 32 + ((l >> 4) & 3) * 8 + i;
    int m = og >> 7, o = og & 127;
    float a = Wt[m * 16384 + c * 128 + o];
    float b = Wt[m * 16384 + (c + 1) * 128 + o];
    unsigned hi, lo;
    hilo2(a, b, hi, lo);
    whi[fp] = hi; wlo[fp] = lo;
}

// grid (chunk=32, b=16) = 512 blocks, 256 threads, 73.7KB LDS (2 blocks/CU).
// Per block: 128 px in 2 tiles of 64. Phase 1: x staged as hi/lo B-frags
// (aliased in kv region). GEMM1: wave w -> kv rows 64w..+63 (A-frags rg
// 8+4w+rt of wall). exp(K+bias) in regs; kv -> LDS [row][px] pitch 72 bf16
// hi/lo. Phase 2: wave h -> ctx_h += P_h.V_h^T (hi/lo 3-MFMA) + l (ones-B).
__global__ __launch_bounds__(256) void ctx_mfma_kernel(
    const float* __restrict__ x,
    const uint4* __restrict__ whi, const uint4* __restrict__ wlo,
    const float* __restrict__ beff, float* __restrict__ part)
{
    __shared__ __align__(16) char smem[73728];   // kv: 2 x 256*72 bf16
    uint4* xs_hi = (uint4*)smem;                 // first 16 KB (dead at GEMM1 end)
    uint4* xs_lo = (uint4*)(smem + 16384);       // next 16 KB
    unsigned short* kv_hi = (unsigned short*)smem;          // [row*72+px]
    unsigned short* kv_lo = (unsigned short*)(smem + 36864);
    const int t = threadIdx.x;
    const int lane = t & 63;
    const int w = __builtin_amdgcn_readfirstlane(t >> 6);
    const int chunk = blockIdx.x, b = blockIdx.y;
    const int lg = lane >> 4, l15 = lane & 15;
    const float* xb = x + (size_t)b * (128 * 4096);

    float bias[4][4];                    // kv rows 64w+16rt+lg*4+r
    #pragma unroll
    for (int rt = 0; rt < 4; ++rt)
        #pragma unroll
        for (int r = 0; r < 4; ++r)
            bias[rt][r] = beff[128 + 64 * w + 16 * rt + lg * 4 + r];

    bf16x8 ones;
    #pragma unroll
    for (int i = 0; i < 8; ++i) ones[i] = (short)0x3F80;

    f32x4 ctx_acc[2][2];
    f32x4 l_acc[2];
    #pragma unroll
    for (int rt = 0; rt < 2; ++rt) {
        l_acc[rt] = (f32x4){0.f, 0.f, 0.f, 0.f};
        #pragma unroll
        for (int et = 0; et < 2; ++et)
            ctx_acc[rt][et] = (f32x4){0.f, 0.f, 0.f, 0.f};
    }

    #pragma unroll 1
    for (int tt = 0; tt < 2; ++tt) {
        const int n0 = chunk * 128 + tt * 64;
        __syncthreads();                 // prev-tile ctx reads of kv done
        #pragma unroll
        for (int p = 0; p < 4; ++p) {    // stage x frags (32 channels/wave)
            float v[8];
            #pragma unroll
            for (int j = 0; j < 8; ++j)
                v[j] = xb[(size_t)((p * 4 + w) * 8 + j) * 4096 + n0 + lane];
            unsigned hw[4], lw[4];
            #pragma unroll
            for (int q = 0; q < 4; ++q) hilo2(v[2*q], v[2*q+1], hw[q], lw[q]);
            xs_hi[(p * 4 + w) * 64 + lane] = make_uint4(hw[0], hw[1], hw[2], hw[3]);
            xs_lo[(p * 4 + w) * 64 + lane] = make_uint4(lw[0], lw[1], lw[2], lw[3]);
        }
        __syncthreads();
        // GEMM1: kv rows 64w..+63 x 64 px
        f32x4 acc1[4][4];
        #pragma unroll
        for (int rt = 0; rt < 4; ++rt)
            #pragma unroll
            for (int nt = 0; nt < 4; ++nt)
                acc1[rt][nt] = (f32x4){0.f, 0.f, 0.f, 0.f};
        #pragma unroll
        for (int ks = 0; ks < 4; ++ks) {
            bf16x8 bh[4], bl[4];
            #pragma unroll
            for (int nt = 0; nt < 4; ++nt) {
                bh[nt] = __builtin_bit_cast(bf16x8, xs_hi[(ks * 4 + lg) * 64 + nt * 16 + l15]);
                bl[nt] = __builtin_bit_cast(bf16x8, xs_lo[(ks * 4 + lg) * 64 + nt * 16 + l15]);
            }
            #pragma unroll
            for (int rt = 0; rt < 4; ++rt) {
                int rg = 8 + 4 * w + rt;
                bf16x8 ah = __builtin_bit_cast(bf16x8, whi[(rg * 4 + ks) * 64 + lane]);
                bf16x8 al = __builtin_bit_cast(bf16x8, wlo[(rg * 4 + ks) * 64 + lane]);
                #pragma unroll
                for (int nt = 0; nt < 4; ++nt) {
                    acc1[rt][nt] = __builtin_amdgcn_mfma_f32_16x16x32_bf16(ah, bh[nt], acc1[rt][nt], 0, 0, 0);
                    acc1[rt][nt] = __builtin_amdgcn_mfma_f32_16x16x32_bf16(ah, bl[nt], acc1[rt][nt], 0, 0, 0);
                    acc1[rt][nt] = __builtin_amdgcn_mfma_f32_16x16x32_bf16(al, bh[nt], acc1[rt][nt], 0, 0, 0);
                }
            }
        }
        __syncthreads();                 // all x-frag reads done (kv overwrites)
        // bias (+exp for K waves), write kv rows to LDS pitch-72 bf16 hi/lo
        #pragma unroll
        for (int rt = 0; rt < 4; ++rt)
            #pragma unroll
            for (int nt = 0; nt < 4; ++nt)
                #pragma unroll
                for (int r = 0; r < 4; ++r) {
                    float vv = acc1[rt][nt][r] + bias[rt][r];
                    if (w < 2) vv = __expf(vv);
                    int row = 64 * w + 16 * rt + lg * 4 + r;
                    int px = nt * 16 + l15;
                    unsigned short hi = f2bf_rn(vv);
                    unsigned short lo = f2bf_rn(vv - bf2f(hi));
                    kv_hi[row * 72 + px] = hi;
                    kv_lo[row * 72 + px] = lo;
                }
        __syncthreads();
        // ctx phase: wave w handles head w
        #pragma unroll
        for (int ks2 = 0; ks2 < 2; ++ks2) {
            int pxb = ks2 * 32 + lg * 8;
            bf16x8 ph[2], pl[2], vh[2], vl[2];
            #pragma unroll
            for (int rt = 0; rt < 2; ++rt) {
                int prow = 32 * w + 16 * rt + l15;
                ph[rt] = __builtin_bit_cast(bf16x8, *(const uint4*)&kv_hi[prow * 72 + pxb]);
                pl[rt] = __builtin_bit_cast(bf16x8, *(const uint4*)&kv_lo[prow * 72 + pxb]);
            }
            #pragma unroll
            for (int et = 0; et < 2; ++et) {
                int vrow = 128 + 32 * w + 16 * et + l15;
                vh[et] = __builtin_bit_cast(bf16x8, *(const uint4*)&kv_hi[vrow * 72 + pxb]);
                vl[et] = __builtin_bit_cast(bf16x8, *(const uint4*)&kv_lo[vrow * 72 + pxb]);
            }
            #pragma unroll
            for (int rt = 0; rt < 2; ++rt) {
                #pragma unroll
                for (int et = 0; et < 2; ++et) {
                    ctx_acc[rt][et] = __builtin_amdgcn_mfma_f32_16x16x32_bf16(ph[rt], vh[et], ctx_acc[rt][et], 0, 0, 0);
                    ctx_acc[rt][et] = __builtin_amdgcn_mfma_f32_16x16x32_bf16(ph[rt], vl[et], ctx_acc[rt][et], 0, 0, 0);
                    ctx_acc[rt][et] = __builtin_amdgcn_mfma_f32_16x16x32_bf16(pl[rt], vh[et], ctx_acc[rt][et], 0, 0, 0);
                }
                l_acc[rt] = __builtin_amdgcn_mfma_f32_16x16x32_bf16(ph[rt], ones, l_acc[rt], 0, 0, 0);
                l_acc[rt] = __builtin_amdgcn_mfma_f32_16x16x32_bf16(pl[rt], ones, l_acc[rt], 0, 0, 0);
            }
        }
    }
    // write partials: ctx[d][e] + l
    float* pout = part + (size_t)((b * 4 + w) * NCHUNK + chunk) * 1056;
    #pragma unroll
    for (int rt = 0; rt < 2; ++rt) {
        #pragma unroll
        for (int et = 0; et < 2; ++et)
            #pragma unroll
            for (int r = 0; r < 4; ++r)
                pout[(16 * rt + lg * 4 + r) * 32 + 16 * et + l15] = ctx_acc[rt][et][r];
        if (l15 == 0)
            #pragma unroll
            for (int r = 0; r < 4; ++r)
                pout[1024 + 16 * rt + lg * 4 + r] = l_acc[rt][r];
    }
}

// grid (16 = batch), 256 threads. Emits M_b in A-fragment order, bf16 hi/lo.
__global__ __launch_bounds__(256) void combine_m_kernel(
    const float* __restrict__ part, const float* __restrict__ w_out,
    unsigned* __restrict__ mhi, unsigned* __restrict__ mlo)
{
    __shared__ float ctx[4096];        // [h][d][e]
    __shared__ float linv[128];
    __shared__ float wt[128 * 129];    // w_out^T, padded
    const int t = threadIdx.x;
    const int b = blockIdx.x;
    const float* pb = part + (size_t)b * 4 * NCHUNK * 1056;

    if (t < 128) {
        int h = t >> 5, d = t & 31;
        float l = 0.f;
        for (int ch = 0; ch < NCHUNK; ++ch)
            l += pb[(h * NCHUNK + ch) * 1056 + 1024 + d];
        linv[t] = 1.0f / (l * 4096.0f);   // folds the v/n division
    }
    for (int i = 0; i < 64; ++i) {        // stage w_out transposed
        int idx = i * 256 + t;
        int o = idx >> 7, c = idx & 127;
        wt[c * 129 + o] = w_out[idx];
    }
    __syncthreads();
    for (int i = 0; i < 16; ++i) {        // context = sum(partials) * linv
        int idx = i * 256 + t;
        int h = idx >> 10, d = (idx >> 5) & 31, e = idx & 31;
        float s = 0.f;
        for (int ch = 0; ch < NCHUNK; ++ch)
            s += pb[(h * NCHUNK + ch) * 1056 + d * 32 + e];
        ctx[idx] = s * linv[h * 32 + d];
    }
    __syncthreads();
    // M[o][j] = SCALE * sum_e wt[(hj*32+e)][o] * ctx[hj][dj][e], j=hj*32+dj.
    for (int it = 0; it < 32; ++it) {
        int fp = it * 256 + t;            // 8192 pairs per batch
        int f = fp * 2;
        int i = f & 7;
        int l = (f >> 3) & 63;
        int rtks = f >> 9;
        int rt = rtks >> 2, ks = rtks & 3;
        int o = rt * 16 + (l & 15);
        int j0 = ks * 32 + (l >> 4) * 8 + i;
        float v01[2];
        #pragma unroll
        for (int jj = 0; jj < 2; ++jj) {
            int j = j0 + jj;
            int h = j >> 5, d = j & 31;
            float s = 0.f;
            #pragma unroll
            for (int e = 0; e < 32; ++e)
                s = fmaf(wt[(h * 32 + e) * 129 + o], ctx[h * 1024 + d * 32 + e], s);
            v01[jj] = s * SCALE;
        }
        unsigned hi, lo;
        hilo2(v01[0], v01[1], hi, lo);
        mhi[(size_t)b * 8192 + fp] = hi;
        mlo[(size_t)b * 8192 + fp] = lo;
    }
}

// grid (tile=64, b=16), 256 threads — unchanged from R10 (validated).
__global__ __launch_bounds__(256) void pass_b_kernel(
    const float* __restrict__ x,
    const uint4* __restrict__ wqhi, const uint4* __restrict__ wqlo,
    const float* __restrict__ beff,
    const unsigned* __restrict__ mhi, const unsigned* __restrict__ mlo,
    const float* __restrict__ b_out, float* __restrict__ out)
{
    __shared__ uint4 xs_hi[1024];
    __shared__ uint4 xs_lo[1024];
    __shared__ float bias_q[128];
    __shared__ float bias_o[128];
    const int t = threadIdx.x;
    const int tile = blockIdx.x, b = blockIdx.y;
    const int lane = t & 63;
    const int w = __builtin_amdgcn_readfirstlane(t >> 6);
    const int n0 = tile * 64;
    const float* xb = x + (size_t)b * (128 * 4096);

    if (t < 128) { bias_q[t] = beff[t]; bias_o[t] = b_out[t]; }

    #pragma unroll
    for (int p = 0; p < 4; ++p) {
        float v[8];
        #pragma unroll
        for (int j = 0; j < 8; ++j)
            v[j] = xb[(size_t)((p * 4 + w) * 8 + j) * 4096 + n0 + lane];
        unsigned hw[4], lw[4];
        #pragma unroll
        for (int q = 0; q < 4; ++q) hilo2(v[2 * q], v[2 * q + 1], hw[q], lw[q]);
        xs_hi[(p * 4 + w) * 64 + lane] = make_uint4(hw[0], hw[1], hw[2], hw[3]);
        xs_lo[(p * 4 + w) * 64 + lane] = make_uint4(lw[0], lw[1], lw[2], lw[3]);
    }
    __syncthreads();

    const int lg = lane >> 4;
    const int l15 = lane & 15;

    f32x4 acc[2][4];
    #pragma unroll
    for (int rt = 0; rt < 2; ++rt)
        #pragma unroll
        for (int nt = 0; nt < 4; ++nt)
            acc[rt][nt] = (f32x4){0.f, 0.f, 0.f, 0.f};
    #pragma unroll
    for (int ks = 0; ks < 4; ++ks) {
        bf16x8 bh[4], bl[4];
        #pragma unroll
        for (int nt = 0; nt < 4; ++nt) {
            bh[nt] = __builtin_bit_cast(bf16x8, xs_hi[(ks * 4 + lg) * 64 + nt * 16 + l15]);
            bl[nt] = __builtin_bit_cast(bf16x8, xs_lo[(ks * 4 + lg) * 64 + nt * 16 + l15]);
        }
        #pragma unroll
        for (int rt = 0; rt < 2; ++rt) {
            int rg = 2 * w + rt;
            bf16x8 ah = __builtin_bit_cast(bf16x8, wqhi[(rg * 4 + ks) * 64 + lane]);
            bf16x8 al = __builtin_bit_cast(bf16x8, wqlo[(rg * 4 + ks) * 64 + lane]);
            #pragma unroll
            for (int nt = 0; nt < 4; ++nt) {
                acc[rt][nt] = __builtin_amdgcn_mfma_f32_16x16x32_bf16(ah, bh[nt], acc[rt][nt], 0, 0, 0);
                acc[rt][nt] = __builtin_amdgcn_mfma_f32_16x16x32_bf16(ah, bl[nt], acc[rt][nt], 0, 0, 0);
                acc[rt][nt] = __builtin_amdgcn_mfma_f32_16x16x32_bf16(al, bh[nt], acc[rt][nt], 0, 0, 0);
            }
        }
    }

    float bq[2][4];
    #pragma unroll
    for (int rt = 0; rt < 2; ++rt)
        #pragma unroll
        for (int r = 0; r < 4; ++r)
            bq[rt][r] = bias_q[w * 32 + rt * 16 + lg * 4 + r];
    #pragma unroll
    for (int nt = 0; nt < 4; ++nt) {
        float m = -1e30f;
        #pragma unroll
        for (int rt = 0; rt < 2; ++rt)
            #pragma unroll
            for (int r = 0; r < 4; ++r) {
                float q = acc[rt][nt][r] + bq[rt][r];
                acc[rt][nt][r] = q;
                m = fmaxf(m, q);
            }
        m = fmaxf(m, __shfl_xor(m, 16));
        m = fmaxf(m, __shfl_xor(m, 32));
        float s = 0.f;
        #pragma unroll
        for (int rt = 0; rt < 2; ++rt)
            #pragma unroll
            for (int r = 0; r < 4; ++r) {
                float e = __expf(acc[rt][nt][r] - m);
                acc[rt][nt][r] = e;
                s += e;
            }
        s += __shfl_xor(s, 16);
        s += __shfl_xor(s, 32);
        float inv = 1.0f / s;
        #pragma unroll
        for (int rt = 0; rt < 2; ++rt)
            #pragma unroll
            for (int r = 0; r < 4; ++r)
                acc[rt][nt][r] *= inv;
    }

    __syncthreads();
    {
        uint2* qh = (uint2*)xs_hi;
        uint2* ql = (uint2*)xs_lo;
        int half = (lg & 1);
        #pragma unroll
        for (int rt = 0; rt < 2; ++rt) {
            int kb = rt * 2 + (lg >> 1);
            #pragma unroll
            for (int nt = 0; nt < 4; ++nt) {
                unsigned h0, l0, h1, l1;
                hilo2(acc[rt][nt][0], acc[rt][nt][1], h0, l0);
                hilo2(acc[rt][nt][2], acc[rt][nt][3], h1, l1);
                int idx = ((w * 4 + kb) * 64 + nt * 16 + l15) * 2 + half;
                qh[idx] = make_uint2(h0, h1);
                ql[idx] = make_uint2(l0, l1);
            }
        }
    }
    __syncthreads();

    f32x4 acc2[2][4];
    #pragma unroll
    for (int rt = 0; rt < 2; ++rt)
        #pragma unroll
        for (int nt = 0; nt < 4; ++nt)
            acc2[rt][nt] = (f32x4){0.f, 0.f, 0.f, 0.f};
    const uint4* mh4 = (const uint4*)(mhi + (size_t)b * 8192);
    const uint4* ml4 = (const uint4*)(mlo + (size_t)b * 8192);
    #pragma unroll
    for (int ks = 0; ks < 4; ++ks) {
        bf16x8 bh[4], bl[4];
        #pragma unroll
        for (int nt = 0; nt < 4; ++nt) {
            bh[nt] = __builtin_bit_cast(bf16x8, xs_hi[(ks * 4 + lg) * 64 + nt * 16 + l15]);
            bl[nt] = __builtin_bit_cast(bf16x8, xs_lo[(ks * 4 + lg) * 64 + nt * 16 + l15]);
        }
        #pragma unroll
        for (int rt = 0; rt < 2; ++rt) {
            int rg = 2 * w + rt;
            bf16x8 ah = __builtin_bit_cast(bf16x8, mh4[(rg * 4 + ks) * 64 + lane]);
            bf16x8 al = __builtin_bit_cast(bf16x8, ml4[(rg * 4 + ks) * 64 + lane]);
            #pragma unroll
            for (int nt = 0; nt < 4; ++nt) {
                acc2[rt][nt] = __builtin_amdgcn_mfma_f32_16x16x32_bf16(ah, bh[nt], acc2[rt][nt], 0, 0, 0);
                acc2[rt][nt] = __builtin_amdgcn_mfma_f32_16x16x32_bf16(ah, bl[nt], acc2[rt][nt], 0, 0, 0);
                acc2[rt][nt] = __builtin_amdgcn_mfma_f32_16x16x32_bf16(al, bh[nt], acc2[rt][nt], 0, 0, 0);
            }
        }
    }
    float* ob = out + (size_t)b * (128 * 4096) + n0;
    #pragma unroll
    for (int rt = 0; rt < 2; ++rt)
        #pragma unroll
        for (int r = 0; r < 4; ++r) {
            int ch = w * 32 + rt * 16 + lg * 4 + r;
            float bo = bias_o[ch];
            #pragma unroll
            for (int nt = 0; nt < 4; ++nt)
                ob[(size_t)ch * 4096 + nt * 16 + l15] = acc2[rt][nt][r] + bo;
        }
}

extern "C" void kernel_launch(void* const* d_in, const int* in_sizes, int n_in,
                              void* d_out, int out_size, void* d_ws, size_t ws_size,
                              hipStream_t stream) {
    const float* x     = (const float*)d_in[0];
    const float* w_qkv = (const float*)d_in[1];
    const float* wA_q  = (const float*)d_in[2];
    const float* bA_q  = (const float*)d_in[3];
    const float* wB_q  = (const float*)d_in[4];
    const float* bB_q  = (const float*)d_in[5];
    const float* wA_k  = (const float*)d_in[6];
    const float* bA_k  = (const float*)d_in[7];
    const float* wB_k  = (const float*)d_in[8];
    const float* bB_k  = (const float*)d_in[9];
    const float* wA_v  = (const float*)d_in[10];
    const float* bA_v  = (const float*)d_in[11];
    const float* wB_v  = (const float*)d_in[12];
    const float* bB_v  = (const float*)d_in[13];
    const float* w_out = (const float*)d_in[14];
    const float* b_out = (const float*)d_in[15];
    float* out = (float*)d_out;

    float* ws = (float*)d_ws;
    float*    Wt      = ws;                           // 49152 f
    float*    beff    = ws + 49152;                   // 384 f
    float*    part    = ws + 49536;                   // 2048*1056 = 2162688 f
    unsigned* wall_hi = (unsigned*)(ws + 2212224);    // 24576 u32
    unsigned* wall_lo = (unsigned*)(ws + 2236800);    // 24576 u32
    unsigned* mhi     = (unsigned*)(ws + 2261376);    // 131072 u32
    unsigned* mlo     = (unsigned*)(ws + 2392448);    // 131072 u32

    fold_kernel<<<192, 256, 0, stream>>>(w_qkv,
        wA_q, bA_q, wB_q, bB_q, wA_k, bA_k, wB_k, bB_k, wA_v, bA_v, wB_v, bB_v,
        Wt, beff);
    wfrag_kernel<<<96, 256, 0, stream>>>(Wt, wall_hi, wall_lo);
    ctx_mfma_kernel<<<dim3(NCHUNK, 16), 256, 0, stream>>>(x,
        (const uint4*)wall_hi, (const uint4*)wall_lo, beff, part);
    combine_m_kernel<<<16, 256, 0, stream>>>(part, w_out, mhi, mlo);
    pass_b_kernel<<<dim3(64, 16), 256, 0, stream>>>(x,
        (const uint4*)wall_hi, (const uint4*)wall_lo, beff, mhi, mlo, b_out, out);
}

// Round 12
// 70.855 us; speedup vs baseline: 3.1951x; 1.4933x over previous
//
#include <hip/hip_runtime.h>

// loraLinearAttention on MI355X.
// R11->R12: combine_m rewritten. Old: grid 16, occupancy 0.6%, 762K LDS bank
// conflicts (ctx reads bank=e%32 constant across lanes), 45us = 43% of total.
// New: grid (4 heads, 16 batches), ks==head so each block owns its 2048
// fragment pairs; ctx_s/w_s padded to pitch 33 (banks (d+e)%32 distinct);
// coalesced part/w_out staging. ctx_mfma/pass_b/fold/wfrag unchanged (R11).

typedef float f32x4 __attribute__((ext_vector_type(4)));
typedef short bf16x8 __attribute__((ext_vector_type(8)));

#define SCALING 0.25f
#define SCALE   0.17677669529663687f   /* 32^-0.5 */
#define NCHUNK  32                     /* 128-px chunks per (b,h) */

__device__ __forceinline__ unsigned short f2bf_rn(float x) {
    union { float f; unsigned u; } v; v.f = x;
    unsigned r = v.u + 0x7FFFu + ((v.u >> 16) & 1u);
    return (unsigned short)(r >> 16);
}
__device__ __forceinline__ float bf2f(unsigned short h) {
    union { unsigned u; float f; } v; v.u = ((unsigned)h) << 16;
    return v.f;
}
__device__ __forceinline__ void hilo2(float a, float b, unsigned& hi, unsigned& lo) {
    unsigned short ah = f2bf_rn(a), bh = f2bf_rn(b);
    unsigned short al = f2bf_rn(a - bf2f(ah)), bl = f2bf_rn(b - bf2f(bh));
    hi = (unsigned)ah | ((unsigned)bh << 16);
    lo = (unsigned)al | ((unsigned)bl << 16);
}

__global__ __launch_bounds__(256) void fold_kernel(
    const float* __restrict__ w_qkv,
    const float* __restrict__ wA_q, const float* __restrict__ bA_q,
    const float* __restrict__ wB_q, const float* __restrict__ bB_q,
    const float* __restrict__ wA_k, const float* __restrict__ bA_k,
    const float* __restrict__ wB_k, const float* __restrict__ bB_k,
    const float* __restrict__ wA_v, const float* __restrict__ bA_v,
    const float* __restrict__ wB_v, const float* __restrict__ bB_v,
    float* __restrict__ Wt, float* __restrict__ beff)
{
    int idx = blockIdx.x * 256 + threadIdx.x;   // 49152 total
    int m = idx >> 14;
    int c = (idx >> 7) & 127;
    int o = idx & 127;
    const float* wA = (m == 0) ? wA_q : (m == 1) ? wA_k : wA_v;
    const float* wB = (m == 0) ? wB_q : (m == 1) ? wB_k : wB_v;
    float s = w_qkv[(m * 128 + o) * 128 + c];
    #pragma unroll
    for (int r = 0; r < 4; ++r)
        s += SCALING * wB[o * 4 + r] * wA[r * 128 + c];
    Wt[m * 16384 + c * 128 + o] = s;           // transposed [c][o]

    if (blockIdx.x == 0 && threadIdx.x < 384) {
        int mm = threadIdx.x >> 7, oo = threadIdx.x & 127;
        const float* wBm = (mm == 0) ? wB_q : (mm == 1) ? wB_k : wB_v;
        const float* bAm = (mm == 0) ? bA_q : (mm == 1) ? bA_k : bA_v;
        const float* bBm = (mm == 0) ? bB_q : (mm == 1) ? bB_k : bB_v;
        float bb = bBm[oo];
        #pragma unroll
        for (int r = 0; r < 4; ++r) bb += wBm[oo * 4 + r] * bAm[r];
        beff[mm * 128 + oo] = SCALING * bb;
    }
}

// Pack ALL of [Wq;Wk;Wv] (384 rows x 128c) into MFMA A-fragment order.
__global__ __launch_bounds__(256) void wfrag_kernel(
    const float* __restrict__ Wt, unsigned* __restrict__ whi,
    unsigned* __restrict__ wlo)
{
    int fp = blockIdx.x * 256 + threadIdx.x;   // 24576 pairs
    int f = fp * 2;
    int i = f & 7;
    int l = (f >> 3) & 63;
    int rtks = f >> 9;
    int rt = rtks >> 2, ks = rtks & 3;
    int og = rt * 16 + (l & 15);               // global row 0..383
    int c = ks * 32 + ((l >> 4) & 3) * 8 + i;
    int m = og >> 7, o = og & 127;
    float a = Wt[m * 16384 + c * 128 + o];
    float b = Wt[m * 16384 + (c + 1) * 128 + o];
    unsigned hi, lo;
    hilo2(a, b, hi, lo);
    whi[fp] = hi; wlo[fp] = lo;
}

// grid (chunk=32, b=16), 256 threads — unchanged from R11.
__global__ __launch_bounds__(256) void ctx_mfma_kernel(
    const float* __restrict__ x,
    const uint4* __restrict__ whi, const uint4* __restrict__ wlo,
    const float* __restrict__ beff, float* __restrict__ part)
{
    __shared__ __align__(16) char smem[73728];   // kv: 2 x 256*72 bf16
    uint4* xs_hi = (uint4*)smem;
    uint4* xs_lo = (uint4*)(smem + 16384);
    unsigned short* kv_hi = (unsigned short*)smem;          // [row*72+px]
    unsigned short* kv_lo = (unsigned short*)(smem + 36864);
    const int t = threadIdx.x;
    const int lane = t & 63;
    const int w = __builtin_amdgcn_readfirstlane(t >> 6);
    const int chunk = blockIdx.x, b = blockIdx.y;
    const int lg = lane >> 4, l15 = lane & 15;
    const float* xb = x + (size_t)b * (128 * 4096);

    float bias[4][4];
    #pragma unroll
    for (int rt = 0; rt < 4; ++rt)
        #pragma unroll
        for (int r = 0; r < 4; ++r)
            bias[rt][r] = beff[128 + 64 * w + 16 * rt + lg * 4 + r];

    bf16x8 ones;
    #pragma unroll
    for (int i = 0; i < 8; ++i) ones[i] = (short)0x3F80;

    f32x4 ctx_acc[2][2];
    f32x4 l_acc[2];
    #pragma unroll
    for (int rt = 0; rt < 2; ++rt) {
        l_acc[rt] = (f32x4){0.f, 0.f, 0.f, 0.f};
        #pragma unroll
        for (int et = 0; et < 2; ++et)
            ctx_acc[rt][et] = (f32x4){0.f, 0.f, 0.f, 0.f};
    }

    #pragma unroll 1
    for (int tt = 0; tt < 2; ++tt) {
        const int n0 = chunk * 128 + tt * 64;
        __syncthreads();
        #pragma unroll
        for (int p = 0; p < 4; ++p) {
            float v[8];
            #pragma unroll
            for (int j = 0; j < 8; ++j)
                v[j] = xb[(size_t)((p * 4 + w) * 8 + j) * 4096 + n0 + lane];
            unsigned hw[4], lw[4];
            #pragma unroll
            for (int q = 0; q < 4; ++q) hilo2(v[2*q], v[2*q+1], hw[q], lw[q]);
            xs_hi[(p * 4 + w) * 64 + lane] = make_uint4(hw[0], hw[1], hw[2], hw[3]);
            xs_lo[(p * 4 + w) * 64 + lane] = make_uint4(lw[0], lw[1], lw[2], lw[3]);
        }
        __syncthreads();
        f32x4 acc1[4][4];
        #pragma unroll
        for (int rt = 0; rt < 4; ++rt)
            #pragma unroll
            for (int nt = 0; nt < 4; ++nt)
                acc1[rt][nt] = (f32x4){0.f, 0.f, 0.f, 0.f};
        #pragma unroll
        for (int ks = 0; ks < 4; ++ks) {
            bf16x8 bh[4], bl[4];
            #pragma unroll
            for (int nt = 0; nt < 4; ++nt) {
                bh[nt] = __builtin_bit_cast(bf16x8, xs_hi[(ks * 4 + lg) * 64 + nt * 16 + l15]);
                bl[nt] = __builtin_bit_cast(bf16x8, xs_lo[(ks * 4 + lg) * 64 + nt * 16 + l15]);
            }
            #pragma unroll
            for (int rt = 0; rt < 4; ++rt) {
                int rg = 8 + 4 * w + rt;
                bf16x8 ah = __builtin_bit_cast(bf16x8, whi[(rg * 4 + ks) * 64 + lane]);
                bf16x8 al = __builtin_bit_cast(bf16x8, wlo[(rg * 4 + ks) * 64 + lane]);
                #pragma unroll
                for (int nt = 0; nt < 4; ++nt) {
                    acc1[rt][nt] = __builtin_amdgcn_mfma_f32_16x16x32_bf16(ah, bh[nt], acc1[rt][nt], 0, 0, 0);
                    acc1[rt][nt] = __builtin_amdgcn_mfma_f32_16x16x32_bf16(ah, bl[nt], acc1[rt][nt], 0, 0, 0);
                    acc1[rt][nt] = __builtin_amdgcn_mfma_f32_16x16x32_bf16(al, bh[nt], acc1[rt][nt], 0, 0, 0);
                }
            }
        }
        __syncthreads();
        #pragma unroll
        for (int rt = 0; rt < 4; ++rt)
            #pragma unroll
            for (int nt = 0; nt < 4; ++nt)
                #pragma unroll
                for (int r = 0; r < 4; ++r) {
                    float vv = acc1[rt][nt][r] + bias[rt][r];
                    if (w < 2) vv = __expf(vv);
                    int row = 64 * w + 16 * rt + lg * 4 + r;
                    int px = nt * 16 + l15;
                    unsigned short hi = f2bf_rn(vv);
                    unsigned short lo = f2bf_rn(vv - bf2f(hi));
                    kv_hi[row * 72 + px] = hi;
                    kv_lo[row * 72 + px] = lo;
                }
        __syncthreads();
        #pragma unroll
        for (int ks2 = 0; ks2 < 2; ++ks2) {
            int pxb = ks2 * 32 + lg * 8;
            bf16x8 ph[2], pl[2], vh[2], vl[2];
            #pragma unroll
            for (int rt = 0; rt < 2; ++rt) {
                int prow = 32 * w + 16 * rt + l15;
                ph[rt] = __builtin_bit_cast(bf16x8, *(const uint4*)&kv_hi[prow * 72 + pxb]);
                pl[rt] = __builtin_bit_cast(bf16x8, *(const uint4*)&kv_lo[prow * 72 + pxb]);
            }
            #pragma unroll
            for (int et = 0; et < 2; ++et) {
                int vrow = 128 + 32 * w + 16 * et + l15;
                vh[et] = __builtin_bit_cast(bf16x8, *(const uint4*)&kv_hi[vrow * 72 + pxb]);
                vl[et] = __builtin_bit_cast(bf16x8, *(const uint4*)&kv_lo[vrow * 72 + pxb]);
            }
            #pragma unroll
            for (int rt = 0; rt < 2; ++rt) {
                #pragma unroll
                for (int et = 0; et < 2; ++et) {
                    ctx_acc[rt][et] = __builtin_amdgcn_mfma_f32_16x16x32_bf16(ph[rt], vh[et], ctx_acc[rt][et], 0, 0, 0);
                    ctx_acc[rt][et] = __builtin_amdgcn_mfma_f32_16x16x32_bf16(ph[rt], vl[et], ctx_acc[rt][et], 0, 0, 0);
                    ctx_acc[rt][et] = __builtin_amdgcn_mfma_f32_16x16x32_bf16(pl[rt], vh[et], ctx_acc[rt][et], 0, 0, 0);
                }
                l_acc[rt] = __builtin_amdgcn_mfma_f32_16x16x32_bf16(ph[rt], ones, l_acc[rt], 0, 0, 0);
                l_acc[rt] = __builtin_amdgcn_mfma_f32_16x16x32_bf16(pl[rt], ones, l_acc[rt], 0, 0, 0);
            }
        }
    }
    float* pout = part + (size_t)((b * 4 + w) * NCHUNK + chunk) * 1056;
    #pragma unroll
    for (int rt = 0; rt < 2; ++rt) {
        #pragma unroll
        for (int et = 0; et < 2; ++et)
            #pragma unroll
            for (int r = 0; r < 4; ++r)
                pout[(16 * rt + lg * 4 + r) * 32 + 16 * et + l15] = ctx_acc[rt][et][r];
        if (l15 == 0)
            #pragma unroll
            for (int r = 0; r < 4; ++r)
                pout[1024 + 16 * rt + lg * 4 + r] = l_acc[rt][r];
    }
}

// grid (4 heads, 16 batches), 256 threads, ~22.5 KB LDS. Reduces part for
// its (b,h), normalizes ctx, emits this head's 2048 M fragment pairs.
__global__ __launch_bounds__(256) void combine_m_kernel(
    const float* __restrict__ part, const float* __restrict__ w_out,
    unsigned* __restrict__ mhi, unsigned* __restrict__ mlo)
{
    __shared__ float ctx_s[32 * 33];     // [d][e] pad 33: bank (d+e)%32
    __shared__ float w_s[128 * 33];      // [o][e] pad 33: bank (o+e)%32
    __shared__ float lpart_s[8][32];
    __shared__ float linv_s[32];
    const int t = threadIdx.x;
    const int h = blockIdx.x, b = blockIdx.y;
    const float* pb = part + (size_t)((b * 4 + h) * NCHUNK) * 1056;

    // phase A: l partials, w_out stage, ctx partial sums (regs)
    {
        int g = t >> 5, d = t & 31;
        float lp = 0.f;
        #pragma unroll
        for (int c4 = 0; c4 < 4; ++c4)
            lp += pb[(size_t)(g * 4 + c4) * 1056 + 1024 + d];
        lpart_s[g][d] = lp;
    }
    #pragma unroll
    for (int i = 0; i < 16; ++i) {       // w_s[o][e] = w_out[o][h*32+e]
        int idx = i * 256 + t;
        int e = idx & 31, o = idx >> 5;
        w_s[o * 33 + e] = w_out[o * 128 + h * 32 + e];
    }
    float csum[4];
    #pragma unroll
    for (int i = 0; i < 4; ++i) {
        int idx = i * 256 + t;           // d*32+e
        float s = 0.f;
        for (int ch = 0; ch < NCHUNK; ++ch)
            s += pb[(size_t)ch * 1056 + idx];
        csum[i] = s;
    }
    __syncthreads();
    if (t < 32) {
        float l = 0.f;
        #pragma unroll
        for (int g = 0; g < 8; ++g) l += lpart_s[g][t];
        linv_s[t] = 1.0f / (l * 4096.0f);   // folds v/n
    }
    __syncthreads();
    #pragma unroll
    for (int i = 0; i < 4; ++i) {
        int idx = i * 256 + t;
        int d = idx >> 5, e = idx & 31;
        ctx_s[d * 33 + e] = csum[i] * linv_s[d];
    }
    __syncthreads();
    // M pack: pairs with ks==h. p -> rt(0..7), l(0..63), ip(0..3), i=2*ip
    #pragma unroll 1
    for (int it = 0; it < 8; ++it) {
        int p = it * 256 + t;
        int rt = p >> 8;
        int l = (p >> 2) & 63;
        int ip = p & 3;
        int o = rt * 16 + (l & 15);
        int d0 = (l >> 4) * 8 + 2 * ip;
        float v0 = 0.f, v1 = 0.f;
        #pragma unroll
        for (int e = 0; e < 32; ++e) {
            float wv = w_s[o * 33 + e];
            v0 = fmaf(wv, ctx_s[d0 * 33 + e], v0);
            v1 = fmaf(wv, ctx_s[(d0 + 1) * 33 + e], v1);
        }
        v0 *= SCALE; v1 *= SCALE;
        unsigned hi, lo;
        hilo2(v0, v1, hi, lo);
        size_t fp = (size_t)b * 8192 + ((rt * 4 + h) * 64 + l) * 4 + ip;
        mhi[fp] = hi;
        mlo[fp] = lo;
    }
}

// grid (tile=64, b=16), 256 threads — unchanged from R10/R11 (validated).
__global__ __launch_bounds__(256) void pass_b_kernel(
    const float* __restrict__ x,
    const uint4* __restrict__ wqhi, const uint4* __restrict__ wqlo,
    const float* __restrict__ beff,
    const unsigned* __restrict__ mhi, const unsigned* __restrict__ mlo,
    const float* __restrict__ b_out, float* __restrict__ out)
{
    __shared__ uint4 xs_hi[1024];
    __shared__ uint4 xs_lo[1024];
    __shared__ float bias_q[128];
    __shared__ float bias_o[128];
    const int t = threadIdx.x;
    const int tile = blockIdx.x, b = blockIdx.y;
    const int lane = t & 63;
    const int w = __builtin_amdgcn_readfirstlane(t >> 6);
    const int n0 = tile * 64;
    const float* xb = x + (size_t)b * (128 * 4096);

    if (t < 128) { bias_q[t] = beff[t]; bias_o[t] = b_out[t]; }

    #pragma unroll
    for (int p = 0; p < 4; ++p) {
        float v[8];
        #pragma unroll
        for (int j = 0; j < 8; ++j)
            v[j] = xb[(size_t)((p * 4 + w) * 8 + j) * 4096 + n0 + lane];
        unsigned hw[4], lw[4];
        #pragma unroll
        for (int q = 0; q < 4; ++q) hilo2(v[2 * q], v[2 * q + 1], hw[q], lw[q]);
        xs_hi[(p * 4 + w) * 64 + lane] = make_uint4(hw[0], hw[1], hw[2], hw[3]);
        xs_lo[(p * 4 + w) * 64 + lane] = make_uint4(lw[0], lw[1], lw[2], lw[3]);
    }
    __syncthreads();

    const int lg = lane >> 4;
    const int l15 = lane & 15;

    f32x4 acc[2][4];
    #pragma unroll
    for (int rt = 0; rt < 2; ++rt)
        #pragma unroll
        for (int nt = 0; nt < 4; ++nt)
            acc[rt][nt] = (f32x4){0.f, 0.f, 0.f, 0.f};
    #pragma unroll
    for (int ks = 0; ks < 4; ++ks) {
        bf16x8 bh[4], bl[4];
        #pragma unroll
        for (int nt = 0; nt < 4; ++nt) {
            bh[nt] = __builtin_bit_cast(bf16x8, xs_hi[(ks * 4 + lg) * 64 + nt * 16 + l15]);
            bl[nt] = __builtin_bit_cast(bf16x8, xs_lo[(ks * 4 + lg) * 64 + nt * 16 + l15]);
        }
        #pragma unroll
        for (int rt = 0; rt < 2; ++rt) {
            int rg = 2 * w + rt;
            bf16x8 ah = __builtin_bit_cast(bf16x8, wqhi[(rg * 4 + ks) * 64 + lane]);
            bf16x8 al = __builtin_bit_cast(bf16x8, wqlo[(rg * 4 + ks) * 64 + lane]);
            #pragma unroll
            for (int nt = 0; nt < 4; ++nt) {
                acc[rt][nt] = __builtin_amdgcn_mfma_f32_16x16x32_bf16(ah, bh[nt], acc[rt][nt], 0, 0, 0);
                acc[rt][nt] = __builtin_amdgcn_mfma_f32_16x16x32_bf16(ah, bl[nt], acc[rt][nt], 0, 0, 0);
                acc[rt][nt] = __builtin_amdgcn_mfma_f32_16x16x32_bf16(al, bh[nt], acc[rt][nt], 0, 0, 0);
            }
        }
    }

    float bq[2][4];
    #pragma unroll
    for (int rt = 0; rt < 2; ++rt)
        #pragma unroll
        for (int r = 0; r < 4; ++r)
            bq[rt][r] = bias_q[w * 32 + rt * 16 + lg * 4 + r];
    #pragma unroll
    for (int nt = 0; nt < 4; ++nt) {
        float m = -1e30f;
        #pragma unroll
        for (int rt = 0; rt < 2; ++rt)
            #pragma unroll
            for (int r = 0; r < 4; ++r) {
                float q = acc[rt][nt][r] + bq[rt][r];
                acc[rt][nt][r] = q;
                m = fmaxf(m, q);
            }
        m = fmaxf(m, __shfl_xor(m, 16));
        m = fmaxf(m, __shfl_xor(m, 32));
        float s = 0.f;
        #pragma unroll
        for (int rt = 0; rt < 2; ++rt)
            #pragma unroll
            for (int r = 0; r < 4; ++r) {
                float e = __expf(acc[rt][nt][r] - m);
                acc[rt][nt][r] = e;
                s += e;
            }
        s += __shfl_xor(s, 16);
        s += __shfl_xor(s, 32);
        float inv = 1.0f / s;
        #pragma unroll
        for (int rt = 0; rt < 2; ++rt)
            #pragma unroll
            for (int r = 0; r < 4; ++r)
                acc[rt][nt][r] *= inv;
    }

    __syncthreads();
    {
        uint2* qh = (uint2*)xs_hi;
        uint2* ql = (uint2*)xs_lo;
        int half = (lg & 1);
        #pragma unroll
        for (int rt = 0; rt < 2; ++rt) {
            int kb = rt * 2 + (lg >> 1);
            #pragma unroll
            for (int nt = 0; nt < 4; ++nt) {
                unsigned h0, l0, h1, l1;
                hilo2(acc[rt][nt][0], acc[rt][nt][1], h0, l0);
                hilo2(acc[rt][nt][2], acc[rt][nt][3], h1, l1);
                int idx = ((w * 4 + kb) * 64 + nt * 16 + l15) * 2 + half;
                qh[idx] = make_uint2(h0, h1);
                ql[idx] = make_uint2(l0, l1);
            }
        }
    }
    __syncthreads();

    f32x4 acc2[2][4];
    #pragma unroll
    for (int rt = 0; rt < 2; ++rt)
        #pragma unroll
        for (int nt = 0; nt < 4; ++nt)
            acc2[rt][nt] = (f32x4){0.f, 0.f, 0.f, 0.f};
    const uint4* mh4 = (const uint4*)(mhi + (size_t)b * 8192);
    const uint4* ml4 = (const uint4*)(mlo + (size_t)b * 8192);
    #pragma unroll
    for (int ks = 0; ks < 4; ++ks) {
        bf16x8 bh[4], bl[4];
        #pragma unroll
        for (int nt = 0; nt < 4; ++nt) {
            bh[nt] = __builtin_bit_cast(bf16x8, xs_hi[(ks * 4 + lg) * 64 + nt * 16 + l15]);
            bl[nt] = __builtin_bit_cast(bf16x8, xs_lo[(ks * 4 + lg) * 64 + nt * 16 + l15]);
        }
        #pragma unroll
        for (int rt = 0; rt < 2; ++rt) {
            int rg = 2 * w + rt;
            bf16x8 ah = __builtin_bit_cast(bf16x8, mh4[(rg * 4 + ks) * 64 + lane]);
            bf16x8 al = __builtin_bit_cast(bf16x8, ml4[(rg * 4 + ks) * 64 + lane]);
            #pragma unroll
            for (int nt = 0; nt < 4; ++nt) {
                acc2[rt][nt] = __builtin_amdgcn_mfma_f32_16x16x32_bf16(ah, bh[nt], acc2[rt][nt], 0, 0, 0);
                acc2[rt][nt] = __builtin_amdgcn_mfma_f32_16x16x32_bf16(ah, bl[nt], acc2[rt][nt], 0, 0, 0);
                acc2[rt][nt] = __builtin_amdgcn_mfma_f32_16x16x32_bf16(al, bh[nt], acc2[rt][nt], 0, 0, 0);
            }
        }
    }
    float* ob = out + (size_t)b * (128 * 4096) + n0;
    #pragma unroll
    for (int rt = 0; rt < 2; ++rt)
        #pragma unroll
        for (int r = 0; r < 4; ++r) {
            int ch = w * 32 + rt * 16 + lg * 4 + r;
            float bo = bias_o[ch];
            #pragma unroll
            for (int nt = 0; nt < 4; ++nt)
                ob[(size_t)ch * 4096 + nt * 16 + l15] = acc2[rt][nt][r] + bo;
        }
}

extern "C" void kernel_launch(void* const* d_in, const int* in_sizes, int n_in,
                              void* d_out, int out_size, void* d_ws, size_t ws_size,
                              hipStream_t stream) {
    const float* x     = (const float*)d_in[0];
    const float* w_qkv = (const float*)d_in[1];
    const float* wA_q  = (const float*)d_in[2];
    const float* bA_q  = (const float*)d_in[3];
    const float* wB_q  = (const float*)d_in[4];
    const float* bB_q  = (const float*)d_in[5];
    const float* wA_k  = (const float*)d_in[6];
    const float* bA_k  = (const float*)d_in[7];
    const float* wB_k  = (const float*)d_in[8];
    const float* bB_k  = (const float*)d_in[9];
    const float* wA_v  = (const float*)d_in[10];
    const float* bA_v  = (const float*)d_in[11];
    const float* wB_v  = (const float*)d_in[12];
    const float* bB_v  = (const float*)d_in[13];
    const float* w_out = (const float*)d_in[14];
    const float* b_out = (const float*)d_in[15];
    float* out = (float*)d_out;

    float* ws = (float*)d_ws;
    float*    Wt      = ws;                           // 49152 f
    float*    beff    = ws + 49152;                   // 384 f
    float*    part    = ws + 49536;                   // 2048*1056 = 2162688 f
    unsigned* wall_hi = (unsigned*)(ws + 2212224);    // 24576 u32
    unsigned* wall_lo = (unsigned*)(ws + 2236800);    // 24576 u32
    unsigned* mhi     = (unsigned*)(ws + 2261376);    // 131072 u32
    unsigned* mlo     = (unsigned*)(ws + 2392448);    // 131072 u32

    fold_kernel<<<192, 256, 0, stream>>>(w_qkv,
        wA_q, bA_q, wB_q, bB_q, wA_k, bA_k, wB_k, bB_k, wA_v, bA_v, wB_v, bB_v,
        Wt, beff);
    wfrag_kernel<<<96, 256, 0, stream>>>(Wt, wall_hi, wall_lo);
    ctx_mfma_kernel<<<dim3(NCHUNK, 16), 256, 0, stream>>>(x,
        (const uint4*)wall_hi, (const uint4*)wall_lo, beff, part);
    combine_m_kernel<<<dim3(4, 16), 256, 0, stream>>>(part, w_out, mhi, mlo);
    pass_b_kernel<<<dim3(64, 16), 256, 0, stream>>>(x,
        (const uint4*)wall_hi, (const uint4*)wall_lo, beff, mhi, mlo, b_out, out);
}

// Round 13
// 68.283 us; speedup vs baseline: 3.3155x; 1.0377x over previous
//
#include <hip/hip_runtime.h>

// loraLinearAttention on MI355X.
// R12->R13: ctx_mfma de-latencied. R12 counters: 41us, MfmaUtil 12.6%,
// occupancy 9% (73.7KB LDS -> 2 blocks/CU) — latency-bound. Changes:
// (1) k-bias dropped (exp(bk) cancels in ctx/l — exact); v-bias folded into
// combine via ctx_full = ctx_raw + bv*l (exact). (2) P,V single-bf16 in LDS
// (ctx 12 MFMA, kv 36.9KB). (3) x staged single-bf16 (xs 16KB, disjoint from
// kv, 2 barriers). LDS 52KB -> 3 blocks/CU; grid 1024 (64-px tiles).
// Error budget: ~2e-7 absmax (vs 1.3e-8 reference-noise floor currently).

typedef float f32x4 __attribute__((ext_vector_type(4)));
typedef short bf16x8 __attribute__((ext_vector_type(8)));

#define SCALING 0.25f
#define SCALE   0.17677669529663687f   /* 32^-0.5 */
#define NCHUNK  64                     /* 64-px chunks per (b,h) */

__device__ __forceinline__ unsigned short f2bf_rn(float x) {
    union { float f; unsigned u; } v; v.f = x;
    unsigned r = v.u + 0x7FFFu + ((v.u >> 16) & 1u);
    return (unsigned short)(r >> 16);
}
__device__ __forceinline__ float bf2f(unsigned short h) {
    union { unsigned u; float f; } v; v.u = ((unsigned)h) << 16;
    return v.f;
}
__device__ __forceinline__ void hilo2(float a, float b, unsigned& hi, unsigned& lo) {
    unsigned short ah = f2bf_rn(a), bh = f2bf_rn(b);
    unsigned short al = f2bf_rn(a - bf2f(ah)), bl = f2bf_rn(b - bf2f(bh));
    hi = (unsigned)ah | ((unsigned)bh << 16);
    lo = (unsigned)al | ((unsigned)bl << 16);
}
__device__ __forceinline__ unsigned pack2(float a, float b) {
    return (unsigned)f2bf_rn(a) | ((unsigned)f2bf_rn(b) << 16);
}

__global__ __launch_bounds__(256) void fold_kernel(
    const float* __restrict__ w_qkv,
    const float* __restrict__ wA_q, const float* __restrict__ bA_q,
    const float* __restrict__ wB_q, const float* __restrict__ bB_q,
    const float* __restrict__ wA_k, const float* __restrict__ bA_k,
    const float* __restrict__ wB_k, const float* __restrict__ bB_k,
    const float* __restrict__ wA_v, const float* __restrict__ bA_v,
    const float* __restrict__ wB_v, const float* __restrict__ bB_v,
    float* __restrict__ Wt, float* __restrict__ beff)
{
    int idx = blockIdx.x * 256 + threadIdx.x;   // 49152 total
    int m = idx >> 14;
    int c = (idx >> 7) & 127;
    int o = idx & 127;
    const float* wA = (m == 0) ? wA_q : (m == 1) ? wA_k : wA_v;
    const float* wB = (m == 0) ? wB_q : (m == 1) ? wB_k : wB_v;
    float s = w_qkv[(m * 128 + o) * 128 + c];
    #pragma unroll
    for (int r = 0; r < 4; ++r)
        s += SCALING * wB[o * 4 + r] * wA[r * 128 + c];
    Wt[m * 16384 + c * 128 + o] = s;           // transposed [c][o]

    if (blockIdx.x == 0 && threadIdx.x < 384) {
        int mm = threadIdx.x >> 7, oo = threadIdx.x & 127;
        const float* wBm = (mm == 0) ? wB_q : (mm == 1) ? wB_k : wB_v;
        const float* bAm = (mm == 0) ? bA_q : (mm == 1) ? bA_k : bA_v;
        const float* bBm = (mm == 0) ? bB_q : (mm == 1) ? bB_k : bB_v;
        float bb = bBm[oo];
        #pragma unroll
        for (int r = 0; r < 4; ++r) bb += wBm[oo * 4 + r] * bAm[r];
        beff[mm * 128 + oo] = SCALING * bb;
    }
}

// Pack ALL of [Wq;Wk;Wv] (384 rows x 128c) into MFMA A-fragment order.
__global__ __launch_bounds__(256) void wfrag_kernel(
    const float* __restrict__ Wt, unsigned* __restrict__ whi,
    unsigned* __restrict__ wlo)
{
    int fp = blockIdx.x * 256 + threadIdx.x;   // 24576 pairs
    int f = fp * 2;
    int i = f & 7;
    int l = (f >> 3) & 63;
    int rtks = f >> 9;
    int rt = rtks >> 2, ks = rtks & 3;
    int og = rt * 16 + (l & 15);               // global row 0..383
    int c = ks * 32 + ((l >> 4) & 3) * 8 + i;
    int m = og >> 7, o = og & 127;
    float a = Wt[m * 16384 + c * 128 + o];
    float b = Wt[m * 16384 + (c + 1) * 128 + o];
    unsigned hi, lo;
    hilo2(a, b, hi, lo);
    whi[fp] = hi; wlo[fp] = lo;
}

// grid (chunk=64, b=16) = 1024 blocks, 256 threads, 52KB LDS (3 blocks/CU).
// One 64-px tile per block. xs: x as single-bf16 B-frags (16KB, disjoint
// from kv). GEMM1: wave w -> kv rows 64w..+63 (W hi/lo x 2 MFMA), NO bias.
// K-waves exp in regs; kv -> LDS [row][px] pitch-72 single bf16. ctx phase:
// wave h: ctx_h += P_h.V_h^T (1 MFMA) + l (ones-B).
__global__ __launch_bounds__(256) void ctx_mfma_kernel(
    const float* __restrict__ x,
    const uint4* __restrict__ whi, const uint4* __restrict__ wlo,
    float* __restrict__ part)
{
    __shared__ __align__(16) char smem[53248];
    uint4* xs = (uint4*)smem;                        // 16 KB
    unsigned short* kv = (unsigned short*)(smem + 16384);  // [256][72] bf16
    const int t = threadIdx.x;
    const int lane = t & 63;
    const int w = __builtin_amdgcn_readfirstlane(t >> 6);
    const int chunk = blockIdx.x, b = blockIdx.y;
    const int lg = lane >> 4, l15 = lane & 15;
    const float* xb = x + (size_t)b * (128 * 4096);
    const int n0 = chunk * 64;

    // stage x single-bf16 B-frags: wave w, pass p: channels (p*4+w)*8..+7
    #pragma unroll
    for (int p = 0; p < 4; ++p) {
        float v[8];
        #pragma unroll
        for (int j = 0; j < 8; ++j)
            v[j] = xb[(size_t)((p * 4 + w) * 8 + j) * 4096 + n0 + lane];
        xs[(p * 4 + w) * 64 + lane] = make_uint4(
            pack2(v[0], v[1]), pack2(v[2], v[3]),
            pack2(v[4], v[5]), pack2(v[6], v[7]));
    }
    __syncthreads();

    // GEMM1: kv rows 64w..+63 x 64 px (no bias)
    f32x4 acc1[4][4];
    #pragma unroll
    for (int rt = 0; rt < 4; ++rt)
        #pragma unroll
        for (int nt = 0; nt < 4; ++nt)
            acc1[rt][nt] = (f32x4){0.f, 0.f, 0.f, 0.f};
    #pragma unroll
    for (int ks = 0; ks < 4; ++ks) {
        bf16x8 bh[4];
        #pragma unroll
        for (int nt = 0; nt < 4; ++nt)
            bh[nt] = __builtin_bit_cast(bf16x8, xs[(ks * 4 + lg) * 64 + nt * 16 + l15]);
        #pragma unroll
        for (int rt = 0; rt < 4; ++rt) {
            int rg = 8 + 4 * w + rt;
            bf16x8 ah = __builtin_bit_cast(bf16x8, whi[(rg * 4 + ks) * 64 + lane]);
            bf16x8 al = __builtin_bit_cast(bf16x8, wlo[(rg * 4 + ks) * 64 + lane]);
            #pragma unroll
            for (int nt = 0; nt < 4; ++nt) {
                acc1[rt][nt] = __builtin_amdgcn_mfma_f32_16x16x32_bf16(ah, bh[nt], acc1[rt][nt], 0, 0, 0);
                acc1[rt][nt] = __builtin_amdgcn_mfma_f32_16x16x32_bf16(al, bh[nt], acc1[rt][nt], 0, 0, 0);
            }
        }
    }
    // exp for K waves, store kv single bf16 (pitch 72)
    #pragma unroll
    for (int rt = 0; rt < 4; ++rt)
        #pragma unroll
        for (int nt = 0; nt < 4; ++nt)
            #pragma unroll
            for (int r = 0; r < 4; ++r) {
                float vv = acc1[rt][nt][r];
                if (w < 2) vv = __expf(vv);
                kv[(64 * w + 16 * rt + lg * 4 + r) * 72 + nt * 16 + l15] = f2bf_rn(vv);
            }
    __syncthreads();

    // ctx phase: wave w = head w
    bf16x8 ones;
    #pragma unroll
    for (int i = 0; i < 8; ++i) ones[i] = (short)0x3F80;
    f32x4 ctx_acc[2][2];
    f32x4 l_acc[2];
    #pragma unroll
    for (int rt = 0; rt < 2; ++rt) {
        l_acc[rt] = (f32x4){0.f, 0.f, 0.f, 0.f};
        #pragma unroll
        for (int et = 0; et < 2; ++et)
            ctx_acc[rt][et] = (f32x4){0.f, 0.f, 0.f, 0.f};
    }
    #pragma unroll
    for (int ks2 = 0; ks2 < 2; ++ks2) {
        int pxb = ks2 * 32 + lg * 8;
        bf16x8 ph[2], vh[2];
        #pragma unroll
        for (int rt = 0; rt < 2; ++rt)
            ph[rt] = __builtin_bit_cast(bf16x8, *(const uint4*)&kv[(32 * w + 16 * rt + l15) * 72 + pxb]);
        #pragma unroll
        for (int et = 0; et < 2; ++et)
            vh[et] = __builtin_bit_cast(bf16x8, *(const uint4*)&kv[(128 + 32 * w + 16 * et + l15) * 72 + pxb]);
        #pragma unroll
        for (int rt = 0; rt < 2; ++rt) {
            #pragma unroll
            for (int et = 0; et < 2; ++et)
                ctx_acc[rt][et] = __builtin_amdgcn_mfma_f32_16x16x32_bf16(ph[rt], vh[et], ctx_acc[rt][et], 0, 0, 0);
            l_acc[rt] = __builtin_amdgcn_mfma_f32_16x16x32_bf16(ph[rt], ones, l_acc[rt], 0, 0, 0);
        }
    }
    float* pout = part + (size_t)((b * 4 + w) * NCHUNK + chunk) * 1056;
    #pragma unroll
    for (int rt = 0; rt < 2; ++rt) {
        #pragma unroll
        for (int et = 0; et < 2; ++et)
            #pragma unroll
            for (int r = 0; r < 4; ++r)
                pout[(16 * rt + lg * 4 + r) * 32 + 16 * et + l15] = ctx_acc[rt][et][r];
        if (l15 == 0)
            #pragma unroll
            for (int r = 0; r < 4; ++r)
                pout[1024 + 16 * rt + lg * 4 + r] = l_acc[rt][r];
    }
}

// grid (4 heads, 16 batches), 256 threads, ~22.5 KB LDS. Reduces part,
// normalizes, ADDS V-BIAS (ctx_full = ctx_raw*linv + bv/4096), emits M frags.
__global__ __launch_bounds__(256) void combine_m_kernel(
    const float* __restrict__ part, const float* __restrict__ w_out,
    const float* __restrict__ beff,
    unsigned* __restrict__ mhi, unsigned* __restrict__ mlo)
{
    __shared__ float ctx_s[32 * 33];     // [d][e] pad 33
    __shared__ float w_s[128 * 33];      // [o][e] pad 33
    __shared__ float lpart_s[8][32];
    __shared__ float linv_s[32];
    __shared__ float bv_s[32];
    const int t = threadIdx.x;
    const int h = blockIdx.x, b = blockIdx.y;
    const float* pb = part + (size_t)((b * 4 + h) * NCHUNK) * 1056;

    {
        int g = t >> 5, d = t & 31;
        float lp = 0.f;
        #pragma unroll
        for (int c8 = 0; c8 < 8; ++c8)
            lp += pb[(size_t)(g * 8 + c8) * 1056 + 1024 + d];
        lpart_s[g][d] = lp;
    }
    if (t < 32) bv_s[t] = beff[256 + h * 32 + t];
    #pragma unroll
    for (int i = 0; i < 16; ++i) {       // w_s[o][e] = w_out[o][h*32+e]
        int idx = i * 256 + t;
        int e = idx & 31, o = idx >> 5;
        w_s[o * 33 + e] = w_out[o * 128 + h * 32 + e];
    }
    float csum[4];
    #pragma unroll
    for (int i = 0; i < 4; ++i) {
        int idx = i * 256 + t;           // d*32+e
        float s = 0.f;
        for (int ch = 0; ch < NCHUNK; ++ch)
            s += pb[(size_t)ch * 1056 + idx];
        csum[i] = s;
    }
    __syncthreads();
    if (t < 32) {
        float l = 0.f;
        #pragma unroll
        for (int g = 0; g < 8; ++g) l += lpart_s[g][t];
        linv_s[t] = 1.0f / (l * 4096.0f);   // folds v/n
    }
    __syncthreads();
    #pragma unroll
    for (int i = 0; i < 4; ++i) {
        int idx = i * 256 + t;
        int d = idx >> 5, e = idx & 31;
        ctx_s[d * 33 + e] = csum[i] * linv_s[d] + bv_s[e] * (1.0f / 4096.0f);
    }
    __syncthreads();
    #pragma unroll 1
    for (int it = 0; it < 8; ++it) {
        int p = it * 256 + t;
        int rt = p >> 8;
        int l = (p >> 2) & 63;
        int ip = p & 3;
        int o = rt * 16 + (l & 15);
        int d0 = (l >> 4) * 8 + 2 * ip;
        float v0 = 0.f, v1 = 0.f;
        #pragma unroll
        for (int e = 0; e < 32; ++e) {
            float wv = w_s[o * 33 + e];
            v0 = fmaf(wv, ctx_s[d0 * 33 + e], v0);
            v1 = fmaf(wv, ctx_s[(d0 + 1) * 33 + e], v1);
        }
        v0 *= SCALE; v1 *= SCALE;
        unsigned hi, lo;
        hilo2(v0, v1, hi, lo);
        size_t fp = (size_t)b * 8192 + ((rt * 4 + h) * 64 + l) * 4 + ip;
        mhi[fp] = hi;
        mlo[fp] = lo;
    }
}

// grid (tile=64, b=16), 256 threads — unchanged (validated R10-R12).
__global__ __launch_bounds__(256) void pass_b_kernel(
    const float* __restrict__ x,
    const uint4* __restrict__ wqhi, const uint4* __restrict__ wqlo,
    const float* __restrict__ beff,
    const unsigned* __restrict__ mhi, const unsigned* __restrict__ mlo,
    const float* __restrict__ b_out, float* __restrict__ out)
{
    __shared__ uint4 xs_hi[1024];
    __shared__ uint4 xs_lo[1024];
    __shared__ float bias_q[128];
    __shared__ float bias_o[128];
    const int t = threadIdx.x;
    const int tile = blockIdx.x, b = blockIdx.y;
    const int lane = t & 63;
    const int w = __builtin_amdgcn_readfirstlane(t >> 6);
    const int n0 = tile * 64;
    const float* xb = x + (size_t)b * (128 * 4096);

    if (t < 128) { bias_q[t] = beff[t]; bias_o[t] = b_out[t]; }

    #pragma unroll
    for (int p = 0; p < 4; ++p) {
        float v[8];
        #pragma unroll
        for (int j = 0; j < 8; ++j)
            v[j] = xb[(size_t)((p * 4 + w) * 8 + j) * 4096 + n0 + lane];
        unsigned hw[4], lw[4];
        #pragma unroll
        for (int q = 0; q < 4; ++q) hilo2(v[2 * q], v[2 * q + 1], hw[q], lw[q]);
        xs_hi[(p * 4 + w) * 64 + lane] = make_uint4(hw[0], hw[1], hw[2], hw[3]);
        xs_lo[(p * 4 + w) * 64 + lane] = make_uint4(lw[0], lw[1], lw[2], lw[3]);
    }
    __syncthreads();

    const int lg = lane >> 4;
    const int l15 = lane & 15;

    f32x4 acc[2][4];
    #pragma unroll
    for (int rt = 0; rt < 2; ++rt)
        #pragma unroll
        for (int nt = 0; nt < 4; ++nt)
            acc[rt][nt] = (f32x4){0.f, 0.f, 0.f, 0.f};
    #pragma unroll
    for (int ks = 0; ks < 4; ++ks) {
        bf16x8 bh[4], bl[4];
        #pragma unroll
        for (int nt = 0; nt < 4; ++nt) {
            bh[nt] = __builtin_bit_cast(bf16x8, xs_hi[(ks * 4 + lg) * 64 + nt * 16 + l15]);
            bl[nt] = __builtin_bit_cast(bf16x8, xs_lo[(ks * 4 + lg) * 64 + nt * 16 + l15]);
        }
        #pragma unroll
        for (int rt = 0; rt < 2; ++rt) {
            int rg = 2 * w + rt;
            bf16x8 ah = __builtin_bit_cast(bf16x8, wqhi[(rg * 4 + ks) * 64 + lane]);
            bf16x8 al = __builtin_bit_cast(bf16x8, wqlo[(rg * 4 + ks) * 64 + lane]);
            #pragma unroll
            for (int nt = 0; nt < 4; ++nt) {
                acc[rt][nt] = __builtin_amdgcn_mfma_f32_16x16x32_bf16(ah, bh[nt], acc[rt][nt], 0, 0, 0);
                acc[rt][nt] = __builtin_amdgcn_mfma_f32_16x16x32_bf16(ah, bl[nt], acc[rt][nt], 0, 0, 0);
                acc[rt][nt] = __builtin_amdgcn_mfma_f32_16x16x32_bf16(al, bh[nt], acc[rt][nt], 0, 0, 0);
            }
        }
    }

    float bq[2][4];
    #pragma unroll
    for (int rt = 0; rt < 2; ++rt)
        #pragma unroll
        for (int r = 0; r < 4; ++r)
            bq[rt][r] = bias_q[w * 32 + rt * 16 + lg * 4 + r];
    #pragma unroll
    for (int nt = 0; nt < 4; ++nt) {
        float m = -1e30f;
        #pragma unroll
        for (int rt = 0; rt < 2; ++rt)
            #pragma unroll
            for (int r = 0; r < 4; ++r) {
                float q = acc[rt][nt][r] + bq[rt][r];
                acc[rt][nt][r] = q;
                m = fmaxf(m, q);
            }
        m = fmaxf(m, __shfl_xor(m, 16));
        m = fmaxf(m, __shfl_xor(m, 32));
        float s = 0.f;
        #pragma unroll
        for (int rt = 0; rt < 2; ++rt)
            #pragma unroll
            for (int r = 0; r < 4; ++r) {
                float e = __expf(acc[rt][nt][r] - m);
                acc[rt][nt][r] = e;
                s += e;
            }
        s += __shfl_xor(s, 16);
        s += __shfl_xor(s, 32);
        float inv = 1.0f / s;
        #pragma unroll
        for (int rt = 0; rt < 2; ++rt)
            #pragma unroll
            for (int r = 0; r < 4; ++r)
                acc[rt][nt][r] *= inv;
    }

    __syncthreads();
    {
        uint2* qh = (uint2*)xs_hi;
        uint2* ql = (uint2*)xs_lo;
        int half = (lg & 1);
        #pragma unroll
        for (int rt = 0; rt < 2; ++rt) {
            int kb = rt * 2 + (lg >> 1);
            #pragma unroll
            for (int nt = 0; nt < 4; ++nt) {
                unsigned h0, l0, h1, l1;
                hilo2(acc[rt][nt][0], acc[rt][nt][1], h0, l0);
                hilo2(acc[rt][nt][2], acc[rt][nt][3], h1, l1);
                int idx = ((w * 4 + kb) * 64 + nt * 16 + l15) * 2 + half;
                qh[idx] = make_uint2(h0, h1);
                ql[idx] = make_uint2(l0, l1);
            }
        }
    }
    __syncthreads();

    f32x4 acc2[2][4];
    #pragma unroll
    for (int rt = 0; rt < 2; ++rt)
        #pragma unroll
        for (int nt = 0; nt < 4; ++nt)
            acc2[rt][nt] = (f32x4){0.f, 0.f, 0.f, 0.f};
    const uint4* mh4 = (const uint4*)(mhi + (size_t)b * 8192);
    const uint4* ml4 = (const uint4*)(mlo + (size_t)b * 8192);
    #pragma unroll
    for (int ks = 0; ks < 4; ++ks) {
        bf16x8 bh[4], bl[4];
        #pragma unroll
        for (int nt = 0; nt < 4; ++nt) {
            bh[nt] = __builtin_bit_cast(bf16x8, xs_hi[(ks * 4 + lg) * 64 + nt * 16 + l15]);
            bl[nt] = __builtin_bit_cast(bf16x8, xs_lo[(ks * 4 + lg) * 64 + nt * 16 + l15]);
        }
        #pragma unroll
        for (int rt = 0; rt < 2; ++rt) {
            int rg = 2 * w + rt;
            bf16x8 ah = __builtin_bit_cast(bf16x8, mh4[(rg * 4 + ks) * 64 + lane]);
            bf16x8 al = __builtin_bit_cast(bf16x8, ml4[(rg * 4 + ks) * 64 + lane]);
            #pragma unroll
            for (int nt = 0; nt < 4; ++nt) {
                acc2[rt][nt] = __builtin_amdgcn_mfma_f32_16x16x32_bf16(ah, bh[nt], acc2[rt][nt], 0, 0, 0);
                acc2[rt][nt] = __builtin_amdgcn_mfma_f32_16x16x32_bf16(ah, bl[nt], acc2[rt][nt], 0, 0, 0);
                acc2[rt][nt] = __builtin_amdgcn_mfma_f32_16x16x32_bf16(al, bh[nt], acc2[rt][nt], 0, 0, 0);
            }
        }
    }
    float* ob = out + (size_t)b * (128 * 4096) + n0;
    #pragma unroll
    for (int rt = 0; rt < 2; ++rt)
        #pragma unroll
        for (int r = 0; r < 4; ++r) {
            int ch = w * 32 + rt * 16 + lg * 4 + r;
            float bo = bias_o[ch];
            #pragma unroll
            for (int nt = 0; nt < 4; ++nt)
                ob[(size_t)ch * 4096 + nt * 16 + l15] = acc2[rt][nt][r] + bo;
        }
}

extern "C" void kernel_launch(void* const* d_in, const int* in_sizes, int n_in,
                              void* d_out, int out_size, void* d_ws, size_t ws_size,
                              hipStream_t stream) {
    const float* x     = (const float*)d_in[0];
    const float* w_qkv = (const float*)d_in[1];
    const float* wA_q  = (const float*)d_in[2];
    const float* bA_q  = (const float*)d_in[3];
    const float* wB_q  = (const float*)d_in[4];
    const float* bB_q  = (const float*)d_in[5];
    const float* wA_k  = (const float*)d_in[6];
    const float* bA_k  = (const float*)d_in[7];
    const float* wB_k  = (const float*)d_in[8];
    const float* bB_k  = (const float*)d_in[9];
    const float* wA_v  = (const float*)d_in[10];
    const float* bA_v  = (const float*)d_in[11];
    const float* wB_v  = (const float*)d_in[12];
    const float* bB_v  = (const float*)d_in[13];
    const float* w_out = (const float*)d_in[14];
    const float* b_out = (const float*)d_in[15];
    float* out = (float*)d_out;

    float* ws = (float*)d_ws;
    float*    Wt      = ws;                           // 49152 f
    float*    beff    = ws + 49152;                   // 384 f
    float*    part    = ws + 49536;                   // 16*4*64*1056 = 4325376 f
    unsigned* wall_hi = (unsigned*)(ws + 4374912);    // 24576 u32
    unsigned* wall_lo = (unsigned*)(ws + 4399488);    // 24576 u32
    unsigned* mhi     = (unsigned*)(ws + 4424064);    // 131072 u32
    unsigned* mlo     = (unsigned*)(ws + 4555136);    // 131072 u32

    fold_kernel<<<192, 256, 0, stream>>>(w_qkv,
        wA_q, bA_q, wB_q, bB_q, wA_k, bA_k, wB_k, bB_k, wA_v, bA_v, wB_v, bB_v,
        Wt, beff);
    wfrag_kernel<<<96, 256, 0, stream>>>(Wt, wall_hi, wall_lo);
    ctx_mfma_kernel<<<dim3(NCHUNK, 16), 256, 0, stream>>>(x,
        (const uint4*)wall_hi, (const uint4*)wall_lo, part);
    combine_m_kernel<<<dim3(4, 16), 256, 0, stream>>>(part, w_out, beff, mhi, mlo);
    pass_b_kernel<<<dim3(64, 16), 256, 0, stream>>>(x,
        (const uint4*)wall_hi, (const uint4*)wall_lo, beff, mhi, mlo, b_out, out);
}

// Round 16
// 67.123 us; speedup vs baseline: 3.3728x; 1.0173x over previous
//
#include <hip/hip_runtime.h>

// loraLinearAttention on MI355X.
// R13->R14: occupancy caps removed on both hot kernels + kernel-count cut.
// ctx: xs aliased into kv (LDS 36.9KB), single-bf16 W_kv (64 MFMA), rt-major
// GEMM1 with early bf16 pack (holds 32 u32 not 64 f32 -> VGPR ~100) =>
// 4 blocks/CU tail-free. pass_b: single-bf16 x/qs (LDS 17.4KB, 128 MFMA).
// combine: ch-outer ILP reduce (NCHUNK=64). prep: fold+wfrag merged, Wt gone.

typedef float f32x4 __attribute__((ext_vector_type(4)));
typedef short bf16x8 __attribute__((ext_vector_type(8)));

#define SCALING 0.25f
#define SCALE   0.17677669529663687f   /* 32^-0.5 */
#define NCHUNK  64                     /* 64-px chunks per (b,h) */

__device__ __forceinline__ unsigned short f2bf_rn(float x) {
    union { float f; unsigned u; } v; v.f = x;
    unsigned r = v.u + 0x7FFFu + ((v.u >> 16) & 1u);
    return (unsigned short)(r >> 16);
}
__device__ __forceinline__ float bf2f(unsigned short h) {
    union { unsigned u; float f; } v; v.u = ((unsigned)h) << 16;
    return v.f;
}
__device__ __forceinline__ void hilo2(float a, float b, unsigned& hi, unsigned& lo) {
    unsigned short ah = f2bf_rn(a), bh = f2bf_rn(b);
    unsigned short al = f2bf_rn(a - bf2f(ah)), bl = f2bf_rn(b - bf2f(bh));
    hi = (unsigned)ah | ((unsigned)bh << 16);
    lo = (unsigned)al | ((unsigned)bl << 16);
}
__device__ __forceinline__ unsigned pack2(float a, float b) {
    return (unsigned)f2bf_rn(a) | ((unsigned)f2bf_rn(b) << 16);
}

// W_eff[m][o][c] = w_qkv + 0.25*wB.wA, computed on the fly.
__device__ __forceinline__ float weff(
    const float* __restrict__ w_qkv, const float* __restrict__ wA,
    const float* __restrict__ wB, int m, int o, int c)
{
    float s = w_qkv[(m * 128 + o) * 128 + c];
    #pragma unroll
    for (int r = 0; r < 4; ++r)
        s += SCALING * wB[o * 4 + r] * wA[r * 128 + c];
    return s;
}

// grid 97 x 256. Blocks 0..95: fragment packs (tid 0..24575: first 8192 =
// Wq A-frag hi/lo pairs, next 16384 = Wkv A-frag single-bf16 pairs).
// Block 96: beff (q and v biases; k bias is mathematically dropped).
__global__ __launch_bounds__(256) void prep_kernel(
    const float* __restrict__ w_qkv,
    const float* __restrict__ wA_q, const float* __restrict__ bA_q,
    const float* __restrict__ wB_q, const float* __restrict__ bB_q,
    const float* __restrict__ wA_k, const float* __restrict__ bA_k,
    const float* __restrict__ wB_k, const float* __restrict__ bB_k,
    const float* __restrict__ wA_v, const float* __restrict__ bA_v,
    const float* __restrict__ wB_v, const float* __restrict__ bB_v,
    unsigned* __restrict__ wqhi, unsigned* __restrict__ wqlo,
    unsigned* __restrict__ wkv, float* __restrict__ beff)
{
    const int t = threadIdx.x;
    if (blockIdx.x == 96) {
        for (int ii = t; ii < 384; ii += 256) {
            int mm = ii >> 7, oo = ii & 127;
            const float* wBm = (mm == 0) ? wB_q : (mm == 1) ? wB_k : wB_v;
            const float* bAm = (mm == 0) ? bA_q : (mm == 1) ? bA_k : bA_v;
            const float* bBm = (mm == 0) ? bB_q : (mm == 1) ? bB_k : bB_v;
            float bb = bBm[oo];
            #pragma unroll
            for (int r = 0; r < 4; ++r) bb += wBm[oo * 4 + r] * bAm[r];
            beff[ii] = SCALING * bb;
        }
        return;
    }
    int tid = blockIdx.x * 256 + t;
    if (tid < 8192) {                       // Wq A-frag, hi/lo
        int fp = tid;
        int f = fp * 2;
        int i = f & 7;
        int l = (f >> 3) & 63;
        int rtks = f >> 9;
        int rt = rtks >> 2, ks = rtks & 3;
        int o = rt * 16 + (l & 15);
        int c = ks * 32 + ((l >> 4) & 3) * 8 + i;
        float a = weff(w_qkv, wA_q, wB_q, 0, o, c);
        float b = weff(w_qkv, wA_q, wB_q, 0, o, c + 1);
        unsigned hi, lo;
        hilo2(a, b, hi, lo);
        wqhi[fp] = hi; wqlo[fp] = lo;
    } else {                                // Wkv A-frag, single bf16
        int fp = tid - 8192;
        int f = fp * 2;
        int i = f & 7;
        int l = (f >> 3) & 63;
        int rtks = f >> 9;                  // 0..63
        int rt = rtks >> 2, ks = rtks & 3;  // rt 0..15
        int row = rt * 16 + (l & 15);       // kv row 0..255
        int c = ks * 32 + ((l >> 4) & 3) * 8 + i;
        int m = 1 + (row >> 7), o = row & 127;
        const float* wA = (m == 1) ? wA_k : wA_v;
        const float* wB = (m == 1) ? wB_k : wB_v;
        float a = weff(w_qkv, wA, wB, m, o, c);
        float b = weff(w_qkv, wA, wB, m, o, c + 1);
        wkv[fp] = pack2(a, b);
    }
}

// grid (chunk=64, b=16) = 1024 blocks, 256 threads, 36.9KB LDS (4 blocks/CU).
// One 64-px tile. xs (16KB, aliased into kv) -> GEMM1 rt-major (single-bf16
// W, 64 MFMA, results packed to bf16 in regs) -> barrier -> kv writes ->
// barrier -> ctx phase (P.V^T + l via ones-MFMA). No biases (exact: exp(bk)
// cancels in ctx/l; bv folded into combine).
__global__ __launch_bounds__(256) void ctx_mfma_kernel(
    const float* __restrict__ x, const unsigned* __restrict__ wkv,
    float* __restrict__ part)
{
    __shared__ __align__(16) char smem[36864];
    uint4* xs = (uint4*)smem;                     // bytes 0..16383 (dead after GEMM1)
    unsigned short* kv = (unsigned short*)smem;   // [256][72] bf16
    const int t = threadIdx.x;
    const int lane = t & 63;
    const int w = __builtin_amdgcn_readfirstlane(t >> 6);
    const int chunk = blockIdx.x, b = blockIdx.y;
    const int lg = lane >> 4, l15 = lane & 15;
    const float* xb = x + (size_t)b * (128 * 4096);
    const int n0 = chunk * 64;
    const uint4* wkv4 = (const uint4*)wkv;

    // stage x single-bf16 B-frags
    #pragma unroll
    for (int p = 0; p < 4; ++p) {
        float v[8];
        #pragma unroll
        for (int j = 0; j < 8; ++j)
            v[j] = xb[(size_t)((p * 4 + w) * 8 + j) * 4096 + n0 + lane];
        xs[(p * 4 + w) * 64 + lane] = make_uint4(
            pack2(v[0], v[1]), pack2(v[2], v[3]),
            pack2(v[4], v[5]), pack2(v[6], v[7]));
    }
    __syncthreads();

    // GEMM1 rt-major: wave w -> kv rows 64w..+63; results packed early.
    unsigned pk[4][8];                   // [rt][nt*2+rr]
    #pragma unroll
    for (int rt = 0; rt < 4; ++rt) {
        f32x4 acc[4];
        #pragma unroll
        for (int nt = 0; nt < 4; ++nt) acc[nt] = (f32x4){0.f, 0.f, 0.f, 0.f};
        #pragma unroll
        for (int ks = 0; ks < 4; ++ks) {
            bf16x8 ah = __builtin_bit_cast(bf16x8,
                wkv4[((4 * w + rt) * 4 + ks) * 64 + lane]);
            #pragma unroll
            for (int nt = 0; nt < 4; ++nt) {
                bf16x8 bh = __builtin_bit_cast(bf16x8,
                    xs[(ks * 4 + lg) * 64 + nt * 16 + l15]);
                acc[nt] = __builtin_amdgcn_mfma_f32_16x16x32_bf16(ah, bh, acc[nt], 0, 0, 0);
            }
        }
        #pragma unroll
        for (int nt = 0; nt < 4; ++nt) {
            float v0 = acc[nt][0], v1 = acc[nt][1];
            float v2 = acc[nt][2], v3 = acc[nt][3];
            if (w < 2) {                 // K waves: exp in regs
                v0 = __expf(v0); v1 = __expf(v1);
                v2 = __expf(v2); v3 = __expf(v3);
            }
            pk[rt][nt * 2]     = pack2(v0, v1);
            pk[rt][nt * 2 + 1] = pack2(v2, v3);
        }
    }
    __syncthreads();                     // all xs reads done (kv overwrites)
    #pragma unroll
    for (int rt = 0; rt < 4; ++rt)
        #pragma unroll
        for (int nt = 0; nt < 4; ++nt)
            #pragma unroll
            for (int rr = 0; rr < 2; ++rr) {
                unsigned u = pk[rt][nt * 2 + rr];
                int row0 = 64 * w + 16 * rt + lg * 4 + rr * 2;
                int px = nt * 16 + l15;
                kv[row0 * 72 + px] = (unsigned short)u;
                kv[(row0 + 1) * 72 + px] = (unsigned short)(u >> 16);
            }
    __syncthreads();

    // ctx phase: wave w = head w (R13-validated)
    bf16x8 ones;
    #pragma unroll
    for (int i = 0; i < 8; ++i) ones[i] = (short)0x3F80;
    f32x4 ctx_acc[2][2];
    f32x4 l_acc[2];
    #pragma unroll
    for (int rt = 0; rt < 2; ++rt) {
        l_acc[rt] = (f32x4){0.f, 0.f, 0.f, 0.f};
        #pragma unroll
        for (int et = 0; et < 2; ++et)
            ctx_acc[rt][et] = (f32x4){0.f, 0.f, 0.f, 0.f};
    }
    #pragma unroll
    for (int ks2 = 0; ks2 < 2; ++ks2) {
        int pxb = ks2 * 32 + lg * 8;
        bf16x8 ph[2], vh[2];
        #pragma unroll
        for (int rt = 0; rt < 2; ++rt)
            ph[rt] = __builtin_bit_cast(bf16x8, *(const uint4*)&kv[(32 * w + 16 * rt + l15) * 72 + pxb]);
        #pragma unroll
        for (int et = 0; et < 2; ++et)
            vh[et] = __builtin_bit_cast(bf16x8, *(const uint4*)&kv[(128 + 32 * w + 16 * et + l15) * 72 + pxb]);
        #pragma unroll
        for (int rt = 0; rt < 2; ++rt) {
            #pragma unroll
            for (int et = 0; et < 2; ++et)
                ctx_acc[rt][et] = __builtin_amdgcn_mfma_f32_16x16x32_bf16(ph[rt], vh[et], ctx_acc[rt][et], 0, 0, 0);
            l_acc[rt] = __builtin_amdgcn_mfma_f32_16x16x32_bf16(ph[rt], ones, l_acc[rt], 0, 0, 0);
        }
    }
    float* pout = part + (size_t)((b * 4 + w) * NCHUNK + chunk) * 1056;
    #pragma unroll
    for (int rt = 0; rt < 2; ++rt) {
        #pragma unroll
        for (int et = 0; et < 2; ++et)
            #pragma unroll
            for (int r = 0; r < 4; ++r)
                pout[(16 * rt + lg * 4 + r) * 32 + 16 * et + l15] = ctx_acc[rt][et][r];
        if (l15 == 0)
            #pragma unroll
            for (int r = 0; r < 4; ++r)
                pout[1024 + 16 * rt + lg * 4 + r] = l_acc[rt][r];
    }
}

// grid (4 heads, 16 batches), 256 threads, ~22.5 KB LDS.
__global__ __launch_bounds__(256) void combine_m_kernel(
    const float* __restrict__ part, const float* __restrict__ w_out,
    const float* __restrict__ beff,
    unsigned* __restrict__ mhi, unsigned* __restrict__ mlo)
{
    __shared__ float ctx_s[32 * 33];
    __shared__ float w_s[128 * 33];
    __shared__ float lpart_s[8][32];
    __shared__ float linv_s[32];
    __shared__ float bv_s[32];
    const int t = threadIdx.x;
    const int h = blockIdx.x, b = blockIdx.y;
    const float* pb = part + (size_t)((b * 4 + h) * NCHUNK) * 1056;

    {
        int g = t >> 5, d = t & 31;
        float lp = 0.f;
        #pragma unroll
        for (int c8 = 0; c8 < 8; ++c8)
            lp += pb[(size_t)(g * 8 + c8) * 1056 + 1024 + d];
        lpart_s[g][d] = lp;
    }
    if (t < 32) bv_s[t] = beff[256 + h * 32 + t];
    #pragma unroll
    for (int i = 0; i < 16; ++i) {
        int idx = i * 256 + t;
        int e = idx & 31, o = idx >> 5;
        w_s[o * 33 + e] = w_out[o * 128 + h * 32 + e];
    }
    float csum[4] = {0.f, 0.f, 0.f, 0.f};
    #pragma unroll 1
    for (int ch = 0; ch < NCHUNK; ++ch) {
        #pragma unroll
        for (int i = 0; i < 4; ++i)
            csum[i] += pb[(size_t)ch * 1056 + i * 256 + t];
    }
    __syncthreads();
    if (t < 32) {
        float l = 0.f;
        #pragma unroll
        for (int g = 0; g < 8; ++g) l += lpart_s[g][t];
        linv_s[t] = 1.0f / (l * 4096.0f);
    }
    __syncthreads();
    #pragma unroll
    for (int i = 0; i < 4; ++i) {
        int idx = i * 256 + t;
        int d = idx >> 5, e = idx & 31;
        ctx_s[d * 33 + e] = csum[i] * linv_s[d] + bv_s[e] * (1.0f / 4096.0f);
    }
    __syncthreads();
    #pragma unroll 1
    for (int it = 0; it < 8; ++it) {
        int p = it * 256 + t;
        int rt = p >> 8;
        int l = (p >> 2) & 63;
        int ip = p & 3;
        int o = rt * 16 + (l & 15);
        int d0 = (l >> 4) * 8 + 2 * ip;
        float v0 = 0.f, v1 = 0.f;
        #pragma unroll
        for (int e = 0; e < 32; ++e) {
            float wv = w_s[o * 33 + e];
            v0 = fmaf(wv, ctx_s[d0 * 33 + e], v0);
            v1 = fmaf(wv, ctx_s[(d0 + 1) * 33 + e], v1);
        }
        v0 *= SCALE; v1 *= SCALE;
        unsigned hi, lo;
        hilo2(v0, v1, hi, lo);
        size_t fp = (size_t)b * 8192 + ((rt * 4 + h) * 64 + l) * 4 + ip;
        mhi[fp] = hi;
        mlo[fp] = lo;
    }
}

// grid (tile=64, b=16), 256 threads, 17.4KB LDS. x and qs single-bf16;
// Wq and M hi/lo (GEMM1/GEMM2 = 2 MFMA per product).
__global__ __launch_bounds__(256) void pass_b_kernel(
    const float* __restrict__ x,
    const uint4* __restrict__ wqhi, const uint4* __restrict__ wqlo,
    const float* __restrict__ beff,
    const unsigned* __restrict__ mhi, const unsigned* __restrict__ mlo,
    const float* __restrict__ b_out, float* __restrict__ out)
{
    __shared__ uint4 xs[1024];           // 16 KB: x, then qs (B-frag layout)
    __shared__ float bias_q[128];
    __shared__ float bias_o[128];
    const int t = threadIdx.x;
    const int tile = blockIdx.x, b = blockIdx.y;
    const int lane = t & 63;
    const int w = __builtin_amdgcn_readfirstlane(t >> 6);
    const int n0 = tile * 64;
    const float* xb = x + (size_t)b * (128 * 4096);

    if (t < 128) { bias_q[t] = beff[t]; bias_o[t] = b_out[t]; }

    #pragma unroll
    for (int p = 0; p < 4; ++p) {
        float v[8];
        #pragma unroll
        for (int j = 0; j < 8; ++j)
            v[j] = xb[(size_t)((p * 4 + w) * 8 + j) * 4096 + n0 + lane];
        xs[(p * 4 + w) * 64 + lane] = make_uint4(
            pack2(v[0], v[1]), pack2(v[2], v[3]),
            pack2(v[4], v[5]), pack2(v[6], v[7]));
    }
    __syncthreads();

    const int lg = lane >> 4;
    const int l15 = lane & 15;

    // GEMM1: q = Wq.x (Wq hi/lo, x single)
    f32x4 acc[2][4];
    #pragma unroll
    for (int rt = 0; rt < 2; ++rt)
        #pragma unroll
        for (int nt = 0; nt < 4; ++nt)
            acc[rt][nt] = (f32x4){0.f, 0.f, 0.f, 0.f};
    #pragma unroll
    for (int ks = 0; ks < 4; ++ks) {
        bf16x8 bh[4];
        #pragma unroll
        for (int nt = 0; nt < 4; ++nt)
            bh[nt] = __builtin_bit_cast(bf16x8, xs[(ks * 4 + lg) * 64 + nt * 16 + l15]);
        #pragma unroll
        for (int rt = 0; rt < 2; ++rt) {
            int rg = 2 * w + rt;
            bf16x8 ah = __builtin_bit_cast(bf16x8, wqhi[(rg * 4 + ks) * 64 + lane]);
            bf16x8 al = __builtin_bit_cast(bf16x8, wqlo[(rg * 4 + ks) * 64 + lane]);
            #pragma unroll
            for (int nt = 0; nt < 4; ++nt) {
                acc[rt][nt] = __builtin_amdgcn_mfma_f32_16x16x32_bf16(ah, bh[nt], acc[rt][nt], 0, 0, 0);
                acc[rt][nt] = __builtin_amdgcn_mfma_f32_16x16x32_bf16(al, bh[nt], acc[rt][nt], 0, 0, 0);
            }
        }
    }

    float bq[2][4];
    #pragma unroll
    for (int rt = 0; rt < 2; ++rt)
        #pragma unroll
        for (int r = 0; r < 4; ++r)
            bq[rt][r] = bias_q[w * 32 + rt * 16 + lg * 4 + r];
    #pragma unroll
    for (int nt = 0; nt < 4; ++nt) {
        float m = -1e30f;
        #pragma unroll
        for (int rt = 0; rt < 2; ++rt)
            #pragma unroll
            for (int r = 0; r < 4; ++r) {
                float q = acc[rt][nt][r] + bq[rt][r];
                acc[rt][nt][r] = q;
                m = fmaxf(m, q);
            }
        m = fmaxf(m, __shfl_xor(m, 16));
        m = fmaxf(m, __shfl_xor(m, 32));
        float s = 0.f;
        #pragma unroll
        for (int rt = 0; rt < 2; ++rt)
            #pragma unroll
            for (int r = 0; r < 4; ++r) {
                float e = __expf(acc[rt][nt][r] - m);
                acc[rt][nt][r] = e;
                s += e;
            }
        s += __shfl_xor(s, 16);
        s += __shfl_xor(s, 32);
        float inv = 1.0f / s;
        #pragma unroll
        for (int rt = 0; rt < 2; ++rt)
            #pragma unroll
            for (int r = 0; r < 4; ++r)
                acc[rt][nt][r] *= inv;
    }

    __syncthreads();                     // GEMM1 xs reads done
    {   // qs -> xs, single bf16, B-frag layout
        uint2* q2 = (uint2*)xs;
        int half = (lg & 1);
        #pragma unroll
        for (int rt = 0; rt < 2; ++rt) {
            int kb = rt * 2 + (lg >> 1);
            #pragma unroll
            for (int nt = 0; nt < 4; ++nt) {
                int idx = ((w * 4 + kb) * 64 + nt * 16 + l15) * 2 + half;
                q2[idx] = make_uint2(pack2(acc[rt][nt][0], acc[rt][nt][1]),
                                     pack2(acc[rt][nt][2], acc[rt][nt][3]));
            }
        }
    }
    __syncthreads();

    // GEMM2: out = M.qs (M hi/lo, qs single)
    f32x4 acc2[2][4];
    #pragma unroll
    for (int rt = 0; rt < 2; ++rt)
        #pragma unroll
        for (int nt = 0; nt < 4; ++nt)
            acc2[rt][nt] = (f32x4){0.f, 0.f, 0.f, 0.f};
    const uint4* mh4 = (const uint4*)(mhi + (size_t)b * 8192);
    const uint4* ml4 = (const uint4*)(mlo + (size_t)b * 8192);
    #pragma unroll
    for (int ks = 0; ks < 4; ++ks) {
        bf16x8 bh[4];
        #pragma unroll
        for (int nt = 0; nt < 4; ++nt)
            bh[nt] = __builtin_bit_cast(bf16x8, xs[(ks * 4 + lg) * 64 + nt * 16 + l15]);
        #pragma unroll
        for (int rt = 0; rt < 2; ++rt) {
            int rg = 2 * w + rt;
            bf16x8 ah = __builtin_bit_cast(bf16x8, mh4[(rg * 4 + ks) * 64 + lane]);
            bf16x8 al = __builtin_bit_cast(bf16x8, ml4[(rg * 4 + ks) * 64 + lane]);
            #pragma unroll
            for (int nt = 0; nt < 4; ++nt) {
                acc2[rt][nt] = __builtin_amdgcn_mfma_f32_16x16x32_bf16(ah, bh[nt], acc2[rt][nt], 0, 0, 0);
                acc2[rt][nt] = __builtin_amdgcn_mfma_f32_16x16x32_bf16(al, bh[nt], acc2[rt][nt], 0, 0, 0);
            }
        }
    }
    float* ob = out + (size_t)b * (128 * 4096) + n0;
    #pragma unroll
    for (int rt = 0; rt < 2; ++rt)
        #pragma unroll
        for (int r = 0; r < 4; ++r) {
            int ch = w * 32 + rt * 16 + lg * 4 + r;
            float bo = bias_o[ch];
            #pragma unroll
            for (int nt = 0; nt < 4; ++nt)
                ob[(size_t)ch * 4096 + nt * 16 + l15] = acc2[rt][nt][r] + bo;
        }
}

extern "C" void kernel_launch(void* const* d_in, const int* in_sizes, int n_in,
                              void* d_out, int out_size, void* d_ws, size_t ws_size,
                              hipStream_t stream) {
    const float* x     = (const float*)d_in[0];
    const float* w_qkv = (const float*)d_in[1];
    const float* wA_q  = (const float*)d_in[2];
    const float* bA_q  = (const float*)d_in[3];
    const float* wB_q  = (const float*)d_in[4];
    const float* bB_q  = (const float*)d_in[5];
    const float* wA_k  = (const float*)d_in[6];
    const float* bA_k  = (const float*)d_in[7];
    const float* wB_k  = (const float*)d_in[8];
    const float* bB_k  = (const float*)d_in[9];
    const float* wA_v  = (const float*)d_in[10];
    const float* bA_v  = (const float*)d_in[11];
    const float* wB_v  = (const float*)d_in[12];
    const float* bB_v  = (const float*)d_in[13];
    const float* w_out = (const float*)d_in[14];
    const float* b_out = (const float*)d_in[15];
    float* out = (float*)d_out;

    float* ws = (float*)d_ws;
    float*    beff = ws;                              // 384 f
    float*    part = ws + 384;                        // 16*4*64*1056 = 4325376 f
    unsigned* wqhi = (unsigned*)(ws + 4325760);       // 8192 u32
    unsigned* wqlo = (unsigned*)(ws + 4333952);       // 8192 u32
    unsigned* wkv  = (unsigned*)(ws + 4342144);       // 16384 u32
    unsigned* mhi  = (unsigned*)(ws + 4358528);       // 131072 u32
    unsigned* mlo  = (unsigned*)(ws + 4489600);       // 131072 u32

    prep_kernel<<<97, 256, 0, stream>>>(w_qkv,
        wA_q, bA_q, wB_q, bB_q, wA_k, bA_k, wB_k, bB_k, wA_v, bA_v, wB_v, bB_v,
        wqhi, wqlo, wkv, beff);
    ctx_mfma_kernel<<<dim3(NCHUNK, 16), 256, 0, stream>>>(x, wkv, part);
    combine_m_kernel<<<dim3(4, 16), 256, 0, stream>>>(part, w_out, beff, mhi, mlo);
    pass_b_kernel<<<dim3(64, 16), 256, 0, stream>>>(x,
        (const uint4*)wqhi, (const uint4*)wqlo, beff, mhi, mlo, b_out, out);
}

// Round 17
// 65.320 us; speedup vs baseline: 3.4659x; 1.0276x over previous
//
#include <hip/hip_runtime.h>

// loraLinearAttention on MI355X.
// R16->R17: q fused into ctx. pass_b previously re-read+re-staged all of x
// just for GEMM1(q)+softmax; ctx already stages x. New ctx: 512 threads,
// waves 0-3 = q (head w, single-bf16 Wq, in-reg softmax, qs B-frags ->
// global, L3-resident), waves 4-7 = K/V (R14 early-pack body). ctx phase:
// waves 0-3 P.V^T per head, waves 4-7 the l ones-MFMAs. out_kernel = lean
// GEMM2-only (qs frags + M hi/lo -> out). LDS 36.9KB, 16 waves/CU as before.

typedef float f32x4 __attribute__((ext_vector_type(4)));
typedef short bf16x8 __attribute__((ext_vector_type(8)));

#define SCALING 0.25f
#define SCALE   0.17677669529663687f   /* 32^-0.5 */
#define NCHUNK  64                     /* 64-px chunks per (b,h) */

__device__ __forceinline__ unsigned short f2bf_rn(float x) {
    union { float f; unsigned u; } v; v.f = x;
    unsigned r = v.u + 0x7FFFu + ((v.u >> 16) & 1u);
    return (unsigned short)(r >> 16);
}
__device__ __forceinline__ float bf2f(unsigned short h) {
    union { unsigned u; float f; } v; v.u = ((unsigned)h) << 16;
    return v.f;
}
__device__ __forceinline__ void hilo2(float a, float b, unsigned& hi, unsigned& lo) {
    unsigned short ah = f2bf_rn(a), bh = f2bf_rn(b);
    unsigned short al = f2bf_rn(a - bf2f(ah)), bl = f2bf_rn(b - bf2f(bh));
    hi = (unsigned)ah | ((unsigned)bh << 16);
    lo = (unsigned)al | ((unsigned)bl << 16);
}
__device__ __forceinline__ unsigned pack2(float a, float b) {
    return (unsigned)f2bf_rn(a) | ((unsigned)f2bf_rn(b) << 16);
}

__device__ __forceinline__ float weff(
    const float* __restrict__ w_qkv, const float* __restrict__ wA,
    const float* __restrict__ wB, int m, int o, int c)
{
    float s = w_qkv[(m * 128 + o) * 128 + c];
    #pragma unroll
    for (int r = 0; r < 4; ++r)
        s += SCALING * wB[o * 4 + r] * wA[r * 128 + c];
    return s;
}

// grid 97 x 256. tid<8192: Wq A-frag single-bf16 pairs; tid 8192..24575:
// Wkv A-frag single-bf16 pairs. Block 96: beff (q bias for softmax, v bias
// for combine; k bias mathematically dropped).
__global__ __launch_bounds__(256) void prep_kernel(
    const float* __restrict__ w_qkv,
    const float* __restrict__ wA_q, const float* __restrict__ bA_q,
    const float* __restrict__ wB_q, const float* __restrict__ bB_q,
    const float* __restrict__ wA_k, const float* __restrict__ bA_k,
    const float* __restrict__ wB_k, const float* __restrict__ bB_k,
    const float* __restrict__ wA_v, const float* __restrict__ bA_v,
    const float* __restrict__ wB_v, const float* __restrict__ bB_v,
    unsigned* __restrict__ wq, unsigned* __restrict__ wkv,
    float* __restrict__ beff)
{
    const int t = threadIdx.x;
    if (blockIdx.x == 96) {
        for (int ii = t; ii < 384; ii += 256) {
            int mm = ii >> 7, oo = ii & 127;
            const float* wBm = (mm == 0) ? wB_q : (mm == 1) ? wB_k : wB_v;
            const float* bAm = (mm == 0) ? bA_q : (mm == 1) ? bA_k : bA_v;
            const float* bBm = (mm == 0) ? bB_q : (mm == 1) ? bB_k : bB_v;
            float bb = bBm[oo];
            #pragma unroll
            for (int r = 0; r < 4; ++r) bb += wBm[oo * 4 + r] * bAm[r];
            beff[ii] = SCALING * bb;
        }
        return;
    }
    int tid = blockIdx.x * 256 + t;
    if (tid < 8192) {                       // Wq A-frag, single bf16
        int fp = tid;
        int f = fp * 2;
        int i = f & 7;
        int l = (f >> 3) & 63;
        int rgks = f >> 9;                  // 0..31
        int rg = rgks >> 2, ks = rgks & 3;  // rg 0..7
        int o = rg * 16 + (l & 15);         // q row 0..127
        int c = ks * 32 + ((l >> 4) & 3) * 8 + i;
        wq[fp] = pack2(weff(w_qkv, wA_q, wB_q, 0, o, c),
                       weff(w_qkv, wA_q, wB_q, 0, o, c + 1));
    } else {                                // Wkv A-frag, single bf16
        int fp = tid - 8192;
        int f = fp * 2;
        int i = f & 7;
        int l = (f >> 3) & 63;
        int rtks = f >> 9;                  // 0..63
        int rt = rtks >> 2, ks = rtks & 3;  // rt 0..15
        int row = rt * 16 + (l & 15);       // kv row 0..255
        int c = ks * 32 + ((l >> 4) & 3) * 8 + i;
        int m = 1 + (row >> 7), o = row & 127;
        const float* wA = (m == 1) ? wA_k : wA_v;
        const float* wB = (m == 1) ? wB_k : wB_v;
        wkv[fp] = pack2(weff(w_qkv, wA, wB, m, o, c),
                        weff(w_qkv, wA, wB, m, o, c + 1));
    }
}

// grid (chunk=64, b=16) = 1024 blocks, 512 threads (8 waves), 36.9KB LDS.
// One 64-px tile. Stage xs (2 ch-groups/wave) -> barrier -> GEMM1:
// waves 0-3: q head w (32 MFMA) + bias + softmax + qs B-frags -> global;
// waves 4-7: kv rows 64(w-4).. (32 MFMA, exp for w<6, early bf16 pack)
// -> barrier -> kv to LDS -> barrier -> ctx: waves 0-3 P.V^T head w,
// waves 4-7 l for head w-4. part out.
__global__ __launch_bounds__(512) void ctx_fused_kernel(
    const float* __restrict__ x, const unsigned* __restrict__ wq,
    const unsigned* __restrict__ wkv, const float* __restrict__ beff,
    float* __restrict__ part, uint4* __restrict__ qs)
{
    __shared__ __align__(16) char smem[36864];
    uint4* xs = (uint4*)smem;                     // 16 KB (dead after GEMM1)
    unsigned short* kv = (unsigned short*)smem;   // [256][72] bf16
    const int t = threadIdx.x;
    const int lane = t & 63;
    const int w = __builtin_amdgcn_readfirstlane(t >> 6);  // 0..7
    const int chunk = blockIdx.x, b = blockIdx.y;
    const int lg = lane >> 4, l15 = lane & 15;
    const float* xb = x + (size_t)b * (128 * 4096);
    const int n0 = chunk * 64;
    const uint4* wq4 = (const uint4*)wq;
    const uint4* wkv4 = (const uint4*)wkv;

    // stage x single-bf16 B-frags: wave w -> channel groups 2w, 2w+1
    #pragma unroll
    for (int g2 = 0; g2 < 2; ++g2) {
        int g = w * 2 + g2;
        float v[8];
        #pragma unroll
        for (int j = 0; j < 8; ++j)
            v[j] = xb[(size_t)(g * 8 + j) * 4096 + n0 + lane];
        xs[g * 64 + lane] = make_uint4(
            pack2(v[0], v[1]), pack2(v[2], v[3]),
            pack2(v[4], v[5]), pack2(v[6], v[7]));
    }
    __syncthreads();

    unsigned pk[4][8];                   // kv waves: packed GEMM1 results

    if (w < 4) {
        // ===== q waves: head w, rows 32w+16rt+lg*4+r =====
        f32x4 acc[2][4];
        #pragma unroll
        for (int rt = 0; rt < 2; ++rt)
            #pragma unroll
            for (int nt = 0; nt < 4; ++nt)
                acc[rt][nt] = (f32x4){0.f, 0.f, 0.f, 0.f};
        #pragma unroll
        for (int ks = 0; ks < 4; ++ks) {
            bf16x8 bh[4];
            #pragma unroll
            for (int nt = 0; nt < 4; ++nt)
                bh[nt] = __builtin_bit_cast(bf16x8, xs[(ks * 4 + lg) * 64 + nt * 16 + l15]);
            #pragma unroll
            for (int rt = 0; rt < 2; ++rt) {
                bf16x8 ah = __builtin_bit_cast(bf16x8,
                    wq4[((2 * w + rt) * 4 + ks) * 64 + lane]);
                #pragma unroll
                for (int nt = 0; nt < 4; ++nt)
                    acc[rt][nt] = __builtin_amdgcn_mfma_f32_16x16x32_bf16(ah, bh[nt], acc[rt][nt], 0, 0, 0);
            }
        }
        float bq[2][4];
        #pragma unroll
        for (int rt = 0; rt < 2; ++rt)
            #pragma unroll
            for (int r = 0; r < 4; ++r)
                bq[rt][r] = beff[w * 32 + rt * 16 + lg * 4 + r];
        #pragma unroll
        for (int nt = 0; nt < 4; ++nt) {
            float m = -1e30f;
            #pragma unroll
            for (int rt = 0; rt < 2; ++rt)
                #pragma unroll
                for (int r = 0; r < 4; ++r) {
                    float q = acc[rt][nt][r] + bq[rt][r];
                    acc[rt][nt][r] = q;
                    m = fmaxf(m, q);
                }
            m = fmaxf(m, __shfl_xor(m, 16));
            m = fmaxf(m, __shfl_xor(m, 32));
            float s = 0.f;
            #pragma unroll
            for (int rt = 0; rt < 2; ++rt)
                #pragma unroll
                for (int r = 0; r < 4; ++r) {
                    float e = __expf(acc[rt][nt][r] - m);
                    acc[rt][nt][r] = e;
                    s += e;
                }
            s += __shfl_xor(s, 16);
            s += __shfl_xor(s, 32);
            float inv = 1.0f / s;
            #pragma unroll
            for (int rt = 0; rt < 2; ++rt)
                #pragma unroll
                for (int r = 0; r < 4; ++r)
                    acc[rt][nt][r] *= inv;
        }
        // qs B-frags -> global (head w occupies k-slice ks=w of GEMM2)
        uint2* q2g = (uint2*)(qs + ((size_t)b * 64 + chunk) * 1024);
        int half = (lg & 1);
        #pragma unroll
        for (int rt = 0; rt < 2; ++rt) {
            int kb = rt * 2 + (lg >> 1);
            #pragma unroll
            for (int nt = 0; nt < 4; ++nt) {
                int idx = ((w * 4 + kb) * 64 + nt * 16 + l15) * 2 + half;
                q2g[idx] = make_uint2(pack2(acc[rt][nt][0], acc[rt][nt][1]),
                                      pack2(acc[rt][nt][2], acc[rt][nt][3]));
            }
        }
    } else {
        // ===== kv waves: rows 64(w-4)..+63; exp for K (w<6) =====
        #pragma unroll
        for (int rt = 0; rt < 4; ++rt) {
            f32x4 acc[4];
            #pragma unroll
            for (int nt = 0; nt < 4; ++nt) acc[nt] = (f32x4){0.f, 0.f, 0.f, 0.f};
            #pragma unroll
            for (int ks = 0; ks < 4; ++ks) {
                bf16x8 ah = __builtin_bit_cast(bf16x8,
                    wkv4[((4 * (w - 4) + rt) * 4 + ks) * 64 + lane]);
                #pragma unroll
                for (int nt = 0; nt < 4; ++nt) {
                    bf16x8 bh = __builtin_bit_cast(bf16x8,
                        xs[(ks * 4 + lg) * 64 + nt * 16 + l15]);
                    acc[nt] = __builtin_amdgcn_mfma_f32_16x16x32_bf16(ah, bh, acc[nt], 0, 0, 0);
                }
            }
            #pragma unroll
            for (int nt = 0; nt < 4; ++nt) {
                float v0 = acc[nt][0], v1 = acc[nt][1];
                float v2 = acc[nt][2], v3 = acc[nt][3];
                if (w < 6) {             // K waves: exp in regs
                    v0 = __expf(v0); v1 = __expf(v1);
                    v2 = __expf(v2); v3 = __expf(v3);
                }
                pk[rt][nt * 2]     = pack2(v0, v1);
                pk[rt][nt * 2 + 1] = pack2(v2, v3);
            }
        }
    }
    __syncthreads();                     // all xs reads done (kv overwrites)
    if (w >= 4) {
        #pragma unroll
        for (int rt = 0; rt < 4; ++rt)
            #pragma unroll
            for (int nt = 0; nt < 4; ++nt)
                #pragma unroll
                for (int rr = 0; rr < 2; ++rr) {
                    unsigned u = pk[rt][nt * 2 + rr];
                    int row0 = 64 * (w - 4) + 16 * rt + lg * 4 + rr * 2;
                    int px = nt * 16 + l15;
                    kv[row0 * 72 + px] = (unsigned short)u;
                    kv[(row0 + 1) * 72 + px] = (unsigned short)(u >> 16);
                }
    }
    __syncthreads();

    if (w < 4) {
        // ctx: head w, P rows 32w.., V rows 128+32w..
        f32x4 ctx_acc[2][2];
        #pragma unroll
        for (int rt = 0; rt < 2; ++rt)
            #pragma unroll
            for (int et = 0; et < 2; ++et)
                ctx_acc[rt][et] = (f32x4){0.f, 0.f, 0.f, 0.f};
        #pragma unroll
        for (int ks2 = 0; ks2 < 2; ++ks2) {
            int pxb = ks2 * 32 + lg * 8;
            bf16x8 ph[2], vh[2];
            #pragma unroll
            for (int rt = 0; rt < 2; ++rt)
                ph[rt] = __builtin_bit_cast(bf16x8, *(const uint4*)&kv[(32 * w + 16 * rt + l15) * 72 + pxb]);
            #pragma unroll
            for (int et = 0; et < 2; ++et)
                vh[et] = __builtin_bit_cast(bf16x8, *(const uint4*)&kv[(128 + 32 * w + 16 * et + l15) * 72 + pxb]);
            #pragma unroll
            for (int rt = 0; rt < 2; ++rt)
                #pragma unroll
                for (int et = 0; et < 2; ++et)
                    ctx_acc[rt][et] = __builtin_amdgcn_mfma_f32_16x16x32_bf16(ph[rt], vh[et], ctx_acc[rt][et], 0, 0, 0);
        }
        float* pout = part + (size_t)((b * 4 + w) * NCHUNK + chunk) * 1056;
        #pragma unroll
        for (int rt = 0; rt < 2; ++rt)
            #pragma unroll
            for (int et = 0; et < 2; ++et)
                #pragma unroll
                for (int r = 0; r < 4; ++r)
                    pout[(16 * rt + lg * 4 + r) * 32 + 16 * et + l15] = ctx_acc[rt][et][r];
    } else {
        // l for head hh = w-4 via ones-MFMA
        int hh = w - 4;
        bf16x8 ones;
        #pragma unroll
        for (int i = 0; i < 8; ++i) ones[i] = (short)0x3F80;
        f32x4 l_acc[2];
        #pragma unroll
        for (int rt = 0; rt < 2; ++rt) l_acc[rt] = (f32x4){0.f, 0.f, 0.f, 0.f};
        #pragma unroll
        for (int ks2 = 0; ks2 < 2; ++ks2) {
            int pxb = ks2 * 32 + lg * 8;
            #pragma unroll
            for (int rt = 0; rt < 2; ++rt) {
                bf16x8 ph = __builtin_bit_cast(bf16x8, *(const uint4*)&kv[(32 * hh + 16 * rt + l15) * 72 + pxb]);
                l_acc[rt] = __builtin_amdgcn_mfma_f32_16x16x32_bf16(ph, ones, l_acc[rt], 0, 0, 0);
            }
        }
        if (l15 == 0) {
            float* pout = part + (size_t)((b * 4 + hh) * NCHUNK + chunk) * 1056;
            #pragma unroll
            for (int rt = 0; rt < 2; ++rt)
                #pragma unroll
                for (int r = 0; r < 4; ++r)
                    pout[1024 + 16 * rt + lg * 4 + r] = l_acc[rt][r];
        }
    }
}

// grid (4 heads, 16 batches), 256 threads, ~22.5 KB LDS. Unchanged (R16).
__global__ __launch_bounds__(256) void combine_m_kernel(
    const float* __restrict__ part, const float* __restrict__ w_out,
    const float* __restrict__ beff,
    unsigned* __restrict__ mhi, unsigned* __restrict__ mlo)
{
    __shared__ float ctx_s[32 * 33];
    __shared__ float w_s[128 * 33];
    __shared__ float lpart_s[8][32];
    __shared__ float linv_s[32];
    __shared__ float bv_s[32];
    const int t = threadIdx.x;
    const int h = blockIdx.x, b = blockIdx.y;
    const float* pb = part + (size_t)((b * 4 + h) * NCHUNK) * 1056;

    {
        int g = t >> 5, d = t & 31;
        float lp = 0.f;
        #pragma unroll
        for (int c8 = 0; c8 < 8; ++c8)
            lp += pb[(size_t)(g * 8 + c8) * 1056 + 1024 + d];
        lpart_s[g][d] = lp;
    }
    if (t < 32) bv_s[t] = beff[256 + h * 32 + t];
    #pragma unroll
    for (int i = 0; i < 16; ++i) {
        int idx = i * 256 + t;
        int e = idx & 31, o = idx >> 5;
        w_s[o * 33 + e] = w_out[o * 128 + h * 32 + e];
    }
    float csum[4] = {0.f, 0.f, 0.f, 0.f};
    #pragma unroll 1
    for (int ch = 0; ch < NCHUNK; ++ch) {
        #pragma unroll
        for (int i = 0; i < 4; ++i)
            csum[i] += pb[(size_t)ch * 1056 + i * 256 + t];
    }
    __syncthreads();
    if (t < 32) {
        float l = 0.f;
        #pragma unroll
        for (int g = 0; g < 8; ++g) l += lpart_s[g][t];
        linv_s[t] = 1.0f / (l * 4096.0f);
    }
    __syncthreads();
    #pragma unroll
    for (int i = 0; i < 4; ++i) {
        int idx = i * 256 + t;
        int d = idx >> 5, e = idx & 31;
        ctx_s[d * 33 + e] = csum[i] * linv_s[d] + bv_s[e] * (1.0f / 4096.0f);
    }
    __syncthreads();
    #pragma unroll 1
    for (int it = 0; it < 8; ++it) {
        int p = it * 256 + t;
        int rt = p >> 8;
        int l = (p >> 2) & 63;
        int ip = p & 3;
        int o = rt * 16 + (l & 15);
        int d0 = (l >> 4) * 8 + 2 * ip;
        float v0 = 0.f, v1 = 0.f;
        #pragma unroll
        for (int e = 0; e < 32; ++e) {
            float wv = w_s[o * 33 + e];
            v0 = fmaf(wv, ctx_s[d0 * 33 + e], v0);
            v1 = fmaf(wv, ctx_s[(d0 + 1) * 33 + e], v1);
        }
        v0 *= SCALE; v1 *= SCALE;
        unsigned hi, lo;
        hilo2(v0, v1, hi, lo);
        size_t fp = (size_t)b * 8192 + ((rt * 4 + h) * 64 + l) * 4 + ip;
        mhi[fp] = hi;
        mlo[fp] = lo;
    }
}

// grid (tile=64, b=16), 256 threads. GEMM2 only: out = M.qs + b_out.
__global__ __launch_bounds__(256) void out_kernel(
    const uint4* __restrict__ qs,
    const unsigned* __restrict__ mhi, const unsigned* __restrict__ mlo,
    const float* __restrict__ b_out, float* __restrict__ out)
{
    __shared__ float bias_o[128];
    const int t = threadIdx.x;
    const int tile = blockIdx.x, b = blockIdx.y;
    const int lane = t & 63;
    const int w = __builtin_amdgcn_readfirstlane(t >> 6);
    const int lg = lane >> 4, l15 = lane & 15;
    if (t < 128) bias_o[t] = b_out[t];
    __syncthreads();

    const uint4* q4 = qs + ((size_t)b * 64 + tile) * 1024;
    const uint4* mh4 = (const uint4*)(mhi + (size_t)b * 8192);
    const uint4* ml4 = (const uint4*)(mlo + (size_t)b * 8192);
    f32x4 acc2[2][4];
    #pragma unroll
    for (int rt = 0; rt < 2; ++rt)
        #pragma unroll
        for (int nt = 0; nt < 4; ++nt)
            acc2[rt][nt] = (f32x4){0.f, 0.f, 0.f, 0.f};
    #pragma unroll
    for (int ks = 0; ks < 4; ++ks) {
        bf16x8 bh[4];
        #pragma unroll
        for (int nt = 0; nt < 4; ++nt)
            bh[nt] = __builtin_bit_cast(bf16x8, q4[(ks * 4 + lg) * 64 + nt * 16 + l15]);
        #pragma unroll
        for (int rt = 0; rt < 2; ++rt) {
            int rg = 2 * w + rt;
            bf16x8 ah = __builtin_bit_cast(bf16x8, mh4[(rg * 4 + ks) * 64 + lane]);
            bf16x8 al = __builtin_bit_cast(bf16x8, ml4[(rg * 4 + ks) * 64 + lane]);
            #pragma unroll
            for (int nt = 0; nt < 4; ++nt) {
                acc2[rt][nt] = __builtin_amdgcn_mfma_f32_16x16x32_bf16(ah, bh[nt], acc2[rt][nt], 0, 0, 0);
                acc2[rt][nt] = __builtin_amdgcn_mfma_f32_16x16x32_bf16(al, bh[nt], acc2[rt][nt], 0, 0, 0);
            }
        }
    }
    float* ob = out + (size_t)b * (128 * 4096) + tile * 64;
    #pragma unroll
    for (int rt = 0; rt < 2; ++rt)
        #pragma unroll
        for (int r = 0; r < 4; ++r) {
            int ch = w * 32 + rt * 16 + lg * 4 + r;
            float bo = bias_o[ch];
            #pragma unroll
            for (int nt = 0; nt < 4; ++nt)
                ob[(size_t)ch * 4096 + nt * 16 + l15] = acc2[rt][nt][r] + bo;
        }
}

extern "C" void kernel_launch(void* const* d_in, const int* in_sizes, int n_in,
                              void* d_out, int out_size, void* d_ws, size_t ws_size,
                              hipStream_t stream) {
    const float* x     = (const float*)d_in[0];
    const float* w_qkv = (const float*)d_in[1];
    const float* wA_q  = (const float*)d_in[2];
    const float* bA_q  = (const float*)d_in[3];
    const float* wB_q  = (const float*)d_in[4];
    const float* bB_q  = (const float*)d_in[5];
    const float* wA_k  = (const float*)d_in[6];
    const float* bA_k  = (const float*)d_in[7];
    const float* wB_k  = (const float*)d_in[8];
    const float* bB_k  = (const float*)d_in[9];
    const float* wA_v  = (const float*)d_in[10];
    const float* bA_v  = (const float*)d_in[11];
    const float* wB_v  = (const float*)d_in[12];
    const float* bB_v  = (const float*)d_in[13];
    const float* w_out = (const float*)d_in[14];
    const float* b_out = (const float*)d_in[15];
    float* out = (float*)d_out;

    float* ws = (float*)d_ws;
    float*    beff = ws;                              // 384 f
    float*    part = ws + 384;                        // 4325376 f
    unsigned* wq   = (unsigned*)(ws + 4325760);       // 8192 u32
    unsigned* wkv  = (unsigned*)(ws + 4333952);       // 16384 u32
    unsigned* mhi  = (unsigned*)(ws + 4350336);       // 131072 u32
    unsigned* mlo  = (unsigned*)(ws + 4481408);       // 131072 u32
    uint4*    qs   = (uint4*)(ws + 4612480);          // 65536 uint4 (1 MB... 16*64*1024)

    prep_kernel<<<97, 256, 0, stream>>>(w_qkv,
        wA_q, bA_q, wB_q, bB_q, wA_k, bA_k, wB_k, bB_k, wA_v, bA_v, wB_v, bB_v,
        wq, wkv, beff);
    ctx_fused_kernel<<<dim3(NCHUNK, 16), 512, 0, stream>>>(x, wq, wkv, beff,
        part, qs);
    combine_m_kernel<<<dim3(4, 16), 256, 0, stream>>>(part, w_out, beff, mhi, mlo);
    out_kernel<<<dim3(64, 16), 256, 0, stream>>>(qs, mhi, mlo, b_out, out);
}

// Round 18
// 54.681 us; speedup vs baseline: 4.1402x; 1.1945x over previous
//
#include <hip/hip_runtime.h>

// loraLinearAttention on MI355X.
// R17->R18: (1) ctx_fused 512->256 threads, UNIFORM waves: wave w does
// q(head w) -> kv(rows 64w, early-pack) -> ctx+l(head w) sequentially.
// R17's 512-thr 2-role split risked blocks/CU=floor(waves/8) quantization
// (VGPR 129-170 -> 1 block/CU) + q-path barrier skew. Sequential roles let
// regs overlay (q acc dead before kv pk lives). (2) combine split 2-stage:
// combine_a (512 blocks, 8-chunk partial sums) + combine_b (64 blocks,
// final reduce + M-pack) - fixes 64-block grid starvation.

typedef float f32x4 __attribute__((ext_vector_type(4)));
typedef short bf16x8 __attribute__((ext_vector_type(8)));

#define SCALING 0.25f
#define SCALE   0.17677669529663687f   /* 32^-0.5 */
#define NCHUNK  64                     /* 64-px chunks per (b,h) */

__device__ __forceinline__ unsigned short f2bf_rn(float x) {
    union { float f; unsigned u; } v; v.f = x;
    unsigned r = v.u + 0x7FFFu + ((v.u >> 16) & 1u);
    return (unsigned short)(r >> 16);
}
__device__ __forceinline__ float bf2f(unsigned short h) {
    union { unsigned u; float f; } v; v.u = ((unsigned)h) << 16;
    return v.f;
}
__device__ __forceinline__ void hilo2(float a, float b, unsigned& hi, unsigned& lo) {
    unsigned short ah = f2bf_rn(a), bh = f2bf_rn(b);
    unsigned short al = f2bf_rn(a - bf2f(ah)), bl = f2bf_rn(b - bf2f(bh));
    hi = (unsigned)ah | ((unsigned)bh << 16);
    lo = (unsigned)al | ((unsigned)bl << 16);
}
__device__ __forceinline__ unsigned pack2(float a, float b) {
    return (unsigned)f2bf_rn(a) | ((unsigned)f2bf_rn(b) << 16);
}

__device__ __forceinline__ float weff(
    const float* __restrict__ w_qkv, const float* __restrict__ wA,
    const float* __restrict__ wB, int m, int o, int c)
{
    float s = w_qkv[(m * 128 + o) * 128 + c];
    #pragma unroll
    for (int r = 0; r < 4; ++r)
        s += SCALING * wB[o * 4 + r] * wA[r * 128 + c];
    return s;
}

// grid 97 x 256. tid<8192: Wq A-frag single-bf16 pairs; 8192..24575: Wkv.
// Block 96: beff (q bias for softmax, v bias for combine; k bias dropped).
__global__ __launch_bounds__(256) void prep_kernel(
    const float* __restrict__ w_qkv,
    const float* __restrict__ wA_q, const float* __restrict__ bA_q,
    const float* __restrict__ wB_q, const float* __restrict__ bB_q,
    const float* __restrict__ wA_k, const float* __restrict__ bA_k,
    const float* __restrict__ wB_k, const float* __restrict__ bB_k,
    const float* __restrict__ wA_v, const float* __restrict__ bA_v,
    const float* __restrict__ wB_v, const float* __restrict__ bB_v,
    unsigned* __restrict__ wq, unsigned* __restrict__ wkv,
    float* __restrict__ beff)
{
    const int t = threadIdx.x;
    if (blockIdx.x == 96) {
        for (int ii = t; ii < 384; ii += 256) {
            int mm = ii >> 7, oo = ii & 127;
            const float* wBm = (mm == 0) ? wB_q : (mm == 1) ? wB_k : wB_v;
            const float* bAm = (mm == 0) ? bA_q : (mm == 1) ? bA_k : bA_v;
            const float* bBm = (mm == 0) ? bB_q : (mm == 1) ? bB_k : bB_v;
            float bb = bBm[oo];
            #pragma unroll
            for (int r = 0; r < 4; ++r) bb += wBm[oo * 4 + r] * bAm[r];
            beff[ii] = SCALING * bb;
        }
        return;
    }
    int tid = blockIdx.x * 256 + t;
    if (tid < 8192) {                       // Wq A-frag, single bf16
        int fp = tid;
        int f = fp * 2;
        int i = f & 7;
        int l = (f >> 3) & 63;
        int rgks = f >> 9;                  // 0..31
        int rg = rgks >> 2, ks = rgks & 3;  // rg 0..7
        int o = rg * 16 + (l & 15);         // q row 0..127
        int c = ks * 32 + ((l >> 4) & 3) * 8 + i;
        wq[fp] = pack2(weff(w_qkv, wA_q, wB_q, 0, o, c),
                       weff(w_qkv, wA_q, wB_q, 0, o, c + 1));
    } else {                                // Wkv A-frag, single bf16
        int fp = tid - 8192;
        int f = fp * 2;
        int i = f & 7;
        int l = (f >> 3) & 63;
        int rtks = f >> 9;                  // 0..63
        int rt = rtks >> 2, ks = rtks & 3;  // rt 0..15
        int row = rt * 16 + (l & 15);       // kv row 0..255
        int c = ks * 32 + ((l >> 4) & 3) * 8 + i;
        int m = 1 + (row >> 7), o = row & 127;
        const float* wA = (m == 1) ? wA_k : wA_v;
        const float* wB = (m == 1) ? wB_k : wB_v;
        wkv[fp] = pack2(weff(w_qkv, wA, wB, m, o, c),
                        weff(w_qkv, wA, wB, m, o, c + 1));
    }
}

// grid (chunk=64, b=16) = 1024 blocks, 256 threads (4 waves), 36.9KB LDS.
// Wave w, sequentially: stage x quarter -> q head w (32 MFMA, softmax,
// qs->global) -> kv rows 64w (32 MFMA, exp for w<2, early pack) ->
// barrier -> kv->LDS -> barrier -> ctx P.V^T + l for head w -> part.
__global__ __launch_bounds__(256) void ctx_fused_kernel(
    const float* __restrict__ x, const unsigned* __restrict__ wq,
    const unsigned* __restrict__ wkv, const float* __restrict__ beff,
    float* __restrict__ part, uint4* __restrict__ qs)
{
    __shared__ __align__(16) char smem[36864];
    uint4* xs = (uint4*)smem;                     // 16 KB (dead after GEMM1s)
    unsigned short* kv = (unsigned short*)smem;   // [256][72] bf16
    const int t = threadIdx.x;
    const int lane = t & 63;
    const int w = __builtin_amdgcn_readfirstlane(t >> 6);  // 0..3
    const int chunk = blockIdx.x, b = blockIdx.y;
    const int lg = lane >> 4, l15 = lane & 15;
    const float* xb = x + (size_t)b * (128 * 4096);
    const int n0 = chunk * 64;
    const uint4* wq4 = (const uint4*)wq;
    const uint4* wkv4 = (const uint4*)wkv;

    // stage x single-bf16 B-frags: wave w -> channel groups p*4+w
    #pragma unroll
    for (int p = 0; p < 4; ++p) {
        int g = p * 4 + w;
        float v[8];
        #pragma unroll
        for (int j = 0; j < 8; ++j)
            v[j] = xb[(size_t)(g * 8 + j) * 4096 + n0 + lane];
        xs[g * 64 + lane] = make_uint4(
            pack2(v[0], v[1]), pack2(v[2], v[3]),
            pack2(v[4], v[5]), pack2(v[6], v[7]));
    }
    __syncthreads();

    // ===== q: head w, rows 32w+16rt+lg*4+r =====
    {
        f32x4 acc[2][4];
        #pragma unroll
        for (int rt = 0; rt < 2; ++rt)
            #pragma unroll
            for (int nt = 0; nt < 4; ++nt)
                acc[rt][nt] = (f32x4){0.f, 0.f, 0.f, 0.f};
        #pragma unroll
        for (int ks = 0; ks < 4; ++ks) {
            bf16x8 bh[4];
            #pragma unroll
            for (int nt = 0; nt < 4; ++nt)
                bh[nt] = __builtin_bit_cast(bf16x8, xs[(ks * 4 + lg) * 64 + nt * 16 + l15]);
            #pragma unroll
            for (int rt = 0; rt < 2; ++rt) {
                bf16x8 ah = __builtin_bit_cast(bf16x8,
                    wq4[((2 * w + rt) * 4 + ks) * 64 + lane]);
                #pragma unroll
                for (int nt = 0; nt < 4; ++nt)
                    acc[rt][nt] = __builtin_amdgcn_mfma_f32_16x16x32_bf16(ah, bh[nt], acc[rt][nt], 0, 0, 0);
            }
        }
        float bq[2][4];
        #pragma unroll
        for (int rt = 0; rt < 2; ++rt)
            #pragma unroll
            for (int r = 0; r < 4; ++r)
                bq[rt][r] = beff[w * 32 + rt * 16 + lg * 4 + r];
        #pragma unroll
        for (int nt = 0; nt < 4; ++nt) {
            float m = -1e30f;
            #pragma unroll
            for (int rt = 0; rt < 2; ++rt)
                #pragma unroll
                for (int r = 0; r < 4; ++r) {
                    float q = acc[rt][nt][r] + bq[rt][r];
                    acc[rt][nt][r] = q;
                    m = fmaxf(m, q);
                }
            m = fmaxf(m, __shfl_xor(m, 16));
            m = fmaxf(m, __shfl_xor(m, 32));
            float s = 0.f;
            #pragma unroll
            for (int rt = 0; rt < 2; ++rt)
                #pragma unroll
                for (int r = 0; r < 4; ++r) {
                    float e = __expf(acc[rt][nt][r] - m);
                    acc[rt][nt][r] = e;
                    s += e;
                }
            s += __shfl_xor(s, 16);
            s += __shfl_xor(s, 32);
            float inv = 1.0f / s;
            #pragma unroll
            for (int rt = 0; rt < 2; ++rt)
                #pragma unroll
                for (int r = 0; r < 4; ++r)
                    acc[rt][nt][r] *= inv;
        }
        uint2* q2g = (uint2*)(qs + ((size_t)b * 64 + chunk) * 1024);
        int half = (lg & 1);
        #pragma unroll
        for (int rt = 0; rt < 2; ++rt) {
            int kb = rt * 2 + (lg >> 1);
            #pragma unroll
            for (int nt = 0; nt < 4; ++nt) {
                int idx = ((w * 4 + kb) * 64 + nt * 16 + l15) * 2 + half;
                q2g[idx] = make_uint2(pack2(acc[rt][nt][0], acc[rt][nt][1]),
                                      pack2(acc[rt][nt][2], acc[rt][nt][3]));
            }
        }
    }

    // ===== kv: rows 64w..+63; exp for K (w<2); early bf16 pack =====
    unsigned pk[4][8];
    #pragma unroll
    for (int rt = 0; rt < 4; ++rt) {
        f32x4 acc[4];
        #pragma unroll
        for (int nt = 0; nt < 4; ++nt) acc[nt] = (f32x4){0.f, 0.f, 0.f, 0.f};
        #pragma unroll
        for (int ks = 0; ks < 4; ++ks) {
            bf16x8 ah = __builtin_bit_cast(bf16x8,
                wkv4[((4 * w + rt) * 4 + ks) * 64 + lane]);
            #pragma unroll
            for (int nt = 0; nt < 4; ++nt) {
                bf16x8 bh = __builtin_bit_cast(bf16x8,
                    xs[(ks * 4 + lg) * 64 + nt * 16 + l15]);
                acc[nt] = __builtin_amdgcn_mfma_f32_16x16x32_bf16(ah, bh, acc[nt], 0, 0, 0);
            }
        }
        #pragma unroll
        for (int nt = 0; nt < 4; ++nt) {
            float v0 = acc[nt][0], v1 = acc[nt][1];
            float v2 = acc[nt][2], v3 = acc[nt][3];
            if (w < 2) {                 // K waves: exp in regs
                v0 = __expf(v0); v1 = __expf(v1);
                v2 = __expf(v2); v3 = __expf(v3);
            }
            pk[rt][nt * 2]     = pack2(v0, v1);
            pk[rt][nt * 2 + 1] = pack2(v2, v3);
        }
    }
    __syncthreads();                     // all xs reads done (kv overwrites)
    #pragma unroll
    for (int rt = 0; rt < 4; ++rt)
        #pragma unroll
        for (int nt = 0; nt < 4; ++nt)
            #pragma unroll
            for (int rr = 0; rr < 2; ++rr) {
                unsigned u = pk[rt][nt * 2 + rr];
                int row0 = 64 * w + 16 * rt + lg * 4 + rr * 2;
                int px = nt * 16 + l15;
                kv[row0 * 72 + px] = (unsigned short)u;
                kv[(row0 + 1) * 72 + px] = (unsigned short)(u >> 16);
            }
    __syncthreads();

    // ===== ctx: head w (P rows 32w.., V rows 128+32w..) + l =====
    bf16x8 ones;
    #pragma unroll
    for (int i = 0; i < 8; ++i) ones[i] = (short)0x3F80;
    f32x4 ctx_acc[2][2];
    f32x4 l_acc[2];
    #pragma unroll
    for (int rt = 0; rt < 2; ++rt) {
        l_acc[rt] = (f32x4){0.f, 0.f, 0.f, 0.f};
        #pragma unroll
        for (int et = 0; et < 2; ++et)
            ctx_acc[rt][et] = (f32x4){0.f, 0.f, 0.f, 0.f};
    }
    #pragma unroll
    for (int ks2 = 0; ks2 < 2; ++ks2) {
        int pxb = ks2 * 32 + lg * 8;
        bf16x8 ph[2], vh[2];
        #pragma unroll
        for (int rt = 0; rt < 2; ++rt)
            ph[rt] = __builtin_bit_cast(bf16x8, *(const uint4*)&kv[(32 * w + 16 * rt + l15) * 72 + pxb]);
        #pragma unroll
        for (int et = 0; et < 2; ++et)
            vh[et] = __builtin_bit_cast(bf16x8, *(const uint4*)&kv[(128 + 32 * w + 16 * et + l15) * 72 + pxb]);
        #pragma unroll
        for (int rt = 0; rt < 2; ++rt) {
            #pragma unroll
            for (int et = 0; et < 2; ++et)
                ctx_acc[rt][et] = __builtin_amdgcn_mfma_f32_16x16x32_bf16(ph[rt], vh[et], ctx_acc[rt][et], 0, 0, 0);
            l_acc[rt] = __builtin_amdgcn_mfma_f32_16x16x32_bf16(ph[rt], ones, l_acc[rt], 0, 0, 0);
        }
    }
    float* pout = part + (size_t)((b * 4 + w) * NCHUNK + chunk) * 1056;
    #pragma unroll
    for (int rt = 0; rt < 2; ++rt) {
        #pragma unroll
        for (int et = 0; et < 2; ++et)
            #pragma unroll
            for (int r = 0; r < 4; ++r)
                pout[(16 * rt + lg * 4 + r) * 32 + 16 * et + l15] = ctx_acc[rt][et][r];
        if (l15 == 0)
            #pragma unroll
            for (int r = 0; r < 4; ++r)
                pout[1024 + 16 * rt + lg * 4 + r] = l_acc[rt][r];
    }
}

// grid (4 heads, 16 b, 8 groups), 256 threads: partial-reduce 8 chunks.
__global__ __launch_bounds__(256) void combine_a_kernel(
    const float* __restrict__ part, float* __restrict__ part2)
{
    const int t = threadIdx.x;
    const int h = blockIdx.x, b = blockIdx.y, g = blockIdx.z;
    const float* pb = part + (size_t)((b * 4 + h) * NCHUNK + g * 8) * 1056;
    float s[4] = {0.f, 0.f, 0.f, 0.f};
    #pragma unroll 1
    for (int ch = 0; ch < 8; ++ch) {
        #pragma unroll
        for (int i = 0; i < 4; ++i)
            s[i] += pb[(size_t)ch * 1056 + i * 256 + t];
    }
    float* po = part2 + (size_t)(((b * 4 + h) * 8) + g) * 1056;
    #pragma unroll
    for (int i = 0; i < 4; ++i) po[i * 256 + t] = s[i];
    if (t < 32) {
        float l = 0.f;
        #pragma unroll
        for (int ch = 0; ch < 8; ++ch) l += pb[(size_t)ch * 1056 + 1024 + t];
        po[1024 + t] = l;
    }
}

// grid (4 heads, 16 batches), 256 threads: final reduce + normalize + M-pack.
__global__ __launch_bounds__(256) void combine_b_kernel(
    const float* __restrict__ part2, const float* __restrict__ w_out,
    const float* __restrict__ beff,
    unsigned* __restrict__ mhi, unsigned* __restrict__ mlo)
{
    __shared__ float ctx_s[32 * 33];
    __shared__ float w_s[128 * 33];
    __shared__ float linv_s[32];
    __shared__ float bv_s[32];
    const int t = threadIdx.x;
    const int h = blockIdx.x, b = blockIdx.y;
    const float* pb = part2 + (size_t)((b * 4 + h) * 8) * 1056;

    if (t < 32) {
        float l = 0.f;
        #pragma unroll
        for (int p = 0; p < 8; ++p) l += pb[(size_t)p * 1056 + 1024 + t];
        linv_s[t] = 1.0f / (l * 4096.0f);
        bv_s[t] = beff[256 + h * 32 + t];
    }
    #pragma unroll
    for (int i = 0; i < 16; ++i) {
        int idx = i * 256 + t;
        int e = idx & 31, o = idx >> 5;
        w_s[o * 33 + e] = w_out[o * 128 + h * 32 + e];
    }
    float csum[4] = {0.f, 0.f, 0.f, 0.f};
    #pragma unroll
    for (int p = 0; p < 8; ++p) {
        #pragma unroll
        for (int i = 0; i < 4; ++i)
            csum[i] += pb[(size_t)p * 1056 + i * 256 + t];
    }
    __syncthreads();
    #pragma unroll
    for (int i = 0; i < 4; ++i) {
        int idx = i * 256 + t;
        int d = idx >> 5, e = idx & 31;
        ctx_s[d * 33 + e] = csum[i] * linv_s[d] + bv_s[e] * (1.0f / 4096.0f);
    }
    __syncthreads();
    #pragma unroll 1
    for (int it = 0; it < 8; ++it) {
        int p = it * 256 + t;
        int rt = p >> 8;
        int l = (p >> 2) & 63;
        int ip = p & 3;
        int o = rt * 16 + (l & 15);
        int d0 = (l >> 4) * 8 + 2 * ip;
        float v0 = 0.f, v1 = 0.f;
        #pragma unroll
        for (int e = 0; e < 32; ++e) {
            float wv = w_s[o * 33 + e];
            v0 = fmaf(wv, ctx_s[d0 * 33 + e], v0);
            v1 = fmaf(wv, ctx_s[(d0 + 1) * 33 + e], v1);
        }
        v0 *= SCALE; v1 *= SCALE;
        unsigned hi, lo;
        hilo2(v0, v1, hi, lo);
        size_t fp = (size_t)b * 8192 + ((rt * 4 + h) * 64 + l) * 4 + ip;
        mhi[fp] = hi;
        mlo[fp] = lo;
    }
}

// grid (tile=64, b=16), 256 threads. GEMM2 only: out = M.qs + b_out.
__global__ __launch_bounds__(256) void out_kernel(
    const uint4* __restrict__ qs,
    const unsigned* __restrict__ mhi, const unsigned* __restrict__ mlo,
    const float* __restrict__ b_out, float* __restrict__ out)
{
    __shared__ float bias_o[128];
    const int t = threadIdx.x;
    const int tile = blockIdx.x, b = blockIdx.y;
    const int lane = t & 63;
    const int w = __builtin_amdgcn_readfirstlane(t >> 6);
    const int lg = lane >> 4, l15 = lane & 15;
    if (t < 128) bias_o[t] = b_out[t];
    __syncthreads();

    const uint4* q4 = qs + ((size_t)b * 64 + tile) * 1024;
    const uint4* mh4 = (const uint4*)(mhi + (size_t)b * 8192);
    const uint4* ml4 = (const uint4*)(mlo + (size_t)b * 8192);
    f32x4 acc2[2][4];
    #pragma unroll
    for (int rt = 0; rt < 2; ++rt)
        #pragma unroll
        for (int nt = 0; nt < 4; ++nt)
            acc2[rt][nt] = (f32x4){0.f, 0.f, 0.f, 0.f};
    #pragma unroll
    for (int ks = 0; ks < 4; ++ks) {
        bf16x8 bh[4];
        #pragma unroll
        for (int nt = 0; nt < 4; ++nt)
            bh[nt] = __builtin_bit_cast(bf16x8, q4[(ks * 4 + lg) * 64 + nt * 16 + l15]);
        #pragma unroll
        for (int rt = 0; rt < 2; ++rt) {
            int rg = 2 * w + rt;
            bf16x8 ah = __builtin_bit_cast(bf16x8, mh4[(rg * 4 + ks) * 64 + lane]);
            bf16x8 al = __builtin_bit_cast(bf16x8, ml4[(rg * 4 + ks) * 64 + lane]);
            #pragma unroll
            for (int nt = 0; nt < 4; ++nt) {
                acc2[rt][nt] = __builtin_amdgcn_mfma_f32_16x16x32_bf16(ah, bh[nt], acc2[rt][nt], 0, 0, 0);
                acc2[rt][nt] = __builtin_amdgcn_mfma_f32_16x16x32_bf16(al, bh[nt], acc2[rt][nt], 0, 0, 0);
            }
        }
    }
    float* ob = out + (size_t)b * (128 * 4096) + tile * 64;
    #pragma unroll
    for (int rt = 0; rt < 2; ++rt)
        #pragma unroll
        for (int r = 0; r < 4; ++r) {
            int ch = w * 32 + rt * 16 + lg * 4 + r;
            float bo = bias_o[ch];
            #pragma unroll
            for (int nt = 0; nt < 4; ++nt)
                ob[(size_t)ch * 4096 + nt * 16 + l15] = acc2[rt][nt][r] + bo;
        }
}

extern "C" void kernel_launch(void* const* d_in, const int* in_sizes, int n_in,
                              void* d_out, int out_size, void* d_ws, size_t ws_size,
                              hipStream_t stream) {
    const float* x     = (const float*)d_in[0];
    const float* w_qkv = (const float*)d_in[1];
    const float* wA_q  = (const float*)d_in[2];
    const float* bA_q  = (const float*)d_in[3];
    const float* wB_q  = (const float*)d_in[4];
    const float* bB_q  = (const float*)d_in[5];
    const float* wA_k  = (const float*)d_in[6];
    const float* bA_k  = (const float*)d_in[7];
    const float* wB_k  = (const float*)d_in[8];
    const float* bB_k  = (const float*)d_in[9];
    const float* wA_v  = (const float*)d_in[10];
    const float* bA_v  = (const float*)d_in[11];
    const float* wB_v  = (const float*)d_in[12];
    const float* bB_v  = (const float*)d_in[13];
    const float* w_out = (const float*)d_in[14];
    const float* b_out = (const float*)d_in[15];
    float* out = (float*)d_out;

    float* ws = (float*)d_ws;
    float*    beff  = ws;                             // 384 f
    float*    part  = ws + 384;                       // 4325376 f
    float*    part2 = ws + 4325760;                   // 540672 f
    unsigned* wq    = (unsigned*)(ws + 4866432);      // 8192 u32
    unsigned* wkv   = (unsigned*)(ws + 4874624);      // 16384 u32
    unsigned* mhi   = (unsigned*)(ws + 4891008);      // 131072 u32
    unsigned* mlo   = (unsigned*)(ws + 5022080);      // 131072 u32
    uint4*    qs    = (uint4*)(ws + 5153152);         // 65536 uint4

    prep_kernel<<<97, 256, 0, stream>>>(w_qkv,
        wA_q, bA_q, wB_q, bB_q, wA_k, bA_k, wB_k, bB_k, wA_v, bA_v, wB_v, bB_v,
        wq, wkv, beff);
    ctx_fused_kernel<<<dim3(NCHUNK, 16), 256, 0, stream>>>(x, wq, wkv, beff,
        part, qs);
    combine_a_kernel<<<dim3(4, 16, 8), 256, 0, stream>>>(part, part2);
    combine_b_kernel<<<dim3(4, 16), 256, 0, stream>>>(part2, w_out, beff, mhi, mlo);
    out_kernel<<<dim3(64, 16), 256, 0, stream>>>(qs, mhi, mlo, b_out, out);
}

// Round 19
// 54.190 us; speedup vs baseline: 4.1777x; 1.0091x over previous
//
#include <hip/hip_runtime.h>

// loraLinearAttention on MI355X.
// R18->R19: (1) M single-bf16 (outputs are ~1e-5 absolute; absmax 7.5e-9 =
// 2.5e-4 RELATIVE already, so 2e-3-rel M costs ~5e-8 absmax - free). Halves
// out GEMM2 MFMA + simplifies combine_b pack. (2) out_kernel 32-px tiles,
// grid (128,16)=2048 blocks - 2x latency hiding on the HBM-bound out write.
// (3) ctx x-stage 2x16-load groups (was 4x8) - 2x loads in flight.

typedef float f32x4 __attribute__((ext_vector_type(4)));
typedef short bf16x8 __attribute__((ext_vector_type(8)));

#define SCALING 0.25f
#define SCALE   0.17677669529663687f   /* 32^-0.5 */
#define NCHUNK  64                     /* 64-px chunks per (b,h) */

__device__ __forceinline__ unsigned short f2bf_rn(float x) {
    union { float f; unsigned u; } v; v.f = x;
    unsigned r = v.u + 0x7FFFu + ((v.u >> 16) & 1u);
    return (unsigned short)(r >> 16);
}
__device__ __forceinline__ unsigned pack2(float a, float b) {
    return (unsigned)f2bf_rn(a) | ((unsigned)f2bf_rn(b) << 16);
}

__device__ __forceinline__ float weff(
    const float* __restrict__ w_qkv, const float* __restrict__ wA,
    const float* __restrict__ wB, int m, int o, int c)
{
    float s = w_qkv[(m * 128 + o) * 128 + c];
    #pragma unroll
    for (int r = 0; r < 4; ++r)
        s += SCALING * wB[o * 4 + r] * wA[r * 128 + c];
    return s;
}

// grid 97 x 256. tid<8192: Wq A-frag single-bf16 pairs; 8192..24575: Wkv.
// Block 96: beff (q bias for softmax, v bias for combine; k bias dropped).
__global__ __launch_bounds__(256) void prep_kernel(
    const float* __restrict__ w_qkv,
    const float* __restrict__ wA_q, const float* __restrict__ bA_q,
    const float* __restrict__ wB_q, const float* __restrict__ bB_q,
    const float* __restrict__ wA_k, const float* __restrict__ bA_k,
    const float* __restrict__ wB_k, const float* __restrict__ bB_k,
    const float* __restrict__ wA_v, const float* __restrict__ bA_v,
    const float* __restrict__ wB_v, const float* __restrict__ bB_v,
    unsigned* __restrict__ wq, unsigned* __restrict__ wkv,
    float* __restrict__ beff)
{
    const int t = threadIdx.x;
    if (blockIdx.x == 96) {
        for (int ii = t; ii < 384; ii += 256) {
            int mm = ii >> 7, oo = ii & 127;
            const float* wBm = (mm == 0) ? wB_q : (mm == 1) ? wB_k : wB_v;
            const float* bAm = (mm == 0) ? bA_q : (mm == 1) ? bA_k : bA_v;
            const float* bBm = (mm == 0) ? bB_q : (mm == 1) ? bB_k : bB_v;
            float bb = bBm[oo];
            #pragma unroll
            for (int r = 0; r < 4; ++r) bb += wBm[oo * 4 + r] * bAm[r];
            beff[ii] = SCALING * bb;
        }
        return;
    }
    int tid = blockIdx.x * 256 + t;
    if (tid < 8192) {                       // Wq A-frag, single bf16
        int fp = tid;
        int f = fp * 2;
        int i = f & 7;
        int l = (f >> 3) & 63;
        int rgks = f >> 9;                  // 0..31
        int rg = rgks >> 2, ks = rgks & 3;  // rg 0..7
        int o = rg * 16 + (l & 15);         // q row 0..127
        int c = ks * 32 + ((l >> 4) & 3) * 8 + i;
        wq[fp] = pack2(weff(w_qkv, wA_q, wB_q, 0, o, c),
                       weff(w_qkv, wA_q, wB_q, 0, o, c + 1));
    } else {                                // Wkv A-frag, single bf16
        int fp = tid - 8192;
        int f = fp * 2;
        int i = f & 7;
        int l = (f >> 3) & 63;
        int rtks = f >> 9;                  // 0..63
        int rt = rtks >> 2, ks = rtks & 3;  // rt 0..15
        int row = rt * 16 + (l & 15);       // kv row 0..255
        int c = ks * 32 + ((l >> 4) & 3) * 8 + i;
        int m = 1 + (row >> 7), o = row & 127;
        const float* wA = (m == 1) ? wA_k : wA_v;
        const float* wB = (m == 1) ? wB_k : wB_v;
        wkv[fp] = pack2(weff(w_qkv, wA, wB, m, o, c),
                        weff(w_qkv, wA, wB, m, o, c + 1));
    }
}

// grid (chunk=64, b=16) = 1024 blocks, 256 threads (4 waves), 36.9KB LDS.
// Wave w, sequentially: stage x quarter (2x16-load groups) -> q head w
// (32 MFMA, softmax, qs->global) -> kv rows 64w (32 MFMA, exp for w<2,
// early pack) -> barrier -> kv->LDS -> barrier -> ctx P.V^T + l -> part.
__global__ __launch_bounds__(256) void ctx_fused_kernel(
    const float* __restrict__ x, const unsigned* __restrict__ wq,
    const unsigned* __restrict__ wkv, const float* __restrict__ beff,
    float* __restrict__ part, uint4* __restrict__ qs)
{
    __shared__ __align__(16) char smem[36864];
    uint4* xs = (uint4*)smem;                     // 16 KB (dead after GEMM1s)
    unsigned short* kv = (unsigned short*)smem;   // [256][72] bf16
    const int t = threadIdx.x;
    const int lane = t & 63;
    const int w = __builtin_amdgcn_readfirstlane(t >> 6);  // 0..3
    const int chunk = blockIdx.x, b = blockIdx.y;
    const int lg = lane >> 4, l15 = lane & 15;
    const float* xb = x + (size_t)b * (128 * 4096);
    const int n0 = chunk * 64;
    const uint4* wq4 = (const uint4*)wq;
    const uint4* wkv4 = (const uint4*)wkv;

    // stage x single-bf16 B-frags: wave w -> channel groups p*4+w (p=0..3),
    // issued as two 16-load groups for deeper in-flight load queues.
    #pragma unroll
    for (int pp = 0; pp < 2; ++pp) {
        float v[16];
        #pragma unroll
        for (int g2 = 0; g2 < 2; ++g2) {
            int g = (pp * 2 + g2) * 4 + w;
            #pragma unroll
            for (int j = 0; j < 8; ++j)
                v[g2 * 8 + j] = xb[(size_t)(g * 8 + j) * 4096 + n0 + lane];
        }
        #pragma unroll
        for (int g2 = 0; g2 < 2; ++g2) {
            int g = (pp * 2 + g2) * 4 + w;
            xs[g * 64 + lane] = make_uint4(
                pack2(v[g2*8+0], v[g2*8+1]), pack2(v[g2*8+2], v[g2*8+3]),
                pack2(v[g2*8+4], v[g2*8+5]), pack2(v[g2*8+6], v[g2*8+7]));
        }
    }
    __syncthreads();

    // ===== q: head w, rows 32w+16rt+lg*4+r =====
    {
        f32x4 acc[2][4];
        #pragma unroll
        for (int rt = 0; rt < 2; ++rt)
            #pragma unroll
            for (int nt = 0; nt < 4; ++nt)
                acc[rt][nt] = (f32x4){0.f, 0.f, 0.f, 0.f};
        #pragma unroll
        for (int ks = 0; ks < 4; ++ks) {
            bf16x8 bh[4];
            #pragma unroll
            for (int nt = 0; nt < 4; ++nt)
                bh[nt] = __builtin_bit_cast(bf16x8, xs[(ks * 4 + lg) * 64 + nt * 16 + l15]);
            #pragma unroll
            for (int rt = 0; rt < 2; ++rt) {
                bf16x8 ah = __builtin_bit_cast(bf16x8,
                    wq4[((2 * w + rt) * 4 + ks) * 64 + lane]);
                #pragma unroll
                for (int nt = 0; nt < 4; ++nt)
                    acc[rt][nt] = __builtin_amdgcn_mfma_f32_16x16x32_bf16(ah, bh[nt], acc[rt][nt], 0, 0, 0);
            }
        }
        float bq[2][4];
        #pragma unroll
        for (int rt = 0; rt < 2; ++rt)
            #pragma unroll
            for (int r = 0; r < 4; ++r)
                bq[rt][r] = beff[w * 32 + rt * 16 + lg * 4 + r];
        #pragma unroll
        for (int nt = 0; nt < 4; ++nt) {
            float m = -1e30f;
            #pragma unroll
            for (int rt = 0; rt < 2; ++rt)
                #pragma unroll
                for (int r = 0; r < 4; ++r) {
                    float q = acc[rt][nt][r] + bq[rt][r];
                    acc[rt][nt][r] = q;
                    m = fmaxf(m, q);
                }
            m = fmaxf(m, __shfl_xor(m, 16));
            m = fmaxf(m, __shfl_xor(m, 32));
            float s = 0.f;
            #pragma unroll
            for (int rt = 0; rt < 2; ++rt)
                #pragma unroll
                for (int r = 0; r < 4; ++r) {
                    float e = __expf(acc[rt][nt][r] - m);
                    acc[rt][nt][r] = e;
                    s += e;
                }
            s += __shfl_xor(s, 16);
            s += __shfl_xor(s, 32);
            float inv = 1.0f / s;
            #pragma unroll
            for (int rt = 0; rt < 2; ++rt)
                #pragma unroll
                for (int r = 0; r < 4; ++r)
                    acc[rt][nt][r] *= inv;
        }
        uint2* q2g = (uint2*)(qs + ((size_t)b * 64 + chunk) * 1024);
        int half = (lg & 1);
        #pragma unroll
        for (int rt = 0; rt < 2; ++rt) {
            int kb = rt * 2 + (lg >> 1);
            #pragma unroll
            for (int nt = 0; nt < 4; ++nt) {
                int idx = ((w * 4 + kb) * 64 + nt * 16 + l15) * 2 + half;
                q2g[idx] = make_uint2(pack2(acc[rt][nt][0], acc[rt][nt][1]),
                                      pack2(acc[rt][nt][2], acc[rt][nt][3]));
            }
        }
    }

    // ===== kv: rows 64w..+63; exp for K (w<2); early bf16 pack =====
    unsigned pk[4][8];
    #pragma unroll
    for (int rt = 0; rt < 4; ++rt) {
        f32x4 acc[4];
        #pragma unroll
        for (int nt = 0; nt < 4; ++nt) acc[nt] = (f32x4){0.f, 0.f, 0.f, 0.f};
        #pragma unroll
        for (int ks = 0; ks < 4; ++ks) {
            bf16x8 ah = __builtin_bit_cast(bf16x8,
                wkv4[((4 * w + rt) * 4 + ks) * 64 + lane]);
            #pragma unroll
            for (int nt = 0; nt < 4; ++nt) {
                bf16x8 bh = __builtin_bit_cast(bf16x8,
                    xs[(ks * 4 + lg) * 64 + nt * 16 + l15]);
                acc[nt] = __builtin_amdgcn_mfma_f32_16x16x32_bf16(ah, bh, acc[nt], 0, 0, 0);
            }
        }
        #pragma unroll
        for (int nt = 0; nt < 4; ++nt) {
            float v0 = acc[nt][0], v1 = acc[nt][1];
            float v2 = acc[nt][2], v3 = acc[nt][3];
            if (w < 2) {                 // K waves: exp in regs
                v0 = __expf(v0); v1 = __expf(v1);
                v2 = __expf(v2); v3 = __expf(v3);
            }
            pk[rt][nt * 2]     = pack2(v0, v1);
            pk[rt][nt * 2 + 1] = pack2(v2, v3);
        }
    }
    __syncthreads();                     // all xs reads done (kv overwrites)
    #pragma unroll
    for (int rt = 0; rt < 4; ++rt)
        #pragma unroll
        for (int nt = 0; nt < 4; ++nt)
            #pragma unroll
            for (int rr = 0; rr < 2; ++rr) {
                unsigned u = pk[rt][nt * 2 + rr];
                int row0 = 64 * w + 16 * rt + lg * 4 + rr * 2;
                int px = nt * 16 + l15;
                kv[row0 * 72 + px] = (unsigned short)u;
                kv[(row0 + 1) * 72 + px] = (unsigned short)(u >> 16);
            }
    __syncthreads();

    // ===== ctx: head w (P rows 32w.., V rows 128+32w..) + l =====
    bf16x8 ones;
    #pragma unroll
    for (int i = 0; i < 8; ++i) ones[i] = (short)0x3F80;
    f32x4 ctx_acc[2][2];
    f32x4 l_acc[2];
    #pragma unroll
    for (int rt = 0; rt < 2; ++rt) {
        l_acc[rt] = (f32x4){0.f, 0.f, 0.f, 0.f};
        #pragma unroll
        for (int et = 0; et < 2; ++et)
            ctx_acc[rt][et] = (f32x4){0.f, 0.f, 0.f, 0.f};
    }
    #pragma unroll
    for (int ks2 = 0; ks2 < 2; ++ks2) {
        int pxb = ks2 * 32 + lg * 8;
        bf16x8 ph[2], vh[2];
        #pragma unroll
        for (int rt = 0; rt < 2; ++rt)
            ph[rt] = __builtin_bit_cast(bf16x8, *(const uint4*)&kv[(32 * w + 16 * rt + l15) * 72 + pxb]);
        #pragma unroll
        for (int et = 0; et < 2; ++et)
            vh[et] = __builtin_bit_cast(bf16x8, *(const uint4*)&kv[(128 + 32 * w + 16 * et + l15) * 72 + pxb]);
        #pragma unroll
        for (int rt = 0; rt < 2; ++rt) {
            #pragma unroll
            for (int et = 0; et < 2; ++et)
                ctx_acc[rt][et] = __builtin_amdgcn_mfma_f32_16x16x32_bf16(ph[rt], vh[et], ctx_acc[rt][et], 0, 0, 0);
            l_acc[rt] = __builtin_amdgcn_mfma_f32_16x16x32_bf16(ph[rt], ones, l_acc[rt], 0, 0, 0);
        }
    }
    float* pout = part + (size_t)((b * 4 + w) * NCHUNK + chunk) * 1056;
    #pragma unroll
    for (int rt = 0; rt < 2; ++rt) {
        #pragma unroll
        for (int et = 0; et < 2; ++et)
            #pragma unroll
            for (int r = 0; r < 4; ++r)
                pout[(16 * rt + lg * 4 + r) * 32 + 16 * et + l15] = ctx_acc[rt][et][r];
        if (l15 == 0)
            #pragma unroll
            for (int r = 0; r < 4; ++r)
                pout[1024 + 16 * rt + lg * 4 + r] = l_acc[rt][r];
    }
}

// grid (4 heads, 16 b, 8 groups), 256 threads: partial-reduce 8 chunks.
__global__ __launch_bounds__(256) void combine_a_kernel(
    const float* __restrict__ part, float* __restrict__ part2)
{
    const int t = threadIdx.x;
    const int h = blockIdx.x, b = blockIdx.y, g = blockIdx.z;
    const float* pb = part + (size_t)((b * 4 + h) * NCHUNK + g * 8) * 1056;
    float s[4] = {0.f, 0.f, 0.f, 0.f};
    #pragma unroll 1
    for (int ch = 0; ch < 8; ++ch) {
        #pragma unroll
        for (int i = 0; i < 4; ++i)
            s[i] += pb[(size_t)ch * 1056 + i * 256 + t];
    }
    float* po = part2 + (size_t)(((b * 4 + h) * 8) + g) * 1056;
    #pragma unroll
    for (int i = 0; i < 4; ++i) po[i * 256 + t] = s[i];
    if (t < 32) {
        float l = 0.f;
        #pragma unroll
        for (int ch = 0; ch < 8; ++ch) l += pb[(size_t)ch * 1056 + 1024 + t];
        po[1024 + t] = l;
    }
}

// grid (4 heads, 16 batches), 256 threads: final reduce + normalize +
// M-pack (SINGLE bf16).
__global__ __launch_bounds__(256) void combine_b_kernel(
    const float* __restrict__ part2, const float* __restrict__ w_out,
    const float* __restrict__ beff, unsigned* __restrict__ mpk)
{
    __shared__ float ctx_s[32 * 33];
    __shared__ float w_s[128 * 33];
    __shared__ float linv_s[32];
    __shared__ float bv_s[32];
    const int t = threadIdx.x;
    const int h = blockIdx.x, b = blockIdx.y;
    const float* pb = part2 + (size_t)((b * 4 + h) * 8) * 1056;

    if (t < 32) {
        float l = 0.f;
        #pragma unroll
        for (int p = 0; p < 8; ++p) l += pb[(size_t)p * 1056 + 1024 + t];
        linv_s[t] = 1.0f / (l * 4096.0f);
        bv_s[t] = beff[256 + h * 32 + t];
    }
    #pragma unroll
    for (int i = 0; i < 16; ++i) {
        int idx = i * 256 + t;
        int e = idx & 31, o = idx >> 5;
        w_s[o * 33 + e] = w_out[o * 128 + h * 32 + e];
    }
    float csum[4] = {0.f, 0.f, 0.f, 0.f};
    #pragma unroll
    for (int p = 0; p < 8; ++p) {
        #pragma unroll
        for (int i = 0; i < 4; ++i)
            csum[i] += pb[(size_t)p * 1056 + i * 256 + t];
    }
    __syncthreads();
    #pragma unroll
    for (int i = 0; i < 4; ++i) {
        int idx = i * 256 + t;
        int d = idx >> 5, e = idx & 31;
        ctx_s[d * 33 + e] = csum[i] * linv_s[d] + bv_s[e] * (1.0f / 4096.0f);
    }
    __syncthreads();
    #pragma unroll 1
    for (int it = 0; it < 8; ++it) {
        int p = it * 256 + t;
        int rt = p >> 8;
        int l = (p >> 2) & 63;
        int ip = p & 3;
        int o = rt * 16 + (l & 15);
        int d0 = (l >> 4) * 8 + 2 * ip;
        float v0 = 0.f, v1 = 0.f;
        #pragma unroll
        for (int e = 0; e < 32; ++e) {
            float wv = w_s[o * 33 + e];
            v0 = fmaf(wv, ctx_s[d0 * 33 + e], v0);
            v1 = fmaf(wv, ctx_s[(d0 + 1) * 33 + e], v1);
        }
        size_t fp = (size_t)b * 8192 + ((rt * 4 + h) * 64 + l) * 4 + ip;
        mpk[fp] = pack2(v0 * SCALE, v1 * SCALE);
    }
}

// grid (tile32=128, b=16) = 2048 blocks, 256 threads. GEMM2: out = M.qs
// + b_out, 32 px per block, M single-bf16 (16 MFMA per wave).
__global__ __launch_bounds__(256) void out_kernel(
    const uint4* __restrict__ qs, const unsigned* __restrict__ mpk,
    const float* __restrict__ b_out, float* __restrict__ out)
{
    __shared__ float bias_o[128];
    const int t = threadIdx.x;
    const int tile32 = blockIdx.x, b = blockIdx.y;
    const int chunk = tile32 >> 1;
    const int nb = (tile32 & 1) * 2;     // nt base: 0 or 2
    const int lane = t & 63;
    const int w = __builtin_amdgcn_readfirstlane(t >> 6);
    const int lg = lane >> 4, l15 = lane & 15;
    if (t < 128) bias_o[t] = b_out[t];
    __syncthreads();

    const uint4* q4 = qs + ((size_t)b * 64 + chunk) * 1024;
    const uint4* mp4 = (const uint4*)(mpk + (size_t)b * 8192);
    f32x4 acc2[2][2];
    #pragma unroll
    for (int rt = 0; rt < 2; ++rt)
        #pragma unroll
        for (int n2 = 0; n2 < 2; ++n2)
            acc2[rt][n2] = (f32x4){0.f, 0.f, 0.f, 0.f};
    #pragma unroll
    for (int ks = 0; ks < 4; ++ks) {
        bf16x8 bh[2];
        #pragma unroll
        for (int n2 = 0; n2 < 2; ++n2)
            bh[n2] = __builtin_bit_cast(bf16x8,
                q4[(ks * 4 + lg) * 64 + (nb + n2) * 16 + l15]);
        #pragma unroll
        for (int rt = 0; rt < 2; ++rt) {
            bf16x8 ah = __builtin_bit_cast(bf16x8,
                mp4[((2 * w + rt) * 4 + ks) * 64 + lane]);
            #pragma unroll
            for (int n2 = 0; n2 < 2; ++n2)
                acc2[rt][n2] = __builtin_amdgcn_mfma_f32_16x16x32_bf16(ah, bh[n2], acc2[rt][n2], 0, 0, 0);
        }
    }
    float* ob = out + (size_t)b * (128 * 4096) + chunk * 64;
    #pragma unroll
    for (int rt = 0; rt < 2; ++rt)
        #pragma unroll
        for (int r = 0; r < 4; ++r) {
            int ch = w * 32 + rt * 16 + lg * 4 + r;
            float bo = bias_o[ch];
            #pragma unroll
            for (int n2 = 0; n2 < 2; ++n2)
                ob[(size_t)ch * 4096 + (nb + n2) * 16 + l15] = acc2[rt][n2][r] + bo;
        }
}

extern "C" void kernel_launch(void* const* d_in, const int* in_sizes, int n_in,
                              void* d_out, int out_size, void* d_ws, size_t ws_size,
                              hipStream_t stream) {
    const float* x     = (const float*)d_in[0];
    const float* w_qkv = (const float*)d_in[1];
    const float* wA_q  = (const float*)d_in[2];
    const float* bA_q  = (const float*)d_in[3];
    const float* wB_q  = (const float*)d_in[4];
    const float* bB_q  = (const float*)d_in[5];
    const float* wA_k  = (const float*)d_in[6];
    const float* bA_k  = (const float*)d_in[7];
    const float* wB_k  = (const float*)d_in[8];
    const float* bB_k  = (const float*)d_in[9];
    const float* wA_v  = (const float*)d_in[10];
    const float* bA_v  = (const float*)d_in[11];
    const float* wB_v  = (const float*)d_in[12];
    const float* bB_v  = (const float*)d_in[13];
    const float* w_out = (const float*)d_in[14];
    const float* b_out = (const float*)d_in[15];
    float* out = (float*)d_out;

    float* ws = (float*)d_ws;
    float*    beff  = ws;                             // 384 f
    float*    part  = ws + 384;                       // 4325376 f
    float*    part2 = ws + 4325760;                   // 540672 f
    unsigned* wq    = (unsigned*)(ws + 4866432);      // 8192 u32
    unsigned* wkv   = (unsigned*)(ws + 4874624);      // 16384 u32
    unsigned* mpk   = (unsigned*)(ws + 4891008);      // 131072 u32
    uint4*    qs    = (uint4*)(ws + 5022080);         // 65536 uint4

    prep_kernel<<<97, 256, 0, stream>>>(w_qkv,
        wA_q, bA_q, wB_q, bB_q, wA_k, bA_k, wB_k, bB_k, wA_v, bA_v, wB_v, bB_v,
        wq, wkv, beff);
    ctx_fused_kernel<<<dim3(NCHUNK, 16), 256, 0, stream>>>(x, wq, wkv, beff,
        part, qs);
    combine_a_kernel<<<dim3(4, 16, 8), 256, 0, stream>>>(part, part2);
    combine_b_kernel<<<dim3(4, 16), 256, 0, stream>>>(part2, w_out, beff, mpk);
    out_kernel<<<dim3(128, 16), 256, 0, stream>>>(qs, mpk, b_out, out);
}